// Round 2
// baseline (3890.744 us; speedup 1.0000x reference)
//
#include <hip/hip_runtime.h>
#include <hip/hip_bf16.h>
#include <math.h>

typedef __hip_bfloat16 bf16;
typedef __attribute__((ext_vector_type(8))) short short8;
typedef __attribute__((ext_vector_type(4))) short short4v;
typedef __attribute__((ext_vector_type(4))) float f32x4;

constexpr int NB = 16;     // batch
constexpr int ND = 128;    // nodes N
constexpr int SQ = 129;    // S = N+1
constexpr int NH = 24;     // heads
constexpr int DM = 768;    // model dim
constexpr int DF = 3072;   // ffn dim
constexpr int NLAY = 12;
constexpr int MROWS = NB * SQ;  // 2064

__device__ __forceinline__ short f2bs(float f) {
  bf16 h = __float2bfloat16(f);
  return *(short*)&h;
}

__device__ __forceinline__ void gload16(const void* g, void* lds) {
  __builtin_amdgcn_global_load_lds(
      (const __attribute__((address_space(1))) unsigned int*)g,
      (__attribute__((address_space(3))) unsigned int*)lds, 16, 0, 0);
}

// ---------------- node features (fp32 in, fp32 out) ----------------
__global__ void k_nodefeat(const int* __restrict__ x, const int* __restrict__ ind,
                           const int* __restrict__ outd,
                           const float* __restrict__ atom, const float* __restrict__ ide,
                           const float* __restrict__ ode, const float* __restrict__ gtok,
                           float* __restrict__ h) {
  int bs = blockIdx.x;
  int b = bs / SQ, s = bs % SQ;
  int t = threadIdx.x;
  float* hrow = h + (size_t)bs * DM;
  if (s == 0) {
    for (int c = t; c < DM; c += 256) hrow[c] = gtok[c];
  } else {
    int n = s - 1;
    const int* xr = x + (b * ND + n) * 9;
    int a0 = xr[0], a1 = xr[1], a2 = xr[2], a3 = xr[3], a4 = xr[4];
    int a5 = xr[5], a6 = xr[6], a7 = xr[7], a8 = xr[8];
    int ii = ind[b * ND + n], oo = outd[b * ND + n];
    for (int c = t; c < DM; c += 256) {
      float acc = ide[(size_t)ii * DM + c] + ode[(size_t)oo * DM + c];
      acc += atom[(size_t)a0 * DM + c];
      acc += atom[(size_t)a1 * DM + c];
      acc += atom[(size_t)a2 * DM + c];
      acc += atom[(size_t)a3 * DM + c];
      acc += atom[(size_t)a4 * DM + c];
      acc += atom[(size_t)a5 * DM + c];
      acc += atom[(size_t)a6 * DM + c];
      acc += atom[(size_t)a7 * DM + c];
      acc += atom[(size_t)a8 * DM + c];
      hrow[c] = acc;
    }
  }
}

// ---------------- gab: virtual-token borders ----------------
__global__ void k_gab_border(const float* __restrict__ ab, const float* __restrict__ virt,
                             float* __restrict__ gab) {
  int b = blockIdx.x;
  const int tot = NH * SQ + NH * ND;
  for (int idx = threadIdx.x; idx < tot; idx += 256) {
    if (idx < NH * SQ) {
      int hh = idx / SQ, j = idx % SQ;
      float v = 2.f * ab[((size_t)b * SQ + 0) * SQ + j] + virt[hh];
      gab[(((size_t)b * NH + hh) * SQ + 0) * SQ + j] = v;
    } else {
      int r = idx - NH * SQ;
      int hh = r / ND, i = r % ND + 1;
      float v = 2.f * ab[((size_t)b * SQ + i) * SQ + 0] + virt[hh];
      gab[(((size_t)b * NH + hh) * SQ + i) * SQ + 0] = v;
    }
  }
}

// ---------------- gab: spatial + multihop edge bias ----------------
__global__ __launch_bounds__(256) void k_gab_edge(
    const int* __restrict__ spos, const int* __restrict__ eidx,
    const float* __restrict__ eemb, const float* __restrict__ edemb,
    const float* __restrict__ semb, const float* __restrict__ ab,
    float* __restrict__ gab) {
  __shared__ float ei[64 * 120];   // [j][d*24+h]
  __shared__ float ed[2880];       // edge_dis_emb[:5] flattened [d][h][k]
  int bi = blockIdx.x;
  int b = bi >> 7, i = bi & 127;
  int t = threadIdx.x;
  for (int idx = t; idx < 2880; idx += 256) ed[idx] = edemb[idx];
  for (int half = 0; half < 2; half++) {
    int j0 = half * 64;
    __syncthreads();
    for (int idx = t; idx < 64 * 120; idx += 256) {
      int j = idx / 120, dh = idx % 120;
      int d = dh / 24, hh = dh % 24;
      const int* ep = eidx + (((size_t)(b * ND + i) * ND + (j0 + j)) * 5 + d) * 3;
      float v = eemb[ep[0] * NH + hh] + eemb[ep[1] * NH + hh] + eemb[ep[2] * NH + hh];
      ei[idx] = v * (1.f / 3.f);
    }
    __syncthreads();
    for (int idx = t; idx < 64 * 24; idx += 256) {
      int j = idx / 24, k = idx % 24;
      const float* er = ei + j * 120;
      float acc = 0.f;
#pragma unroll 8
      for (int dh = 0; dh < 120; dh++) acc += er[dh] * ed[dh * 24 + k];
      int sp = spos[(size_t)(b * ND + i) * ND + (j0 + j)];
      int spc = (sp == 0) ? 1 : sp;
      spc = (spc > 1) ? spc - 1 : spc;
      if (spc > 5) spc = 5;
      float eb = acc / (float)spc;
      float sb = semb[sp * NH + k];
      float a2 = 2.f * ab[((size_t)b * SQ + (i + 1)) * SQ + (j0 + j + 1)];
      gab[(((size_t)b * NH + k) * SQ + (i + 1)) * SQ + (j0 + j + 1)] = a2 + sb + eb;
    }
  }
}

// ---------------- weight transpose+cast: f32 [R,C] -> bf16 [C,R] ----------------
struct Ptrs4 { const float* p[4]; };

__global__ void k_transpose(Ptrs4 ps, short* __restrict__ dst, int R, int C, int dstride) {
  __shared__ short tile[64][68];
  const float* src = ps.p[blockIdx.z];
  short* d = dst + (size_t)blockIdx.z * dstride;
  int r0 = blockIdx.x * 64, c0 = blockIdx.y * 64;
  int t = threadIdx.x;
  int tr = t >> 4, tc = (t & 15) * 4;
#pragma unroll
  for (int i = 0; i < 4; i++) {
    int r = tr + i * 16;
    f32x4 v = *(const f32x4*)(src + (size_t)(r0 + r) * C + c0 + tc);
    tile[r][tc + 0] = f2bs(v[0]);
    tile[r][tc + 1] = f2bs(v[1]);
    tile[r][tc + 2] = f2bs(v[2]);
    tile[r][tc + 3] = f2bs(v[3]);
  }
  __syncthreads();
#pragma unroll
  for (int i = 0; i < 4; i++) {
    int rr = tr + i * 16;
    short4v o;
    o[0] = tile[tc + 0][rr];
    o[1] = tile[tc + 1][rr];
    o[2] = tile[tc + 2][rr];
    o[3] = tile[tc + 3][rr];
    *(short4v*)(d + (size_t)(c0 + rr) * R + r0 + tc) = o;
  }
}

// ---------------- LayerNorm: fp32 row -> bf16 row ----------------
__global__ void k_ln(const float* __restrict__ h, const float* __restrict__ g,
                     const float* __restrict__ bb, bf16* __restrict__ y) {
  int r = blockIdx.x;
  int t = threadIdx.x, lane = t & 63, wid = t >> 6;
  __shared__ float red[8];
  const float* row = h + (size_t)r * DM;
  float v0 = row[t], v1 = row[t + 256], v2 = row[t + 512];
  float s = v0 + v1 + v2;
#pragma unroll
  for (int o = 32; o > 0; o >>= 1) s += __shfl_xor(s, o);
  if (lane == 0) red[wid] = s;
  __syncthreads();
  float mean = (red[0] + red[1] + red[2] + red[3]) * (1.f / 768.f);
  float d0 = v0 - mean, d1 = v1 - mean, d2 = v2 - mean;
  float q = d0 * d0 + d1 * d1 + d2 * d2;
#pragma unroll
  for (int o = 32; o > 0; o >>= 1) q += __shfl_xor(q, o);
  if (lane == 0) red[4 + wid] = q;
  __syncthreads();
  float var = (red[4] + red[5] + red[6] + red[7]) * (1.f / 768.f);
  float rstd = rsqrtf(var + 1e-5f);
  bf16* yr = y + (size_t)r * DM;
  yr[t] = __float2bfloat16(d0 * rstd * g[t] + bb[t]);
  yr[t + 256] = __float2bfloat16(d1 * rstd * g[t + 256] + bb[t + 256]);
  yr[t + 512] = __float2bfloat16(d2 * rstd * g[t + 512] + bb[t + 512]);
}

// ---------------- GEMM: C[M,N] = A[M,K](bf16) @ BT[N,K]^T + bias ----------------
// MODE 0: store fp32; MODE 1: resid fp32 +=; MODE 2: exact GELU -> bf16
struct GemmPtrs {
  const short* bt[3];
  const float* bias[3];
  void* out[3];
};

template <int MODE>
__global__ __launch_bounds__(256, 2) void k_gemm(const short* __restrict__ A, GemmPtrs p,
                                                 int M, int N, int K) {
  __shared__ short At[128 * 32];
  __shared__ short Bt[128 * 32];
  const short* BT = p.bt[blockIdx.z];
  const float* bias = p.bias[blockIdx.z];
  int m0 = blockIdx.x * 128, n0 = blockIdx.y * 128;
  int t = threadIdx.x, lane = t & 63, wid = t >> 6;
  int wr = wid >> 1, wc = wid & 1;
  f32x4 acc[4][4];
#pragma unroll
  for (int a = 0; a < 4; a++)
#pragma unroll
    for (int c = 0; c < 4; c++) acc[a][c] = (f32x4){0.f, 0.f, 0.f, 0.f};

  int srow = wid * 32 + (lane >> 2);
  int scol = (lane & 3) * 8;
  int ar0 = m0 + srow; if (ar0 >= M) ar0 = M - 1;
  int ar1 = m0 + srow + 16; if (ar1 >= M) ar1 = M - 1;
  int br0 = n0 + srow, br1 = br0 + 16;
  const short* Ag0 = A + (size_t)ar0 * K + scol;
  const short* Ag1 = A + (size_t)ar1 * K + scol;
  const short* Bg0 = BT + (size_t)br0 * K + scol;
  const short* Bg1 = BT + (size_t)br1 * K + scol;
  short* Al0 = &At[(wid * 32) * 32];
  short* Al1 = &At[(wid * 32 + 16) * 32];
  short* Bl0 = &Bt[(wid * 32) * 32];
  short* Bl1 = &Bt[(wid * 32 + 16) * 32];
  int fr = lane & 15, fo = (lane >> 4) * 8;

  for (int k0 = 0; k0 < K; k0 += 32) {
    gload16(Ag0 + k0, Al0);
    gload16(Ag1 + k0, Al1);
    gload16(Bg0 + k0, Bl0);
    gload16(Bg1 + k0, Bl1);
    __syncthreads();
    short8 af[4], bfr[4];
#pragma unroll
    for (int mr = 0; mr < 4; mr++)
      af[mr] = *(const short8*)&At[(wr * 64 + mr * 16 + fr) * 32 + fo];
#pragma unroll
    for (int nc = 0; nc < 4; nc++)
      bfr[nc] = *(const short8*)&Bt[(wc * 64 + nc * 16 + fr) * 32 + fo];
#pragma unroll
    for (int mr = 0; mr < 4; mr++)
#pragma unroll
      for (int nc = 0; nc < 4; nc++)
        acc[mr][nc] = __builtin_amdgcn_mfma_f32_16x16x32_bf16(af[mr], bfr[nc], acc[mr][nc], 0, 0, 0);
    __syncthreads();
  }

  int rsub = (lane >> 4) * 4;
#pragma unroll
  for (int nc = 0; nc < 4; nc++) {
    int col = n0 + wc * 64 + nc * 16 + fr;
    float bv = bias[col];
#pragma unroll
    for (int mr = 0; mr < 4; mr++) {
#pragma unroll
      for (int e = 0; e < 4; e++) {
        int r = m0 + wr * 64 + mr * 16 + rsub + e;
        if (r < M) {
          float v = acc[mr][nc][e] + bv;
          if (MODE == 0) {
            ((float*)p.out[blockIdx.z])[(size_t)r * N + col] = v;
          } else if (MODE == 1) {
            ((float*)p.out[blockIdx.z])[(size_t)r * N + col] += v;
          } else {
            float gg = 0.5f * v * (1.f + erff(v * 0.70710678118654752f));
            ((bf16*)p.out[blockIdx.z])[(size_t)r * N + col] = __float2bfloat16(gg);
          }
        }
      }
    }
  }
}

// ---------------- attention: per (b,h) block ----------------
__global__ __launch_bounds__(256) void k_attn(const float* __restrict__ Q,
                                              const float* __restrict__ Kb,
                                              const float* __restrict__ Vb,
                                              const float* __restrict__ gab,
                                              bf16* __restrict__ ctx) {
  int bh = blockIdx.x;
  int b = bh / NH, hh = bh % NH;
  __shared__ float Kl[129][33];
  __shared__ float Vl[129][33];
  __shared__ float pl[4][132];
  int t = threadIdx.x;
  for (int idx = t; idx < 129 * 32; idx += 256) {
    int ks = idx >> 5, d = idx & 31;
    size_t src = ((size_t)(b * SQ + ks)) * DM + hh * 32 + d;
    Kl[ks][d] = Kb[src];
    Vl[ks][d] = Vb[src];
  }
  __syncthreads();
  int w = t >> 6, lane = t & 63;
  const float scale = 0.17677669529663689f;  // 1/sqrt(32)
  for (int q = w; q < SQ; q += 4) {
    const float* qrow = Q + ((size_t)(b * SQ + q)) * DM + hh * 32;
    float qv[32];
#pragma unroll
    for (int d = 0; d < 32; d++) qv[d] = qrow[d];
    const float* grow = gab + (((size_t)(b * NH + hh)) * SQ + q) * SQ;
    float sc0, sc1, sc2 = -1e30f;
    {
      int k = lane;
      float s = 0.f;
#pragma unroll
      for (int d = 0; d < 32; d++) s += qv[d] * Kl[k][d];
      sc0 = s * scale + grow[k];
    }
    {
      int k = lane + 64;
      float s = 0.f;
#pragma unroll
      for (int d = 0; d < 32; d++) s += qv[d] * Kl[k][d];
      sc1 = s * scale + grow[k];
    }
    if (lane == 0) {
      float s = 0.f;
#pragma unroll
      for (int d = 0; d < 32; d++) s += qv[d] * Kl[128][d];
      sc2 = s * scale + grow[128];
    }
    float m = fmaxf(sc0, fmaxf(sc1, sc2));
#pragma unroll
    for (int o = 32; o > 0; o >>= 1) m = fmaxf(m, __shfl_xor(m, o));
    float e0 = __expf(sc0 - m), e1 = __expf(sc1 - m);
    float e2 = (lane == 0) ? __expf(sc2 - m) : 0.f;
    float sum = e0 + e1 + e2;
#pragma unroll
    for (int o = 32; o > 0; o >>= 1) sum += __shfl_xor(sum, o);
    float inv = 1.f / sum;
    pl[w][lane] = e0 * inv;
    pl[w][lane + 64] = e1 * inv;
    if (lane == 0) pl[w][128] = e2 * inv;
    asm volatile("s_waitcnt lgkmcnt(0)" ::: "memory");
    int d = lane & 31, half = lane >> 5;
    float a = 0.f;
    if (half == 0) {
      for (int k = 0; k < 65; k++) a += pl[w][k] * Vl[k][d];
    } else {
      for (int k = 65; k < 129; k++) a += pl[w][k] * Vl[k][d];
    }
    a += __shfl_down(a, 32);
    if (lane < 32)
      ctx[((size_t)(b * SQ + q)) * DM + hh * 32 + d] = __float2bfloat16(a);
  }
}

// ---------------- final: LN row0 + pooled projection ----------------
__global__ void k_final(const float* __restrict__ h, const float* __restrict__ g,
                        const float* __restrict__ bb, const float* __restrict__ ow,
                        const float* __restrict__ ob, float* __restrict__ out) {
  int b = blockIdx.x;
  int t = threadIdx.x, lane = t & 63, wid = t >> 6;
  __shared__ float red[8];
  __shared__ float yn[768];
  const float* row = h + (size_t)(b * SQ) * DM;
  float v0 = row[t], v1 = row[t + 256], v2 = row[t + 512];
  float s = v0 + v1 + v2;
#pragma unroll
  for (int o = 32; o > 0; o >>= 1) s += __shfl_xor(s, o);
  if (lane == 0) red[wid] = s;
  __syncthreads();
  float mean = (red[0] + red[1] + red[2] + red[3]) * (1.f / 768.f);
  float d0 = v0 - mean, d1 = v1 - mean, d2 = v2 - mean;
  float q = d0 * d0 + d1 * d1 + d2 * d2;
#pragma unroll
  for (int o = 32; o > 0; o >>= 1) q += __shfl_xor(q, o);
  if (lane == 0) red[4 + wid] = q;
  __syncthreads();
  float var = (red[4] + red[5] + red[6] + red[7]) * (1.f / 768.f);
  float rstd = rsqrtf(var + 1e-5f);
  yn[t] = d0 * rstd * g[t] + bb[t];
  yn[t + 256] = d1 * rstd * g[t + 256] + bb[t + 256];
  yn[t + 512] = d2 * rstd * g[t + 512] + bb[t + 512];
  __syncthreads();
  if (t < 128) {
    float acc = ob[t];
    for (int d = 0; d < 768; d++) acc += yn[d] * ow[d * 128 + t];
    out[b * 128 + t] = acc;
  }
}

extern "C" void kernel_launch(void* const* d_in, const int* in_sizes, int n_in,
                              void* d_out, int out_size, void* d_ws, size_t ws_size,
                              hipStream_t stream) {
  (void)in_sizes; (void)n_in; (void)out_size; (void)ws_size;
  const int* x     = (const int*)d_in[0];
  const int* ind   = (const int*)d_in[1];
  const int* outd  = (const int*)d_in[2];
  const int* spos  = (const int*)d_in[3];
  const int* eidx  = (const int*)d_in[4];
  const float* ab   = (const float*)d_in[5];
  const float* atom = (const float*)d_in[6];
  const float* ide  = (const float*)d_in[7];
  const float* ode  = (const float*)d_in[8];
  const float* gtok = (const float*)d_in[9];
  const float* eemb = (const float*)d_in[10];
  const float* edemb= (const float*)d_in[11];
  const float* semb = (const float*)d_in[12];
  const float* virt = (const float*)d_in[13];
  const float* ln1g = (const float*)d_in[14];
  const float* ln1b = (const float*)d_in[15];
  const float* wq  = (const float*)d_in[16];
  const float* bq   = (const float*)d_in[17];
  const float* wk  = (const float*)d_in[18];
  const float* bk   = (const float*)d_in[19];
  const float* wv  = (const float*)d_in[20];
  const float* bv   = (const float*)d_in[21];
  const float* wo  = (const float*)d_in[22];
  const float* bo   = (const float*)d_in[23];
  const float* ln2g = (const float*)d_in[24];
  const float* ln2b = (const float*)d_in[25];
  const float* w1  = (const float*)d_in[26];
  const float* b1   = (const float*)d_in[27];
  const float* w2  = (const float*)d_in[28];
  const float* b2   = (const float*)d_in[29];
  const float* fg   = (const float*)d_in[30];
  const float* fb   = (const float*)d_in[31];
  const float* ow   = (const float*)d_in[32];
  const float* ob   = (const float*)d_in[33];
  float* out = (float*)d_out;

  char* ws = (char*)d_ws;
  size_t off = 0;
  auto alloc = [&](size_t bytes) -> void* {
    void* p = ws + off;
    off += (bytes + 255) & ~(size_t)255;
    return p;
  };
  float* gab = (float*)alloc((size_t)NB * NH * SQ * SQ * 4);
  float* h   = (float*)alloc((size_t)MROWS * DM * 4);
  bf16* y    = (bf16*)alloc((size_t)MROWS * DM * 2);
  float* qb  = (float*)alloc((size_t)MROWS * DM * 4);
  float* kb2 = (float*)alloc((size_t)MROWS * DM * 4);
  float* vb2 = (float*)alloc((size_t)MROWS * DM * 4);
  bf16* ctx  = (bf16*)alloc((size_t)MROWS * DM * 2);
  bf16* t1   = (bf16*)alloc((size_t)MROWS * DF * 2);
  short* wT  = (short*)alloc((size_t)4 * DM * DM * 2);
  short* w1T = (short*)alloc((size_t)DM * DF * 2);
  short* w2T = (short*)alloc((size_t)DM * DF * 2);

  dim3 blk(256);
  k_nodefeat<<<dim3(NB * SQ), blk, 0, stream>>>(x, ind, outd, atom, ide, ode, gtok, h);
  k_gab_border<<<dim3(NB), blk, 0, stream>>>(ab, virt, gab);
  k_gab_edge<<<dim3(NB * ND), blk, 0, stream>>>(spos, eidx, eemb, edemb, semb, ab, gab);

  const int DD2 = DM * DM;
  for (int l = 0; l < NLAY; l++) {
    Ptrs4 p4;
    p4.p[0] = wq + (size_t)l * DD2;
    p4.p[1] = wk + (size_t)l * DD2;
    p4.p[2] = wv + (size_t)l * DD2;
    p4.p[3] = wo + (size_t)l * DD2;
    k_transpose<<<dim3(12, 12, 4), blk, 0, stream>>>(p4, wT, DM, DM, DD2);
    Ptrs4 pw1; pw1.p[0] = w1 + (size_t)l * DM * DF; pw1.p[1] = pw1.p[2] = pw1.p[3] = pw1.p[0];
    k_transpose<<<dim3(12, 48, 1), blk, 0, stream>>>(pw1, w1T, DM, DF, 0);
    Ptrs4 pw2; pw2.p[0] = w2 + (size_t)l * DF * DM; pw2.p[1] = pw2.p[2] = pw2.p[3] = pw2.p[0];
    k_transpose<<<dim3(48, 12, 1), blk, 0, stream>>>(pw2, w2T, DF, DM, 0);

    k_ln<<<dim3(MROWS), blk, 0, stream>>>(h, ln1g + l * DM, ln1b + l * DM, y);

    GemmPtrs gq;
    gq.bt[0] = wT; gq.bt[1] = wT + DD2; gq.bt[2] = wT + 2 * DD2;
    gq.bias[0] = bq + l * DM; gq.bias[1] = bk + l * DM; gq.bias[2] = bv + l * DM;
    gq.out[0] = qb; gq.out[1] = kb2; gq.out[2] = vb2;
    k_gemm<0><<<dim3(17, 6, 3), blk, 0, stream>>>((const short*)y, gq, MROWS, DM, DM);

    k_attn<<<dim3(NB * NH), blk, 0, stream>>>(qb, kb2, vb2, gab, ctx);

    GemmPtrs go;
    go.bt[0] = go.bt[1] = go.bt[2] = wT + 3 * DD2;
    go.bias[0] = go.bias[1] = go.bias[2] = bo + l * DM;
    go.out[0] = go.out[1] = go.out[2] = h;
    k_gemm<1><<<dim3(17, 6, 1), blk, 0, stream>>>((const short*)ctx, go, MROWS, DM, DM);

    k_ln<<<dim3(MROWS), blk, 0, stream>>>(h, ln2g + l * DM, ln2b + l * DM, y);

    GemmPtrs g1;
    g1.bt[0] = g1.bt[1] = g1.bt[2] = w1T;
    g1.bias[0] = g1.bias[1] = g1.bias[2] = b1 + l * DF;
    g1.out[0] = g1.out[1] = g1.out[2] = t1;
    k_gemm<2><<<dim3(17, 24, 1), blk, 0, stream>>>((const short*)y, g1, MROWS, DF, DM);

    GemmPtrs g2;
    g2.bt[0] = g2.bt[1] = g2.bt[2] = w2T;
    g2.bias[0] = g2.bias[1] = g2.bias[2] = b2 + l * DM;
    g2.out[0] = g2.out[1] = g2.out[2] = h;
    k_gemm<1><<<dim3(17, 6, 1), blk, 0, stream>>>((const short*)t1, g2, MROWS, DM, DF);
  }

  k_final<<<dim3(NB), blk, 0, stream>>>(h, fg, fb, ow, ob, out);
}

// Round 3
// 2499.268 us; speedup vs baseline: 1.5568x; 1.5568x over previous
//
#include <hip/hip_runtime.h>
#include <hip/hip_bf16.h>
#include <math.h>

typedef __hip_bfloat16 bf16;
typedef __attribute__((ext_vector_type(8))) short short8;
typedef __attribute__((ext_vector_type(4))) short short4v;
typedef __attribute__((ext_vector_type(4))) float f32x4;
typedef __attribute__((ext_vector_type(2))) float f32x2;

constexpr int NB = 16;     // batch
constexpr int ND = 128;    // nodes N
constexpr int SQ = 129;    // S = N+1
constexpr int NH = 24;     // heads
constexpr int DM = 768;    // model dim
constexpr int DF = 3072;   // ffn dim
constexpr int NLAY = 12;
constexpr int MROWS = NB * SQ;  // 2064

__device__ __forceinline__ short f2bs(float f) {
  bf16 h = __float2bfloat16(f);
  return *(short*)&h;
}
__device__ __forceinline__ float bs2f(short s) {
  return __bfloat162float(*reinterpret_cast<bf16*>(&s));
}

__device__ __forceinline__ void gload16(const void* g, void* lds) {
  __builtin_amdgcn_global_load_lds(
      (const __attribute__((address_space(1))) unsigned int*)g,
      (__attribute__((address_space(3))) unsigned int*)lds, 16, 0, 0);
}

// ---------------- node features (fp32 in, fp32 out) ----------------
__global__ void k_nodefeat(const int* __restrict__ x, const int* __restrict__ ind,
                           const int* __restrict__ outd,
                           const float* __restrict__ atom, const float* __restrict__ ide,
                           const float* __restrict__ ode, const float* __restrict__ gtok,
                           float* __restrict__ h) {
  int bs = blockIdx.x;
  int b = bs / SQ, s = bs % SQ;
  int t = threadIdx.x;
  float* hrow = h + (size_t)bs * DM;
  if (s == 0) {
    for (int c = t; c < DM; c += 256) hrow[c] = gtok[c];
  } else {
    int n = s - 1;
    const int* xr = x + (b * ND + n) * 9;
    int a0 = xr[0], a1 = xr[1], a2 = xr[2], a3 = xr[3], a4 = xr[4];
    int a5 = xr[5], a6 = xr[6], a7 = xr[7], a8 = xr[8];
    int ii = ind[b * ND + n], oo = outd[b * ND + n];
    for (int c = t; c < DM; c += 256) {
      float acc = ide[(size_t)ii * DM + c] + ode[(size_t)oo * DM + c];
      acc += atom[(size_t)a0 * DM + c];
      acc += atom[(size_t)a1 * DM + c];
      acc += atom[(size_t)a2 * DM + c];
      acc += atom[(size_t)a3 * DM + c];
      acc += atom[(size_t)a4 * DM + c];
      acc += atom[(size_t)a5 * DM + c];
      acc += atom[(size_t)a6 * DM + c];
      acc += atom[(size_t)a7 * DM + c];
      acc += atom[(size_t)a8 * DM + c];
      hrow[c] = acc;
    }
  }
}

// ---------------- gab: virtual-token borders ----------------
__global__ void k_gab_border(const float* __restrict__ ab, const float* __restrict__ virt,
                             float* __restrict__ gab) {
  int b = blockIdx.x;
  const int tot = NH * SQ + NH * ND;
  for (int idx = threadIdx.x; idx < tot; idx += 256) {
    if (idx < NH * SQ) {
      int hh = idx / SQ, j = idx % SQ;
      float v = 2.f * ab[((size_t)b * SQ + 0) * SQ + j] + virt[hh];
      gab[(((size_t)b * NH + hh) * SQ + 0) * SQ + j] = v;
    } else {
      int r = idx - NH * SQ;
      int hh = r / ND, i = r % ND + 1;
      float v = 2.f * ab[((size_t)b * SQ + i) * SQ + 0] + virt[hh];
      gab[(((size_t)b * NH + hh) * SQ + i) * SQ + 0] = v;
    }
  }
}

// ---------------- gab: spatial + multihop edge bias ----------------
// One block per (b, i, half). 256 threads. LDS ~26.9KB -> 5 blocks/CU.
__global__ __launch_bounds__(256) void k_gab_edge(
    const int* __restrict__ spos, const int* __restrict__ eidx,
    const float* __restrict__ eemb, const float* __restrict__ edemb,
    const float* __restrict__ semb, const float* __restrict__ ab,
    float* __restrict__ gab) {
  __shared__ short ei2[64 * 120];  // bf16 [j][d*24+h]
  __shared__ float ed[2880];       // edge_dis_emb[:5] [d][h][k]
  int bi = blockIdx.x;
  int half = bi & 1;
  int i = (bi >> 1) & 127;
  int b = bi >> 8;
  int j0 = half * 64;
  int t = threadIdx.x;
  for (int idx = t; idx < 2880; idx += 256) ed[idx] = edemb[idx];
  const size_t rowbase = ((size_t)(b * ND + i)) * ND + j0;
  for (int idx = t; idx < 64 * 120; idx += 256) {
    int j = idx / 120, dh = idx % 120;
    int d = dh / 24, hh = dh % 24;
    const int* ep = eidx + ((rowbase + j) * 5 + d) * 3;
    float v = eemb[ep[0] * NH + hh] + eemb[ep[1] * NH + hh] + eemb[ep[2] * NH + hh];
    ei2[idx] = f2bs(v * (1.f / 3.f));
  }
  __syncthreads();
  int j = t >> 2, k0 = (t & 3) * 6;
  f32x2 acc0 = {0.f, 0.f}, acc1 = {0.f, 0.f}, acc2 = {0.f, 0.f};
  const short* er = &ei2[j * 120];
  for (int dh = 0; dh < 120; dh++) {
    float e = bs2f(er[dh]);
    const float* edr = &ed[dh * 24 + k0];
    f32x2 e0 = *(const f32x2*)(edr);
    f32x2 e1 = *(const f32x2*)(edr + 2);
    f32x2 e2 = *(const f32x2*)(edr + 4);
    acc0 += e * e0;
    acc1 += e * e1;
    acc2 += e * e2;
  }
  float accs[6] = {acc0[0], acc0[1], acc1[0], acc1[1], acc2[0], acc2[1]};
  int sp = spos[rowbase + j];
  int spc = (sp == 0) ? 1 : sp;
  spc = (spc > 1) ? spc - 1 : spc;
  if (spc > 5) spc = 5;
  float rinv = 1.f / (float)spc;
  float a2 = 2.f * ab[((size_t)b * SQ + (i + 1)) * SQ + (j0 + j + 1)];
  size_t obase = (((size_t)b * NH) * SQ + (i + 1)) * SQ + (j0 + j + 1);
#pragma unroll
  for (int u = 0; u < 6; u++) {
    int k = k0 + u;
    float v = a2 + semb[sp * NH + k] + accs[u] * rinv;
    gab[obase + (size_t)k * SQ * SQ] = v;
  }
}

// ---------------- weight transpose+cast: f32 [R,C] -> bf16 [C,R] ----------------
struct Ptrs4 { const float* p[4]; };

template <int NW>
__global__ void k_transpose(Ptrs4 ps, short* __restrict__ dst, int R, int C,
                            size_t sstride) {
  __shared__ short tile[64][68];
  int z = blockIdx.z;
  const float* src = ps.p[z % NW] + (size_t)(z / NW) * sstride;
  short* d = dst + (size_t)z * (size_t)R * C;
  int r0 = blockIdx.x * 64, c0 = blockIdx.y * 64;
  int t = threadIdx.x;
  int tr = t >> 4, tc = (t & 15) * 4;
#pragma unroll
  for (int i = 0; i < 4; i++) {
    int r = tr + i * 16;
    f32x4 v = *(const f32x4*)(src + (size_t)(r0 + r) * C + c0 + tc);
    tile[r][tc + 0] = f2bs(v[0]);
    tile[r][tc + 1] = f2bs(v[1]);
    tile[r][tc + 2] = f2bs(v[2]);
    tile[r][tc + 3] = f2bs(v[3]);
  }
  __syncthreads();
#pragma unroll
  for (int i = 0; i < 4; i++) {
    int rr = tr + i * 16;
    short4v o;
    o[0] = tile[tc + 0][rr];
    o[1] = tile[tc + 1][rr];
    o[2] = tile[tc + 2][rr];
    o[3] = tile[tc + 3][rr];
    *(short4v*)(d + (size_t)(c0 + rr) * R + r0 + tc) = o;
  }
}

// ---------------- LayerNorm: fp32 row -> bf16 row ----------------
__global__ void k_ln(const float* __restrict__ h, const float* __restrict__ g,
                     const float* __restrict__ bb, bf16* __restrict__ y) {
  int r = blockIdx.x;
  int t = threadIdx.x, lane = t & 63, wid = t >> 6;
  __shared__ float red[8];
  const float* row = h + (size_t)r * DM;
  float v0 = row[t], v1 = row[t + 256], v2 = row[t + 512];
  float s = v0 + v1 + v2;
#pragma unroll
  for (int o = 32; o > 0; o >>= 1) s += __shfl_xor(s, o);
  if (lane == 0) red[wid] = s;
  __syncthreads();
  float mean = (red[0] + red[1] + red[2] + red[3]) * (1.f / 768.f);
  float d0 = v0 - mean, d1 = v1 - mean, d2 = v2 - mean;
  float q = d0 * d0 + d1 * d1 + d2 * d2;
#pragma unroll
  for (int o = 32; o > 0; o >>= 1) q += __shfl_xor(q, o);
  if (lane == 0) red[4 + wid] = q;
  __syncthreads();
  float var = (red[4] + red[5] + red[6] + red[7]) * (1.f / 768.f);
  float rstd = rsqrtf(var + 1e-5f);
  bf16* yr = y + (size_t)r * DM;
  yr[t] = __float2bfloat16(d0 * rstd * g[t] + bb[t]);
  yr[t + 256] = __float2bfloat16(d1 * rstd * g[t + 256] + bb[t + 256]);
  yr[t + 512] = __float2bfloat16(d2 * rstd * g[t + 512] + bb[t + 512]);
}

// ---------------- fused: h += p0+p1+cbias; y = LN(h) ----------------
__global__ void k_ln_add2(float* __restrict__ h, const float* __restrict__ p0,
                          const float* __restrict__ p1, const float* __restrict__ cb,
                          const float* __restrict__ g, const float* __restrict__ bb,
                          bf16* __restrict__ y) {
  int r = blockIdx.x;
  int t = threadIdx.x, lane = t & 63, wid = t >> 6;
  __shared__ float red[8];
  size_t base = (size_t)r * DM;
  float v0 = h[base + t] + p0[base + t] + p1[base + t] + cb[t];
  float v1 = h[base + t + 256] + p0[base + t + 256] + p1[base + t + 256] + cb[t + 256];
  float v2 = h[base + t + 512] + p0[base + t + 512] + p1[base + t + 512] + cb[t + 512];
  h[base + t] = v0;
  h[base + t + 256] = v1;
  h[base + t + 512] = v2;
  float s = v0 + v1 + v2;
#pragma unroll
  for (int o = 32; o > 0; o >>= 1) s += __shfl_xor(s, o);
  if (lane == 0) red[wid] = s;
  __syncthreads();
  float mean = (red[0] + red[1] + red[2] + red[3]) * (1.f / 768.f);
  float d0 = v0 - mean, d1 = v1 - mean, d2 = v2 - mean;
  float q = d0 * d0 + d1 * d1 + d2 * d2;
#pragma unroll
  for (int o = 32; o > 0; o >>= 1) q += __shfl_xor(q, o);
  if (lane == 0) red[4 + wid] = q;
  __syncthreads();
  float var = (red[4] + red[5] + red[6] + red[7]) * (1.f / 768.f);
  float rstd = rsqrtf(var + 1e-5f);
  bf16* yr = y + base;
  yr[t] = __float2bfloat16(d0 * rstd * g[t] + bb[t]);
  yr[t + 256] = __float2bfloat16(d1 * rstd * g[t + 256] + bb[t + 256]);
  yr[t + 512] = __float2bfloat16(d2 * rstd * g[t + 512] + bb[t + 512]);
}

// ---------------- GEMM common ----------------
// MODE 0: store fp32 + bias; MODE 2: exact GELU(bias+v) -> bf16; MODE 3: raw fp32 store
struct GemmPtrs {
  const short* bt[3];
  const float* bias[3];
  void* out[3];
  int aoff[3];
};

// 128x128 tile (FFN1)
template <int MODE>
__global__ __launch_bounds__(256, 2) void k_gemm128(const short* __restrict__ A, GemmPtrs p,
                                                    int M, int N, int K, int lda, int ldb) {
  __shared__ short At[128 * 32];
  __shared__ short Bt[128 * 32];
  int z = blockIdx.z;
  const short* BT = p.bt[z];
  const float* bias = p.bias[z];
  A += p.aoff[z];
  int m0 = blockIdx.x * 128, n0 = blockIdx.y * 128;
  int t = threadIdx.x, lane = t & 63, wid = t >> 6;
  int wr = wid >> 1, wc = wid & 1;
  f32x4 acc[4][4];
#pragma unroll
  for (int a = 0; a < 4; a++)
#pragma unroll
    for (int c = 0; c < 4; c++) acc[a][c] = (f32x4){0.f, 0.f, 0.f, 0.f};

  int srow = wid * 32 + (lane >> 2);
  int scol = (lane & 3) * 8;
  int ar0 = m0 + srow; if (ar0 >= M) ar0 = M - 1;
  int ar1 = m0 + srow + 16; if (ar1 >= M) ar1 = M - 1;
  int br0 = n0 + srow, br1 = br0 + 16;
  const short* Ag0 = A + (size_t)ar0 * lda + scol;
  const short* Ag1 = A + (size_t)ar1 * lda + scol;
  const short* Bg0 = BT + (size_t)br0 * ldb + scol;
  const short* Bg1 = BT + (size_t)br1 * ldb + scol;
  short* Al0 = &At[(wid * 32) * 32];
  short* Al1 = &At[(wid * 32 + 16) * 32];
  short* Bl0 = &Bt[(wid * 32) * 32];
  short* Bl1 = &Bt[(wid * 32 + 16) * 32];
  int fr = lane & 15, fo = (lane >> 4) * 8;

  for (int k0 = 0; k0 < K; k0 += 32) {
    gload16(Ag0 + k0, Al0);
    gload16(Ag1 + k0, Al1);
    gload16(Bg0 + k0, Bl0);
    gload16(Bg1 + k0, Bl1);
    __syncthreads();
    short8 af[4], bfr[4];
#pragma unroll
    for (int mr = 0; mr < 4; mr++)
      af[mr] = *(const short8*)&At[(wr * 64 + mr * 16 + fr) * 32 + fo];
#pragma unroll
    for (int nc = 0; nc < 4; nc++)
      bfr[nc] = *(const short8*)&Bt[(wc * 64 + nc * 16 + fr) * 32 + fo];
#pragma unroll
    for (int mr = 0; mr < 4; mr++)
#pragma unroll
      for (int nc = 0; nc < 4; nc++)
        acc[mr][nc] = __builtin_amdgcn_mfma_f32_16x16x32_bf16(af[mr], bfr[nc], acc[mr][nc], 0, 0, 0);
    __syncthreads();
  }

  int rsub = (lane >> 4) * 4;
#pragma unroll
  for (int nc = 0; nc < 4; nc++) {
    int col = n0 + wc * 64 + nc * 16 + fr;
    float bv = (MODE == 3) ? 0.f : bias[col];
#pragma unroll
    for (int mr = 0; mr < 4; mr++) {
#pragma unroll
      for (int e = 0; e < 4; e++) {
        int r = m0 + wr * 64 + mr * 16 + rsub + e;
        if (r < M) {
          float v = acc[mr][nc][e] + bv;
          if (MODE == 0 || MODE == 3) {
            ((float*)p.out[z])[(size_t)r * N + col] = v;
          } else {
            float gg = 0.5f * v * (1.f + erff(v * 0.70710678118654752f));
            ((bf16*)p.out[z])[(size_t)r * N + col] = __float2bfloat16(gg);
          }
        }
      }
    }
  }
}

// 64x128 tile (QKV / Wo / FFN2) — more blocks, 3 blocks/CU.
template <int MODE>
__global__ __launch_bounds__(256, 3) void k_gemm64(const short* __restrict__ A, GemmPtrs p,
                                                   int M, int N, int K, int lda, int ldb) {
  __shared__ short At[64 * 32];
  __shared__ short Bt[128 * 32];
  int z = blockIdx.z;
  const short* BT = p.bt[z];
  const float* bias = p.bias[z];
  A += p.aoff[z];
  int m0 = blockIdx.x * 64, n0 = blockIdx.y * 128;
  int t = threadIdx.x, lane = t & 63, wid = t >> 6;
  int wr = wid >> 1, wc = wid & 1;
  f32x4 acc[2][4];
#pragma unroll
  for (int a = 0; a < 2; a++)
#pragma unroll
    for (int c = 0; c < 4; c++) acc[a][c] = (f32x4){0.f, 0.f, 0.f, 0.f};

  int lrow = lane >> 2, lcol = (lane & 3) * 8;
  // seg0: A rows [wid*16, wid*16+16); seg1: B rows [wid*16,...); seg2: B rows [64+wid*16,...)
  int ar = m0 + wid * 16 + lrow; if (ar >= M) ar = M - 1;
  const short* gA = A + (size_t)ar * lda + lcol;
  const short* gB0 = BT + (size_t)(n0 + wid * 16 + lrow) * ldb + lcol;
  const short* gB1 = BT + (size_t)(n0 + 64 + wid * 16 + lrow) * ldb + lcol;
  short* lA = &At[(wid * 16) * 32];
  short* lB0 = &Bt[(wid * 16) * 32];
  short* lB1 = &Bt[(64 + wid * 16) * 32];
  int fr = lane & 15, fo = (lane >> 4) * 8;

  for (int k0 = 0; k0 < K; k0 += 32) {
    gload16(gA + k0, lA);
    gload16(gB0 + k0, lB0);
    gload16(gB1 + k0, lB1);
    __syncthreads();
    short8 af[2], bfr[4];
#pragma unroll
    for (int mr = 0; mr < 2; mr++)
      af[mr] = *(const short8*)&At[(wr * 32 + mr * 16 + fr) * 32 + fo];
#pragma unroll
    for (int nc = 0; nc < 4; nc++)
      bfr[nc] = *(const short8*)&Bt[(wc * 64 + nc * 16 + fr) * 32 + fo];
#pragma unroll
    for (int mr = 0; mr < 2; mr++)
#pragma unroll
      for (int nc = 0; nc < 4; nc++)
        acc[mr][nc] = __builtin_amdgcn_mfma_f32_16x16x32_bf16(af[mr], bfr[nc], acc[mr][nc], 0, 0, 0);
    __syncthreads();
  }

  int rsub = (lane >> 4) * 4;
#pragma unroll
  for (int nc = 0; nc < 4; nc++) {
    int col = n0 + wc * 64 + nc * 16 + fr;
    float bv = (MODE == 3) ? 0.f : bias[col];
#pragma unroll
    for (int mr = 0; mr < 2; mr++) {
#pragma unroll
      for (int e = 0; e < 4; e++) {
        int r = m0 + wr * 32 + mr * 16 + rsub + e;
        if (r < M) {
          float v = acc[mr][nc][e] + bv;
          if (MODE == 0 || MODE == 3) {
            ((float*)p.out[z])[(size_t)r * N + col] = v;
          } else {
            float gg = 0.5f * v * (1.f + erff(v * 0.70710678118654752f));
            ((bf16*)p.out[z])[(size_t)r * N + col] = __float2bfloat16(gg);
          }
        }
      }
    }
  }
}

// ---------------- attention: block per (b,h,qchunk) ----------------
__global__ __launch_bounds__(256) void k_attn(const float* __restrict__ Q,
                                              const float* __restrict__ Kb,
                                              const float* __restrict__ Vb,
                                              const float* __restrict__ gab,
                                              bf16* __restrict__ ctx) {
  int bh = blockIdx.x;
  int qc = blockIdx.y;
  int b = bh / NH, hh = bh % NH;
  __shared__ float Kl[129][33];
  __shared__ float Vl[129][33];
  __shared__ float pl[4][132];
  int t = threadIdx.x;
  for (int idx = t; idx < 129 * 32; idx += 256) {
    int ks = idx >> 5, d = idx & 31;
    size_t src = ((size_t)(b * SQ + ks)) * DM + hh * 32 + d;
    Kl[ks][d] = Kb[src];
    Vl[ks][d] = Vb[src];
  }
  __syncthreads();
  int w = t >> 6, lane = t & 63;
  int gw = qc * 4 + w;  // 0..15
  const float scale = 0.17677669529663689f;  // 1/sqrt(32)
  for (int q = gw; q < SQ; q += 16) {
    const float* qrow = Q + ((size_t)(b * SQ + q)) * DM + hh * 32;
    float qv[32];
#pragma unroll
    for (int d = 0; d < 32; d++) qv[d] = qrow[d];
    const float* grow = gab + (((size_t)(b * NH + hh)) * SQ + q) * SQ;
    float sc0, sc1, sc2 = -1e30f;
    {
      int k = lane;
      float sa = 0.f, sb = 0.f;
#pragma unroll
      for (int d = 0; d < 16; d++) { sa += qv[d] * Kl[k][d]; sb += qv[d + 16] * Kl[k][d + 16]; }
      sc0 = (sa + sb) * scale + grow[k];
    }
    {
      int k = lane + 64;
      float sa = 0.f, sb = 0.f;
#pragma unroll
      for (int d = 0; d < 16; d++) { sa += qv[d] * Kl[k][d]; sb += qv[d + 16] * Kl[k][d + 16]; }
      sc1 = (sa + sb) * scale + grow[k];
    }
    if (lane == 0) {
      float sa = 0.f, sb = 0.f;
#pragma unroll
      for (int d = 0; d < 16; d++) { sa += qv[d] * Kl[128][d]; sb += qv[d + 16] * Kl[128][d + 16]; }
      sc2 = (sa + sb) * scale + grow[128];
    }
    float m = fmaxf(sc0, fmaxf(sc1, sc2));
#pragma unroll
    for (int o = 32; o > 0; o >>= 1) m = fmaxf(m, __shfl_xor(m, o));
    float e0 = __expf(sc0 - m), e1 = __expf(sc1 - m);
    float e2 = (lane == 0) ? __expf(sc2 - m) : 0.f;
    float sum = e0 + e1 + e2;
#pragma unroll
    for (int o = 32; o > 0; o >>= 1) sum += __shfl_xor(sum, o);
    float inv = 1.f / sum;
    pl[w][lane] = e0 * inv;
    pl[w][lane + 64] = e1 * inv;
    if (lane == 0) pl[w][128] = e2 * inv;
    asm volatile("s_waitcnt lgkmcnt(0)" ::: "memory");
    int d = lane & 31, half = lane >> 5;
    int kb = half ? 65 : 0;
    float a0 = 0.f, a1 = 0.f, a2 = 0.f, a3 = 0.f;
    for (int kk = 0; kk < 64; kk += 4) {
      a0 += pl[w][kb + kk] * Vl[kb + kk][d];
      a1 += pl[w][kb + kk + 1] * Vl[kb + kk + 1][d];
      a2 += pl[w][kb + kk + 2] * Vl[kb + kk + 2][d];
      a3 += pl[w][kb + kk + 3] * Vl[kb + kk + 3][d];
    }
    float a = (a0 + a1) + (a2 + a3);
    if (!half) a += pl[w][64] * Vl[64][d];
    a += __shfl_down(a, 32);
    if (lane < 32)
      ctx[((size_t)(b * SQ + q)) * DM + hh * 32 + d] = __float2bfloat16(a);
  }
}

// ---------------- final: h_row0 + p0 + p1 + cbias -> LN -> project ----------------
__global__ void k_final_add2(const float* __restrict__ h, const float* __restrict__ p0,
                             const float* __restrict__ p1, const float* __restrict__ cb,
                             const float* __restrict__ g, const float* __restrict__ bb,
                             const float* __restrict__ ow, const float* __restrict__ ob,
                             float* __restrict__ out) {
  int b = blockIdx.x;
  int t = threadIdx.x, lane = t & 63, wid = t >> 6;
  __shared__ float red[8];
  __shared__ float yn[768];
  size_t base = (size_t)(b * SQ) * DM;
  float v0 = h[base + t] + p0[base + t] + p1[base + t] + cb[t];
  float v1 = h[base + t + 256] + p0[base + t + 256] + p1[base + t + 256] + cb[t + 256];
  float v2 = h[base + t + 512] + p0[base + t + 512] + p1[base + t + 512] + cb[t + 512];
  float s = v0 + v1 + v2;
#pragma unroll
  for (int o = 32; o > 0; o >>= 1) s += __shfl_xor(s, o);
  if (lane == 0) red[wid] = s;
  __syncthreads();
  float mean = (red[0] + red[1] + red[2] + red[3]) * (1.f / 768.f);
  float d0 = v0 - mean, d1 = v1 - mean, d2 = v2 - mean;
  float q = d0 * d0 + d1 * d1 + d2 * d2;
#pragma unroll
  for (int o = 32; o > 0; o >>= 1) q += __shfl_xor(q, o);
  if (lane == 0) red[4 + wid] = q;
  __syncthreads();
  float var = (red[4] + red[5] + red[6] + red[7]) * (1.f / 768.f);
  float rstd = rsqrtf(var + 1e-5f);
  yn[t] = d0 * rstd * g[t] + bb[t];
  yn[t + 256] = d1 * rstd * g[t + 256] + bb[t + 256];
  yn[t + 512] = d2 * rstd * g[t + 512] + bb[t + 512];
  __syncthreads();
  if (t < 128) {
    float acc = ob[t];
    for (int d = 0; d < 768; d++) acc += yn[d] * ow[d * 128 + t];
    out[b * 128 + t] = acc;
  }
}

extern "C" void kernel_launch(void* const* d_in, const int* in_sizes, int n_in,
                              void* d_out, int out_size, void* d_ws, size_t ws_size,
                              hipStream_t stream) {
  (void)in_sizes; (void)n_in; (void)out_size;
  const int* x     = (const int*)d_in[0];
  const int* ind   = (const int*)d_in[1];
  const int* outd  = (const int*)d_in[2];
  const int* spos  = (const int*)d_in[3];
  const int* eidx  = (const int*)d_in[4];
  const float* ab   = (const float*)d_in[5];
  const float* atom = (const float*)d_in[6];
  const float* ide  = (const float*)d_in[7];
  const float* ode  = (const float*)d_in[8];
  const float* gtok = (const float*)d_in[9];
  const float* eemb = (const float*)d_in[10];
  const float* edemb= (const float*)d_in[11];
  const float* semb = (const float*)d_in[12];
  const float* virt = (const float*)d_in[13];
  const float* ln1g = (const float*)d_in[14];
  const float* ln1b = (const float*)d_in[15];
  const float* wq  = (const float*)d_in[16];
  const float* bq   = (const float*)d_in[17];
  const float* wk  = (const float*)d_in[18];
  const float* bk   = (const float*)d_in[19];
  const float* wv  = (const float*)d_in[20];
  const float* bv   = (const float*)d_in[21];
  const float* wo  = (const float*)d_in[22];
  const float* bo   = (const float*)d_in[23];
  const float* ln2g = (const float*)d_in[24];
  const float* ln2b = (const float*)d_in[25];
  const float* w1  = (const float*)d_in[26];
  const float* b1   = (const float*)d_in[27];
  const float* w2  = (const float*)d_in[28];
  const float* b2   = (const float*)d_in[29];
  const float* fg   = (const float*)d_in[30];
  const float* fb   = (const float*)d_in[31];
  const float* ow   = (const float*)d_in[32];
  const float* ob   = (const float*)d_in[33];
  float* out = (float*)d_out;

  const int DD2 = DM * DM;
  const size_t WQKVO = (size_t)DD2;       // elems per matrix
  const size_t WFF = (size_t)DM * DF;

  char* ws = (char*)d_ws;
  size_t off = 0;
  auto alloc = [&](size_t bytes) -> void* {
    void* p = ws + off;
    off += (bytes + 255) & ~(size_t)255;
    return p;
  };
  float* gab = (float*)alloc((size_t)NB * NH * SQ * SQ * 4);
  float* h   = (float*)alloc((size_t)MROWS * DM * 4);
  bf16* y    = (bf16*)alloc((size_t)MROWS * DM * 2);
  float* qb  = (float*)alloc((size_t)MROWS * DM * 4);
  float* kb2 = (float*)alloc((size_t)MROWS * DM * 4);
  float* vb2 = (float*)alloc((size_t)MROWS * DM * 4);
  bf16* ctx  = (bf16*)alloc((size_t)MROWS * DM * 2);
  bf16* t1   = (bf16*)alloc((size_t)MROWS * DF * 2);
  // p0/p1 reuse qb/kb2 (dead by the time partials are written)
  float* p0 = qb;
  float* p1 = kb2;

  size_t need_hoist = off + ((size_t)NLAY * 4 * WQKVO + 2 * (size_t)NLAY * WFF) * 2 + (1 << 20);
  bool hoist = ws_size >= need_hoist;
  short* wT  = (short*)alloc((hoist ? (size_t)NLAY * 4 * WQKVO : 4 * WQKVO) * 2);
  short* w1T = (short*)alloc((hoist ? (size_t)NLAY * WFF : WFF) * 2);
  short* w2T = (short*)alloc((hoist ? (size_t)NLAY * WFF : WFF) * 2);

  dim3 blk(256);
  k_nodefeat<<<dim3(NB * SQ), blk, 0, stream>>>(x, ind, outd, atom, ide, ode, gtok, h);
  k_gab_border<<<dim3(NB), blk, 0, stream>>>(ab, virt, gab);
  k_gab_edge<<<dim3(NB * ND * 2), blk, 0, stream>>>(spos, eidx, eemb, edemb, semb, ab, gab);

  if (hoist) {
    Ptrs4 pq; pq.p[0] = wq; pq.p[1] = wk; pq.p[2] = wv; pq.p[3] = wo;
    k_transpose<4><<<dim3(12, 12, 48), blk, 0, stream>>>(pq, wT, DM, DM, WQKVO);
    Ptrs4 pa; pa.p[0] = w1; pa.p[1] = pa.p[2] = pa.p[3] = w1;
    k_transpose<1><<<dim3(12, 48, 12), blk, 0, stream>>>(pa, w1T, DM, DF, WFF);
    Ptrs4 pb; pb.p[0] = w2; pb.p[1] = pb.p[2] = pb.p[3] = w2;
    k_transpose<1><<<dim3(48, 12, 12), blk, 0, stream>>>(pb, w2T, DF, DM, WFF);
  }

  for (int l = 0; l < NLAY; l++) {
    if (!hoist) {
      Ptrs4 pq;
      pq.p[0] = wq + (size_t)l * DD2; pq.p[1] = wk + (size_t)l * DD2;
      pq.p[2] = wv + (size_t)l * DD2; pq.p[3] = wo + (size_t)l * DD2;
      k_transpose<4><<<dim3(12, 12, 4), blk, 0, stream>>>(pq, wT, DM, DM, 0);
      Ptrs4 pa; pa.p[0] = w1 + (size_t)l * WFF; pa.p[1] = pa.p[2] = pa.p[3] = pa.p[0];
      k_transpose<1><<<dim3(12, 48, 1), blk, 0, stream>>>(pa, w1T, DM, DF, 0);
      Ptrs4 pb; pb.p[0] = w2 + (size_t)l * WFF; pb.p[1] = pb.p[2] = pb.p[3] = pb.p[0];
      k_transpose<1><<<dim3(48, 12, 1), blk, 0, stream>>>(pb, w2T, DF, DM, 0);
    }
    const short* wTl  = wT  + (hoist ? (size_t)l * 4 * WQKVO : 0);
    const short* w1Tl = w1T + (hoist ? (size_t)l * WFF : 0);
    const short* w2Tl = w2T + (hoist ? (size_t)l * WFF : 0);

    if (l == 0)
      k_ln<<<dim3(MROWS), blk, 0, stream>>>(h, ln1g, ln1b, y);
    // (for l>0, k_ln_add2 at the end of the previous iteration produced y)

    GemmPtrs gq;
    gq.bt[0] = wTl; gq.bt[1] = wTl + DD2; gq.bt[2] = wTl + 2 * DD2;
    gq.bias[0] = bq + l * DM; gq.bias[1] = bk + l * DM; gq.bias[2] = bv + l * DM;
    gq.out[0] = qb; gq.out[1] = kb2; gq.out[2] = vb2;
    gq.aoff[0] = gq.aoff[1] = gq.aoff[2] = 0;
    k_gemm64<0><<<dim3(33, 6, 3), blk, 0, stream>>>((const short*)y, gq, MROWS, DM, DM, DM, DM);

    k_attn<<<dim3(NB * NH, 4), blk, 0, stream>>>(qb, kb2, vb2, gab, ctx);

    GemmPtrs go;  // Wo split-K: K=768 -> 2 x 384
    go.bt[0] = wTl + 3 * DD2; go.bt[1] = wTl + 3 * DD2 + 384;
    go.bias[0] = go.bias[1] = nullptr;
    go.out[0] = p0; go.out[1] = p1;
    go.aoff[0] = 0; go.aoff[1] = 384;
    go.bt[2] = go.bt[0]; go.out[2] = p0; go.aoff[2] = 0; go.bias[2] = nullptr;
    k_gemm64<3><<<dim3(33, 6, 2), blk, 0, stream>>>((const short*)ctx, go, MROWS, DM, 384, DM, DM);

    k_ln_add2<<<dim3(MROWS), blk, 0, stream>>>(h, p0, p1, bo + l * DM,
                                               ln2g + l * DM, ln2b + l * DM, y);

    GemmPtrs g1;
    g1.bt[0] = g1.bt[1] = g1.bt[2] = w1Tl;
    g1.bias[0] = g1.bias[1] = g1.bias[2] = b1 + l * DF;
    g1.out[0] = g1.out[1] = g1.out[2] = t1;
    g1.aoff[0] = g1.aoff[1] = g1.aoff[2] = 0;
    k_gemm128<2><<<dim3(17, 24, 1), blk, 0, stream>>>((const short*)y, g1, MROWS, DF, DM, DM, DM);

    GemmPtrs g2;  // FFN2 split-K: K=3072 -> 2 x 1536
    g2.bt[0] = w2Tl; g2.bt[1] = w2Tl + 1536;
    g2.bias[0] = g2.bias[1] = nullptr;
    g2.out[0] = p0; g2.out[1] = p1;
    g2.aoff[0] = 0; g2.aoff[1] = 1536;
    g2.bt[2] = g2.bt[0]; g2.out[2] = p0; g2.aoff[2] = 0; g2.bias[2] = nullptr;
    k_gemm64<3><<<dim3(33, 6, 2), blk, 0, stream>>>((const short*)t1, g2, MROWS, DM, 1536, DF, DF);

    if (l < NLAY - 1) {
      k_ln_add2<<<dim3(MROWS), blk, 0, stream>>>(h, p0, p1, b2 + l * DM,
                                                 ln1g + (l + 1) * DM, ln1b + (l + 1) * DM, y);
    } else {
      k_final_add2<<<dim3(NB), blk, 0, stream>>>(h, p0, p1, b2 + l * DM, fg, fb, ow, ob, out);
    }
  }
}

// Round 4
// 2372.306 us; speedup vs baseline: 1.6401x; 1.0535x over previous
//
#include <hip/hip_runtime.h>
#include <hip/hip_bf16.h>
#include <math.h>

typedef __hip_bfloat16 bf16;
typedef __attribute__((ext_vector_type(8))) short short8;
typedef __attribute__((ext_vector_type(4))) short short4v;
typedef __attribute__((ext_vector_type(4))) float f32x4;
typedef __attribute__((ext_vector_type(2))) float f32x2;

constexpr int NB = 16;     // batch
constexpr int ND = 128;    // nodes N
constexpr int SQ = 129;    // S = N+1
constexpr int NH = 24;     // heads
constexpr int DM = 768;    // model dim
constexpr int DF = 3072;   // ffn dim
constexpr int NLAY = 12;
constexpr int MROWS = NB * SQ;  // 2064

__device__ __forceinline__ short f2bs(float f) {
  bf16 h = __float2bfloat16(f);
  return *(short*)&h;
}
__device__ __forceinline__ float bs2f(short s) {
  return __bfloat162float(*reinterpret_cast<bf16*>(&s));
}

__device__ __forceinline__ void gload16(const void* g, void* lds) {
  __builtin_amdgcn_global_load_lds(
      (const __attribute__((address_space(1))) unsigned int*)g,
      (__attribute__((address_space(3))) unsigned int*)lds, 16, 0, 0);
}

// ---------------- node features (fp32 in, fp32 out) ----------------
__global__ void k_nodefeat(const int* __restrict__ x, const int* __restrict__ ind,
                           const int* __restrict__ outd,
                           const float* __restrict__ atom, const float* __restrict__ ide,
                           const float* __restrict__ ode, const float* __restrict__ gtok,
                           float* __restrict__ h) {
  int bs = blockIdx.x;
  int b = bs / SQ, s = bs % SQ;
  int t = threadIdx.x;
  float* hrow = h + (size_t)bs * DM;
  if (s == 0) {
    for (int c = t; c < DM; c += 256) hrow[c] = gtok[c];
  } else {
    int n = s - 1;
    const int* xr = x + (b * ND + n) * 9;
    int a0 = xr[0], a1 = xr[1], a2 = xr[2], a3 = xr[3], a4 = xr[4];
    int a5 = xr[5], a6 = xr[6], a7 = xr[7], a8 = xr[8];
    int ii = ind[b * ND + n], oo = outd[b * ND + n];
    for (int c = t; c < DM; c += 256) {
      float acc = ide[(size_t)ii * DM + c] + ode[(size_t)oo * DM + c];
      acc += atom[(size_t)a0 * DM + c];
      acc += atom[(size_t)a1 * DM + c];
      acc += atom[(size_t)a2 * DM + c];
      acc += atom[(size_t)a3 * DM + c];
      acc += atom[(size_t)a4 * DM + c];
      acc += atom[(size_t)a5 * DM + c];
      acc += atom[(size_t)a6 * DM + c];
      acc += atom[(size_t)a7 * DM + c];
      acc += atom[(size_t)a8 * DM + c];
      hrow[c] = acc;
    }
  }
}

// ---------------- gab: virtual-token borders ----------------
__global__ void k_gab_border(const float* __restrict__ ab, const float* __restrict__ virt,
                             float* __restrict__ gab) {
  int b = blockIdx.x;
  const int tot = NH * SQ + NH * ND;
  for (int idx = threadIdx.x; idx < tot; idx += 256) {
    if (idx < NH * SQ) {
      int hh = idx / SQ, j = idx % SQ;
      float v = 2.f * ab[((size_t)b * SQ + 0) * SQ + j] + virt[hh];
      gab[(((size_t)b * NH + hh) * SQ + 0) * SQ + j] = v;
    } else {
      int r = idx - NH * SQ;
      int hh = r / ND, i = r % ND + 1;
      float v = 2.f * ab[((size_t)b * SQ + i) * SQ + 0] + virt[hh];
      gab[(((size_t)b * NH + hh) * SQ + i) * SQ + 0] = v;
    }
  }
}

// ---------------- gab: spatial + multihop edge bias ----------------
__global__ __launch_bounds__(256) void k_gab_edge(
    const int* __restrict__ spos, const int* __restrict__ eidx,
    const float* __restrict__ eemb, const float* __restrict__ edemb,
    const float* __restrict__ semb, const float* __restrict__ ab,
    float* __restrict__ gab) {
  __shared__ short ei2[64 * 120];  // bf16 [j][d*24+h]
  __shared__ float ed[2880];       // edge_dis_emb[:5] [d][h][k]
  int bi = blockIdx.x;
  int half = bi & 1;
  int i = (bi >> 1) & 127;
  int b = bi >> 8;
  int j0 = half * 64;
  int t = threadIdx.x;
  for (int idx = t; idx < 2880; idx += 256) ed[idx] = edemb[idx];
  const size_t rowbase = ((size_t)(b * ND + i)) * ND + j0;
  for (int idx = t; idx < 64 * 120; idx += 256) {
    int j = idx / 120, dh = idx % 120;
    int d = dh / 24, hh = dh % 24;
    const int* ep = eidx + ((rowbase + j) * 5 + d) * 3;
    float v = eemb[ep[0] * NH + hh] + eemb[ep[1] * NH + hh] + eemb[ep[2] * NH + hh];
    ei2[idx] = f2bs(v * (1.f / 3.f));
  }
  __syncthreads();
  int j = t >> 2, k0 = (t & 3) * 6;
  f32x2 acc0 = {0.f, 0.f}, acc1 = {0.f, 0.f}, acc2 = {0.f, 0.f};
  const short* er = &ei2[j * 120];
  for (int dh = 0; dh < 120; dh++) {
    float e = bs2f(er[dh]);
    const float* edr = &ed[dh * 24 + k0];
    f32x2 e0 = *(const f32x2*)(edr);
    f32x2 e1 = *(const f32x2*)(edr + 2);
    f32x2 e2 = *(const f32x2*)(edr + 4);
    acc0 += e * e0;
    acc1 += e * e1;
    acc2 += e * e2;
  }
  float accs[6] = {acc0[0], acc0[1], acc1[0], acc1[1], acc2[0], acc2[1]};
  int sp = spos[rowbase + j];
  int spc = (sp == 0) ? 1 : sp;
  spc = (spc > 1) ? spc - 1 : spc;
  if (spc > 5) spc = 5;
  float rinv = 1.f / (float)spc;
  float a2 = 2.f * ab[((size_t)b * SQ + (i + 1)) * SQ + (j0 + j + 1)];
  size_t obase = (((size_t)b * NH) * SQ + (i + 1)) * SQ + (j0 + j + 1);
#pragma unroll
  for (int u = 0; u < 6; u++) {
    int k = k0 + u;
    float v = a2 + semb[sp * NH + k] + accs[u] * rinv;
    gab[obase + (size_t)k * SQ * SQ] = v;
  }
}

// ---------------- weight transpose+cast: f32 [R,C] -> bf16 [C,R] ----------------
struct Ptrs4 { const float* p[4]; };

template <int NW>
__global__ void k_transpose(Ptrs4 ps, short* __restrict__ dst, int R, int C,
                            size_t sstride) {
  __shared__ short tile[64][68];
  int z = blockIdx.z;
  const float* src = ps.p[z % NW] + (size_t)(z / NW) * sstride;
  short* d = dst + (size_t)z * (size_t)R * C;
  int r0 = blockIdx.x * 64, c0 = blockIdx.y * 64;
  int t = threadIdx.x;
  int tr = t >> 4, tc = (t & 15) * 4;
#pragma unroll
  for (int i = 0; i < 4; i++) {
    int r = tr + i * 16;
    f32x4 v = *(const f32x4*)(src + (size_t)(r0 + r) * C + c0 + tc);
    tile[r][tc + 0] = f2bs(v[0]);
    tile[r][tc + 1] = f2bs(v[1]);
    tile[r][tc + 2] = f2bs(v[2]);
    tile[r][tc + 3] = f2bs(v[3]);
  }
  __syncthreads();
#pragma unroll
  for (int i = 0; i < 4; i++) {
    int rr = tr + i * 16;
    short4v o;
    o[0] = tile[tc + 0][rr];
    o[1] = tile[tc + 1][rr];
    o[2] = tile[tc + 2][rr];
    o[3] = tile[tc + 3][rr];
    *(short4v*)(d + (size_t)(c0 + rr) * R + r0 + tc) = o;
  }
}

// ---------------- LayerNorm: fp32 row -> bf16 row ----------------
__global__ void k_ln(const float* __restrict__ h, const float* __restrict__ g,
                     const float* __restrict__ bb, bf16* __restrict__ y) {
  int r = blockIdx.x;
  int t = threadIdx.x, lane = t & 63, wid = t >> 6;
  __shared__ float red[8];
  const float* row = h + (size_t)r * DM;
  float v0 = row[t], v1 = row[t + 256], v2 = row[t + 512];
  float s = v0 + v1 + v2;
#pragma unroll
  for (int o = 32; o > 0; o >>= 1) s += __shfl_xor(s, o);
  if (lane == 0) red[wid] = s;
  __syncthreads();
  float mean = (red[0] + red[1] + red[2] + red[3]) * (1.f / 768.f);
  float d0 = v0 - mean, d1 = v1 - mean, d2 = v2 - mean;
  float q = d0 * d0 + d1 * d1 + d2 * d2;
#pragma unroll
  for (int o = 32; o > 0; o >>= 1) q += __shfl_xor(q, o);
  if (lane == 0) red[4 + wid] = q;
  __syncthreads();
  float var = (red[4] + red[5] + red[6] + red[7]) * (1.f / 768.f);
  float rstd = rsqrtf(var + 1e-5f);
  bf16* yr = y + (size_t)r * DM;
  yr[t] = __float2bfloat16(d0 * rstd * g[t] + bb[t]);
  yr[t + 256] = __float2bfloat16(d1 * rstd * g[t + 256] + bb[t + 256]);
  yr[t + 512] = __float2bfloat16(d2 * rstd * g[t + 512] + bb[t + 512]);
}

// ---------------- fused: h += p0+p1+cbias; y = LN(h) ----------------
__global__ void k_ln_add2(float* __restrict__ h, const float* __restrict__ p0,
                          const float* __restrict__ p1, const float* __restrict__ cb,
                          const float* __restrict__ g, const float* __restrict__ bb,
                          bf16* __restrict__ y) {
  int r = blockIdx.x;
  int t = threadIdx.x, lane = t & 63, wid = t >> 6;
  __shared__ float red[8];
  size_t base = (size_t)r * DM;
  float v0 = h[base + t] + p0[base + t] + p1[base + t] + cb[t];
  float v1 = h[base + t + 256] + p0[base + t + 256] + p1[base + t + 256] + cb[t + 256];
  float v2 = h[base + t + 512] + p0[base + t + 512] + p1[base + t + 512] + cb[t + 512];
  h[base + t] = v0;
  h[base + t + 256] = v1;
  h[base + t + 512] = v2;
  float s = v0 + v1 + v2;
#pragma unroll
  for (int o = 32; o > 0; o >>= 1) s += __shfl_xor(s, o);
  if (lane == 0) red[wid] = s;
  __syncthreads();
  float mean = (red[0] + red[1] + red[2] + red[3]) * (1.f / 768.f);
  float d0 = v0 - mean, d1 = v1 - mean, d2 = v2 - mean;
  float q = d0 * d0 + d1 * d1 + d2 * d2;
#pragma unroll
  for (int o = 32; o > 0; o >>= 1) q += __shfl_xor(q, o);
  if (lane == 0) red[4 + wid] = q;
  __syncthreads();
  float var = (red[4] + red[5] + red[6] + red[7]) * (1.f / 768.f);
  float rstd = rsqrtf(var + 1e-5f);
  bf16* yr = y + base;
  yr[t] = __float2bfloat16(d0 * rstd * g[t] + bb[t]);
  yr[t + 256] = __float2bfloat16(d1 * rstd * g[t + 256] + bb[t + 256]);
  yr[t + 512] = __float2bfloat16(d2 * rstd * g[t + 512] + bb[t + 512]);
}

// ---------------- GEMM: 64x128 tile, BK=64, double-buffered, swizzled LDS ----
// MODE 0: store fp32 + bias; MODE 2: exact GELU(bias+v) -> bf16; MODE 3: raw fp32
struct GemmPtrs {
  const short* bt[3];
  const float* bias[3];
  void* out[3];
  int aoff[3];
};

template <int MODE>
__global__ __launch_bounds__(256, 3) void k_gemm64(const short* __restrict__ A, GemmPtrs p,
                                                   int M, int N, int K, int lda, int ldb) {
  __shared__ short At[2][64 * 64];
  __shared__ short Bt[2][128 * 64];
  int z = blockIdx.z;
  const short* BT = p.bt[z];
  const float* bias = p.bias[z];
  A += p.aoff[z];
  int m0 = blockIdx.x * 64, n0 = blockIdx.y * 128;
  int t = threadIdx.x, lane = t & 63, wid = t >> 6;
  int wr = wid >> 1, wc = wid & 1;
  f32x4 acc[2][4];
#pragma unroll
  for (int a = 0; a < 2; a++)
#pragma unroll
    for (int c = 0; c < 4; c++) acc[a][c] = (f32x4){0.f, 0.f, 0.f, 0.f};

  // staging: swizzled global source, linear LDS dest (rule #21)
  int lrow8 = lane >> 3;                 // 0..7
  int lseg = (lane & 7) ^ lrow8;         // source 16B-seg (swizzle)
  int arow0 = m0 + wid * 16 + lrow8;
  int arow1 = arow0 + 8;
  if (arow0 >= M) arow0 = M - 1;
  if (arow1 >= M) arow1 = M - 1;
  const short* gA0 = A + (size_t)arow0 * lda + lseg * 8;
  const short* gA1 = A + (size_t)arow1 * lda + lseg * 8;
  int brow = n0 + wid * 32 + lrow8;
  const short* gB0 = BT + (size_t)brow * ldb + lseg * 8;
  const short* gB1 = BT + (size_t)(brow + 8) * ldb + lseg * 8;
  const short* gB2 = BT + (size_t)(brow + 16) * ldb + lseg * 8;
  const short* gB3 = BT + (size_t)(brow + 24) * ldb + lseg * 8;

  const int NIT = K >> 6;
  // prologue: stage tile 0 into buf 0
  {
    short* lA = &At[0][wid * 16 * 64];
    short* lB = &Bt[0][wid * 32 * 64];
    gload16(gA0, lA);
    gload16(gA1, lA + 8 * 64);
    gload16(gB0, lB);
    gload16(gB1, lB + 8 * 64);
    gload16(gB2, lB + 16 * 64);
    gload16(gB3, lB + 24 * 64);
  }
  __syncthreads();

  int fr = lane & 15, q = lane >> 4;
  for (int it = 0; it < NIT; ++it) {
    int cur = it & 1;
    if (it + 1 < NIT) {
      int nxt = cur ^ 1;
      int k0 = (it + 1) << 6;
      short* lA = &At[nxt][wid * 16 * 64];
      short* lB = &Bt[nxt][wid * 32 * 64];
      gload16(gA0 + k0, lA);
      gload16(gA1 + k0, lA + 8 * 64);
      gload16(gB0 + k0, lB);
      gload16(gB1 + k0, lB + 8 * 64);
      gload16(gB2 + k0, lB + 16 * 64);
      gload16(gB3 + k0, lB + 24 * 64);
    }
    const short* Ab = At[cur];
    const short* Bb = Bt[cur];
    short8 af[2][2], bfr[4][2];
#pragma unroll
    for (int mr = 0; mr < 2; mr++)
#pragma unroll
      for (int kk = 0; kk < 2; kk++) {
        int row = wr * 32 + mr * 16 + fr;
        int seg = (q + kk * 4) ^ (fr & 7);
        af[mr][kk] = *(const short8*)&Ab[row * 64 + seg * 8];
      }
#pragma unroll
    for (int nc = 0; nc < 4; nc++)
#pragma unroll
      for (int kk = 0; kk < 2; kk++) {
        int row = wc * 64 + nc * 16 + fr;
        int seg = (q + kk * 4) ^ (fr & 7);
        bfr[nc][kk] = *(const short8*)&Bb[row * 64 + seg * 8];
      }
#pragma unroll
    for (int kk = 0; kk < 2; kk++)
#pragma unroll
      for (int mr = 0; mr < 2; mr++)
#pragma unroll
        for (int nc = 0; nc < 4; nc++)
          acc[mr][nc] = __builtin_amdgcn_mfma_f32_16x16x32_bf16(af[mr][kk], bfr[nc][kk],
                                                                acc[mr][nc], 0, 0, 0);
    __syncthreads();
  }

  int rsub = q * 4;
#pragma unroll
  for (int nc = 0; nc < 4; nc++) {
    int col = n0 + wc * 64 + nc * 16 + fr;
    float bv = (MODE == 3) ? 0.f : bias[col];
#pragma unroll
    for (int mr = 0; mr < 2; mr++) {
#pragma unroll
      for (int e = 0; e < 4; e++) {
        int r = m0 + wr * 32 + mr * 16 + rsub + e;
        if (r < M) {
          float v = acc[mr][nc][e] + bv;
          if (MODE == 0 || MODE == 3) {
            ((float*)p.out[z])[(size_t)r * N + col] = v;
          } else {
            float gg = 0.5f * v * (1.f + erff(v * 0.70710678118654752f));
            ((bf16*)p.out[z])[(size_t)r * N + col] = __float2bfloat16(gg);
          }
        }
      }
    }
  }
}

// ---------------- attention: block per (b,h,qchunk) ----------------
__global__ __launch_bounds__(256) void k_attn(const float* __restrict__ Q,
                                              const float* __restrict__ Kb,
                                              const float* __restrict__ Vb,
                                              const float* __restrict__ gab,
                                              bf16* __restrict__ ctx) {
  int bh = blockIdx.x;
  int qc = blockIdx.y;
  int b = bh / NH, hh = bh % NH;
  __shared__ float Kl[129][33];
  __shared__ float Vl[129][33];
  __shared__ float pl[4][132];
  int t = threadIdx.x;
  for (int idx = t; idx < 129 * 8; idx += 256) {
    int ks = idx >> 3, seg = idx & 7;
    size_t src = ((size_t)(b * SQ + ks)) * DM + hh * 32 + seg * 4;
    f32x4 kv = *(const f32x4*)&Kb[src];
    f32x4 vv = *(const f32x4*)&Vb[src];
    int dd = seg * 4;
    Kl[ks][dd] = kv[0]; Kl[ks][dd + 1] = kv[1]; Kl[ks][dd + 2] = kv[2]; Kl[ks][dd + 3] = kv[3];
    Vl[ks][dd] = vv[0]; Vl[ks][dd + 1] = vv[1]; Vl[ks][dd + 2] = vv[2]; Vl[ks][dd + 3] = vv[3];
  }
  __syncthreads();
  int w = t >> 6, lane = t & 63;
  int gw = qc * 4 + w;  // 0..15
  const float scale = 0.17677669529663689f;  // 1/sqrt(32)
  for (int q = gw; q < SQ; q += 16) {
    const float* qrow = Q + ((size_t)(b * SQ + q)) * DM + hh * 32;
    float qv[32];
#pragma unroll
    for (int d = 0; d < 32; d++) qv[d] = qrow[d];
    const float* grow = gab + (((size_t)(b * NH + hh)) * SQ + q) * SQ;
    float sc0, sc1, sc2 = -1e30f;
    {
      int k = lane;
      float sa = 0.f, sb = 0.f;
#pragma unroll
      for (int d = 0; d < 16; d++) { sa += qv[d] * Kl[k][d]; sb += qv[d + 16] * Kl[k][d + 16]; }
      sc0 = (sa + sb) * scale + grow[k];
    }
    {
      int k = lane + 64;
      float sa = 0.f, sb = 0.f;
#pragma unroll
      for (int d = 0; d < 16; d++) { sa += qv[d] * Kl[k][d]; sb += qv[d + 16] * Kl[k][d + 16]; }
      sc1 = (sa + sb) * scale + grow[k];
    }
    if (lane == 0) {
      float sa = 0.f, sb = 0.f;
#pragma unroll
      for (int d = 0; d < 16; d++) { sa += qv[d] * Kl[128][d]; sb += qv[d + 16] * Kl[128][d + 16]; }
      sc2 = (sa + sb) * scale + grow[128];
    }
    float m = fmaxf(sc0, fmaxf(sc1, sc2));
#pragma unroll
    for (int o = 32; o > 0; o >>= 1) m = fmaxf(m, __shfl_xor(m, o));
    float e0 = __expf(sc0 - m), e1 = __expf(sc1 - m);
    float e2 = (lane == 0) ? __expf(sc2 - m) : 0.f;
    float sum = e0 + e1 + e2;
#pragma unroll
    for (int o = 32; o > 0; o >>= 1) sum += __shfl_xor(sum, o);
    float inv = 1.f / sum;
    pl[w][lane] = e0 * inv;
    pl[w][lane + 64] = e1 * inv;
    if (lane == 0) pl[w][128] = e2 * inv;
    asm volatile("s_waitcnt lgkmcnt(0)" ::: "memory");
    int d = lane & 31, half = lane >> 5;
    int kb = half ? 65 : 0;
    float a0 = 0.f, a1 = 0.f, a2 = 0.f, a3 = 0.f;
    for (int kk = 0; kk < 64; kk += 4) {
      a0 += pl[w][kb + kk] * Vl[kb + kk][d];
      a1 += pl[w][kb + kk + 1] * Vl[kb + kk + 1][d];
      a2 += pl[w][kb + kk + 2] * Vl[kb + kk + 2][d];
      a3 += pl[w][kb + kk + 3] * Vl[kb + kk + 3][d];
    }
    float a = (a0 + a1) + (a2 + a3);
    if (!half) a += pl[w][64] * Vl[64][d];
    a += __shfl_down(a, 32);
    if (lane < 32)
      ctx[((size_t)(b * SQ + q)) * DM + hh * 32 + d] = __float2bfloat16(a);
  }
}

// ---------------- final: h_row0 + p0 + p1 + cbias -> LN -> project ----------------
__global__ void k_final_add2(const float* __restrict__ h, const float* __restrict__ p0,
                             const float* __restrict__ p1, const float* __restrict__ cb,
                             const float* __restrict__ g, const float* __restrict__ bb,
                             const float* __restrict__ ow, const float* __restrict__ ob,
                             float* __restrict__ out) {
  int b = blockIdx.x;
  int t = threadIdx.x, lane = t & 63, wid = t >> 6;
  __shared__ float red[8];
  __shared__ float yn[768];
  size_t base = (size_t)(b * SQ) * DM;
  float v0 = h[base + t] + p0[base + t] + p1[base + t] + cb[t];
  float v1 = h[base + t + 256] + p0[base + t + 256] + p1[base + t + 256] + cb[t + 256];
  float v2 = h[base + t + 512] + p0[base + t + 512] + p1[base + t + 512] + cb[t + 512];
  float s = v0 + v1 + v2;
#pragma unroll
  for (int o = 32; o > 0; o >>= 1) s += __shfl_xor(s, o);
  if (lane == 0) red[wid] = s;
  __syncthreads();
  float mean = (red[0] + red[1] + red[2] + red[3]) * (1.f / 768.f);
  float d0 = v0 - mean, d1 = v1 - mean, d2 = v2 - mean;
  float q = d0 * d0 + d1 * d1 + d2 * d2;
#pragma unroll
  for (int o = 32; o > 0; o >>= 1) q += __shfl_xor(q, o);
  if (lane == 0) red[4 + wid] = q;
  __syncthreads();
  float var = (red[4] + red[5] + red[6] + red[7]) * (1.f / 768.f);
  float rstd = rsqrtf(var + 1e-5f);
  yn[t] = d0 * rstd * g[t] + bb[t];
  yn[t + 256] = d1 * rstd * g[t + 256] + bb[t + 256];
  yn[t + 512] = d2 * rstd * g[t + 512] + bb[t + 512];
  __syncthreads();
  if (t < 128) {
    float acc = ob[t];
    for (int d = 0; d < 768; d++) acc += yn[d] * ow[d * 128 + t];
    out[b * 128 + t] = acc;
  }
}

extern "C" void kernel_launch(void* const* d_in, const int* in_sizes, int n_in,
                              void* d_out, int out_size, void* d_ws, size_t ws_size,
                              hipStream_t stream) {
  (void)in_sizes; (void)n_in; (void)out_size;
  const int* x     = (const int*)d_in[0];
  const int* ind   = (const int*)d_in[1];
  const int* outd  = (const int*)d_in[2];
  const int* spos  = (const int*)d_in[3];
  const int* eidx  = (const int*)d_in[4];
  const float* ab   = (const float*)d_in[5];
  const float* atom = (const float*)d_in[6];
  const float* ide  = (const float*)d_in[7];
  const float* ode  = (const float*)d_in[8];
  const float* gtok = (const float*)d_in[9];
  const float* eemb = (const float*)d_in[10];
  const float* edemb= (const float*)d_in[11];
  const float* semb = (const float*)d_in[12];
  const float* virt = (const float*)d_in[13];
  const float* ln1g = (const float*)d_in[14];
  const float* ln1b = (const float*)d_in[15];
  const float* wq  = (const float*)d_in[16];
  const float* bq   = (const float*)d_in[17];
  const float* wk  = (const float*)d_in[18];
  const float* bk   = (const float*)d_in[19];
  const float* wv  = (const float*)d_in[20];
  const float* bv   = (const float*)d_in[21];
  const float* wo  = (const float*)d_in[22];
  const float* bo   = (const float*)d_in[23];
  const float* ln2g = (const float*)d_in[24];
  const float* ln2b = (const float*)d_in[25];
  const float* w1  = (const float*)d_in[26];
  const float* b1   = (const float*)d_in[27];
  const float* w2  = (const float*)d_in[28];
  const float* b2   = (const float*)d_in[29];
  const float* fg   = (const float*)d_in[30];
  const float* fb   = (const float*)d_in[31];
  const float* ow   = (const float*)d_in[32];
  const float* ob   = (const float*)d_in[33];
  float* out = (float*)d_out;

  const int DD2 = DM * DM;
  const size_t WQKVO = (size_t)DD2;
  const size_t WFF = (size_t)DM * DF;

  char* ws = (char*)d_ws;
  size_t off = 0;
  auto alloc = [&](size_t bytes) -> void* {
    void* p = ws + off;
    off += (bytes + 255) & ~(size_t)255;
    return p;
  };
  float* gab = (float*)alloc((size_t)NB * NH * SQ * SQ * 4);
  float* h   = (float*)alloc((size_t)MROWS * DM * 4);
  bf16* y    = (bf16*)alloc((size_t)MROWS * DM * 2);
  float* qb  = (float*)alloc((size_t)MROWS * DM * 4);
  float* kb2 = (float*)alloc((size_t)MROWS * DM * 4);
  float* vb2 = (float*)alloc((size_t)MROWS * DM * 4);
  bf16* ctx  = (bf16*)alloc((size_t)MROWS * DM * 2);
  bf16* t1   = (bf16*)alloc((size_t)MROWS * DF * 2);
  float* p0 = qb;
  float* p1 = kb2;

  size_t need_hoist = off + ((size_t)NLAY * 4 * WQKVO + 2 * (size_t)NLAY * WFF) * 2 + (1 << 20);
  bool hoist = ws_size >= need_hoist;
  short* wT  = (short*)alloc((hoist ? (size_t)NLAY * 4 * WQKVO : 4 * WQKVO) * 2);
  short* w1T = (short*)alloc((hoist ? (size_t)NLAY * WFF : WFF) * 2);
  short* w2T = (short*)alloc((hoist ? (size_t)NLAY * WFF : WFF) * 2);

  dim3 blk(256);
  k_nodefeat<<<dim3(NB * SQ), blk, 0, stream>>>(x, ind, outd, atom, ide, ode, gtok, h);
  k_gab_border<<<dim3(NB), blk, 0, stream>>>(ab, virt, gab);
  k_gab_edge<<<dim3(NB * ND * 2), blk, 0, stream>>>(spos, eidx, eemb, edemb, semb, ab, gab);

  if (hoist) {
    Ptrs4 pq; pq.p[0] = wq; pq.p[1] = wk; pq.p[2] = wv; pq.p[3] = wo;
    k_transpose<4><<<dim3(12, 12, 48), blk, 0, stream>>>(pq, wT, DM, DM, WQKVO);
    Ptrs4 pa; pa.p[0] = w1; pa.p[1] = pa.p[2] = pa.p[3] = w1;
    k_transpose<1><<<dim3(12, 48, 12), blk, 0, stream>>>(pa, w1T, DM, DF, WFF);
    Ptrs4 pb; pb.p[0] = w2; pb.p[1] = pb.p[2] = pb.p[3] = w2;
    k_transpose<1><<<dim3(48, 12, 12), blk, 0, stream>>>(pb, w2T, DF, DM, WFF);
  }

  for (int l = 0; l < NLAY; l++) {
    if (!hoist) {
      Ptrs4 pq;
      pq.p[0] = wq + (size_t)l * DD2; pq.p[1] = wk + (size_t)l * DD2;
      pq.p[2] = wv + (size_t)l * DD2; pq.p[3] = wo + (size_t)l * DD2;
      k_transpose<4><<<dim3(12, 12, 4), blk, 0, stream>>>(pq, wT, DM, DM, 0);
      Ptrs4 pa; pa.p[0] = w1 + (size_t)l * WFF; pa.p[1] = pa.p[2] = pa.p[3] = pa.p[0];
      k_transpose<1><<<dim3(12, 48, 1), blk, 0, stream>>>(pa, w1T, DM, DF, 0);
      Ptrs4 pb; pb.p[0] = w2 + (size_t)l * WFF; pb.p[1] = pb.p[2] = pb.p[3] = pb.p[0];
      k_transpose<1><<<dim3(48, 12, 1), blk, 0, stream>>>(pb, w2T, DF, DM, 0);
    }
    const short* wTl  = wT  + (hoist ? (size_t)l * 4 * WQKVO : 0);
    const short* w1Tl = w1T + (hoist ? (size_t)l * WFF : 0);
    const short* w2Tl = w2T + (hoist ? (size_t)l * WFF : 0);

    if (l == 0)
      k_ln<<<dim3(MROWS), blk, 0, stream>>>(h, ln1g, ln1b, y);

    GemmPtrs gq;
    gq.bt[0] = wTl; gq.bt[1] = wTl + DD2; gq.bt[2] = wTl + 2 * DD2;
    gq.bias[0] = bq + l * DM; gq.bias[1] = bk + l * DM; gq.bias[2] = bv + l * DM;
    gq.out[0] = qb; gq.out[1] = kb2; gq.out[2] = vb2;
    gq.aoff[0] = gq.aoff[1] = gq.aoff[2] = 0;
    k_gemm64<0><<<dim3(33, 6, 3), blk, 0, stream>>>((const short*)y, gq, MROWS, DM, DM, DM, DM);

    k_attn<<<dim3(NB * NH, 4), blk, 0, stream>>>(qb, kb2, vb2, gab, ctx);

    GemmPtrs go;  // Wo split-K: K=768 -> 2 x 384
    go.bt[0] = wTl + 3 * DD2; go.bt[1] = wTl + 3 * DD2 + 384;
    go.bias[0] = go.bias[1] = nullptr;
    go.out[0] = p0; go.out[1] = p1;
    go.aoff[0] = 0; go.aoff[1] = 384;
    go.bt[2] = go.bt[0]; go.out[2] = p0; go.aoff[2] = 0; go.bias[2] = nullptr;
    k_gemm64<3><<<dim3(33, 6, 2), blk, 0, stream>>>((const short*)ctx, go, MROWS, DM, 384, DM, DM);

    k_ln_add2<<<dim3(MROWS), blk, 0, stream>>>(h, p0, p1, bo + l * DM,
                                               ln2g + l * DM, ln2b + l * DM, y);

    GemmPtrs g1;
    g1.bt[0] = g1.bt[1] = g1.bt[2] = w1Tl;
    g1.bias[0] = g1.bias[1] = g1.bias[2] = b1 + l * DF;
    g1.out[0] = g1.out[1] = g1.out[2] = t1;
    g1.aoff[0] = g1.aoff[1] = g1.aoff[2] = 0;
    k_gemm64<2><<<dim3(33, 24, 1), blk, 0, stream>>>((const short*)y, g1, MROWS, DF, DM, DM, DM);

    GemmPtrs g2;  // FFN2 split-K: K=3072 -> 2 x 1536
    g2.bt[0] = w2Tl; g2.bt[1] = w2Tl + 1536;
    g2.bias[0] = g2.bias[1] = nullptr;
    g2.out[0] = p0; g2.out[1] = p1;
    g2.aoff[0] = 0; g2.aoff[1] = 1536;
    g2.bt[2] = g2.bt[0]; g2.out[2] = p0; g2.aoff[2] = 0; g2.bias[2] = nullptr;
    k_gemm64<3><<<dim3(33, 6, 2), blk, 0, stream>>>((const short*)t1, g2, MROWS, DM, 1536, DF, DF);

    if (l < NLAY - 1) {
      k_ln_add2<<<dim3(MROWS), blk, 0, stream>>>(h, p0, p1, b2 + l * DM,
                                                 ln1g + (l + 1) * DM, ln1b + (l + 1) * DM, y);
    } else {
      k_final_add2<<<dim3(NB), blk, 0, stream>>>(h, p0, p1, b2 + l * DM, fg, fb, ow, ob, out);
    }
  }
}

// Round 5
// 2175.162 us; speedup vs baseline: 1.7887x; 1.0906x over previous
//
#include <hip/hip_runtime.h>
#include <hip/hip_bf16.h>
#include <math.h>

typedef __hip_bfloat16 bf16;
typedef __attribute__((ext_vector_type(8))) short short8;
typedef __attribute__((ext_vector_type(4))) short short4v;
typedef __attribute__((ext_vector_type(4))) float f32x4;
typedef __attribute__((ext_vector_type(2))) float f32x2;

constexpr int NB = 16;     // batch
constexpr int ND = 128;    // nodes N
constexpr int SQ = 129;    // S = N+1
constexpr int NH = 24;     // heads
constexpr int DM = 768;    // model dim
constexpr int DF = 3072;   // ffn dim
constexpr int NLAY = 12;
constexpr int MROWS = NB * SQ;  // 2064

__device__ __forceinline__ short f2bs(float f) {
  bf16 h = __float2bfloat16(f);
  return *(short*)&h;
}

__device__ __forceinline__ void gload16(const void* g, void* lds) {
  __builtin_amdgcn_global_load_lds(
      (const __attribute__((address_space(1))) unsigned int*)g,
      (__attribute__((address_space(3))) unsigned int*)lds, 16, 0, 0);
}

// ---------------- node features ----------------
__global__ void k_nodefeat(const int* __restrict__ x, const int* __restrict__ ind,
                           const int* __restrict__ outd,
                           const float* __restrict__ atom, const float* __restrict__ ide,
                           const float* __restrict__ ode, const float* __restrict__ gtok,
                           float* __restrict__ h) {
  int bs = blockIdx.x;
  int b = bs / SQ, s = bs % SQ;
  int t = threadIdx.x;
  float* hrow = h + (size_t)bs * DM;
  if (s == 0) {
    for (int c = t; c < DM; c += 256) hrow[c] = gtok[c];
  } else {
    int n = s - 1;
    const int* xr = x + (b * ND + n) * 9;
    int a0 = xr[0], a1 = xr[1], a2 = xr[2], a3 = xr[3], a4 = xr[4];
    int a5 = xr[5], a6 = xr[6], a7 = xr[7], a8 = xr[8];
    int ii = ind[b * ND + n], oo = outd[b * ND + n];
    for (int c = t; c < DM; c += 256) {
      float acc = ide[(size_t)ii * DM + c] + ode[(size_t)oo * DM + c];
      acc += atom[(size_t)a0 * DM + c];
      acc += atom[(size_t)a1 * DM + c];
      acc += atom[(size_t)a2 * DM + c];
      acc += atom[(size_t)a3 * DM + c];
      acc += atom[(size_t)a4 * DM + c];
      acc += atom[(size_t)a5 * DM + c];
      acc += atom[(size_t)a6 * DM + c];
      acc += atom[(size_t)a7 * DM + c];
      acc += atom[(size_t)a8 * DM + c];
      hrow[c] = acc;
    }
  }
}

// ---------------- gab: virtual-token borders ----------------
__global__ void k_gab_border(const float* __restrict__ ab, const float* __restrict__ virt,
                             float* __restrict__ gab) {
  int b = blockIdx.x;
  const int tot = NH * SQ + NH * ND;
  for (int idx = threadIdx.x; idx < tot; idx += 256) {
    if (idx < NH * SQ) {
      int hh = idx / SQ, j = idx % SQ;
      float v = 2.f * ab[((size_t)b * SQ + 0) * SQ + j] + virt[hh];
      gab[(((size_t)b * NH + hh) * SQ + 0) * SQ + j] = v;
    } else {
      int r = idx - NH * SQ;
      int hh = r / ND, i = r % ND + 1;
      float v = 2.f * ab[((size_t)b * SQ + i) * SQ + 0] + virt[hh];
      gab[(((size_t)b * NH + hh) * SQ + i) * SQ + 0] = v;
    }
  }
}

// ---------------- gab: spatial + multihop edge bias (MFMA) ----------------
// block = (b, i, half): A = ei[64j][128dh] bf16, B^T = edT[32k][128dh] bf16.
__global__ __launch_bounds__(256) void k_gab_edge(
    const int* __restrict__ spos, const int* __restrict__ eidx,
    const float* __restrict__ eemb, const float* __restrict__ edemb,
    const float* __restrict__ semb, const float* __restrict__ ab,
    float* __restrict__ gab) {
  __shared__ short ei2[64 * 136];  // [j][dh], pad 136
  __shared__ short edT[32 * 136];  // [k][dh], pad 136
  int bi = blockIdx.x;
  int half = bi & 1;
  int i = (bi >> 1) & 127;
  int b = bi >> 8;
  int j0 = half * 64;
  int t = threadIdx.x;
  // edT: transposed-cast edge_dis_emb[:5] -> [k][dh], zero-padded
  for (int idx = t; idx < 32 * 128; idx += 256) {
    int k = idx >> 7, dh = idx & 127;
    float v = (k < 24 && dh < 120) ? edemb[dh * 24 + k] : 0.f;
    edT[k * 136 + dh] = f2bs(v);
  }
  const size_t rowbase = ((size_t)(b * ND + i)) * ND + j0;
  for (int idx = t; idx < 64 * 120; idx += 256) {
    int j = idx / 120, dh = idx % 120;
    int d = dh / 24, hh = dh % 24;
    const int* ep = eidx + ((rowbase + j) * 5 + d) * 3;
    float v = eemb[ep[0] * NH + hh] + eemb[ep[1] * NH + hh] + eemb[ep[2] * NH + hh];
    ei2[j * 136 + dh] = f2bs(v * (1.f / 3.f));
  }
  // zero ei2 K-pad dh in [120,128)
  for (int idx = t; idx < 64 * 8; idx += 256) {
    int j = idx >> 3, dh = 120 + (idx & 7);
    ei2[j * 136 + dh] = 0;
  }
  __syncthreads();

  int lane = t & 63, w = t >> 6;
  int fr = lane & 15, q = lane >> 4, fo = q * 8;
  f32x4 acc0 = {0.f, 0.f, 0.f, 0.f}, acc1 = {0.f, 0.f, 0.f, 0.f};
#pragma unroll
  for (int kk = 0; kk < 4; kk++) {
    short8 af = *(const short8*)&ei2[(w * 16 + fr) * 136 + kk * 32 + fo];
    short8 b0 = *(const short8*)&edT[(fr) * 136 + kk * 32 + fo];
    short8 b1 = *(const short8*)&edT[(16 + fr) * 136 + kk * 32 + fo];
    acc0 = __builtin_amdgcn_mfma_f32_16x16x32_bf16(af, b0, acc0, 0, 0, 0);
    acc1 = __builtin_amdgcn_mfma_f32_16x16x32_bf16(af, b1, acc1, 0, 0, 0);
  }
  // epilogue: C row = j_local = q*4+e, col = k = fr (+16)
#pragma unroll
  for (int e = 0; e < 4; e++) {
    int j = w * 16 + q * 4 + e;
    int sp = spos[rowbase + j];
    int spc = (sp == 0) ? 1 : sp;
    spc = (spc > 1) ? spc - 1 : spc;
    if (spc > 5) spc = 5;
    float rinv = 1.f / (float)spc;
    float a2 = 2.f * ab[((size_t)b * SQ + (i + 1)) * SQ + (j0 + j + 1)];
    size_t obase = (((size_t)b * NH) * SQ + (i + 1)) * SQ + (j0 + j + 1);
    {
      int k = fr;
      float v = a2 + semb[sp * NH + k] + acc0[e] * rinv;
      gab[obase + (size_t)k * SQ * SQ] = v;
    }
    if (fr < 8) {
      int k = 16 + fr;
      float v = a2 + semb[sp * NH + k] + acc1[e] * rinv;
      gab[obase + (size_t)k * SQ * SQ] = v;
    }
  }
}

// ---------------- weight transpose+cast: f32 [R,C] -> bf16 [C,R] ----------------
struct Ptrs4 { const float* p[4]; };

template <int NW>
__global__ void k_transpose(Ptrs4 ps, short* __restrict__ dst, int R, int C,
                            size_t sstride) {
  __shared__ short tile[64][68];
  int z = blockIdx.z;
  const float* src = ps.p[z % NW] + (size_t)(z / NW) * sstride;
  short* d = dst + (size_t)z * (size_t)R * C;
  int r0 = blockIdx.x * 64, c0 = blockIdx.y * 64;
  int t = threadIdx.x;
  int tr = t >> 4, tc = (t & 15) * 4;
#pragma unroll
  for (int i = 0; i < 4; i++) {
    int r = tr + i * 16;
    f32x4 v = *(const f32x4*)(src + (size_t)(r0 + r) * C + c0 + tc);
    tile[r][tc + 0] = f2bs(v[0]);
    tile[r][tc + 1] = f2bs(v[1]);
    tile[r][tc + 2] = f2bs(v[2]);
    tile[r][tc + 3] = f2bs(v[3]);
  }
  __syncthreads();
#pragma unroll
  for (int i = 0; i < 4; i++) {
    int rr = tr + i * 16;
    short4v o;
    o[0] = tile[tc + 0][rr];
    o[1] = tile[tc + 1][rr];
    o[2] = tile[tc + 2][rr];
    o[3] = tile[tc + 3][rr];
    *(short4v*)(d + (size_t)(c0 + rr) * R + r0 + tc) = o;
  }
}

// ---------------- LayerNorm: fp32 row -> bf16 row ----------------
__global__ void k_ln(const float* __restrict__ h, const float* __restrict__ g,
                     const float* __restrict__ bb, bf16* __restrict__ y) {
  int r = blockIdx.x;
  int t = threadIdx.x, lane = t & 63, wid = t >> 6;
  __shared__ float red[8];
  const float* row = h + (size_t)r * DM;
  float v0 = row[t], v1 = row[t + 256], v2 = row[t + 512];
  float s = v0 + v1 + v2;
#pragma unroll
  for (int o = 32; o > 0; o >>= 1) s += __shfl_xor(s, o);
  if (lane == 0) red[wid] = s;
  __syncthreads();
  float mean = (red[0] + red[1] + red[2] + red[3]) * (1.f / 768.f);
  float d0 = v0 - mean, d1 = v1 - mean, d2 = v2 - mean;
  float q = d0 * d0 + d1 * d1 + d2 * d2;
#pragma unroll
  for (int o = 32; o > 0; o >>= 1) q += __shfl_xor(q, o);
  if (lane == 0) red[4 + wid] = q;
  __syncthreads();
  float var = (red[4] + red[5] + red[6] + red[7]) * (1.f / 768.f);
  float rstd = rsqrtf(var + 1e-5f);
  bf16* yr = y + (size_t)r * DM;
  yr[t] = __float2bfloat16(d0 * rstd * g[t] + bb[t]);
  yr[t + 256] = __float2bfloat16(d1 * rstd * g[t + 256] + bb[t + 256]);
  yr[t + 512] = __float2bfloat16(d2 * rstd * g[t + 512] + bb[t + 512]);
}

// ---------------- fused: h += p0+p1+cbias; y = LN(h) ----------------
__global__ void k_ln_add2(float* __restrict__ h, const float* __restrict__ p0,
                          const float* __restrict__ p1, const float* __restrict__ cb,
                          const float* __restrict__ g, const float* __restrict__ bb,
                          bf16* __restrict__ y) {
  int r = blockIdx.x;
  int t = threadIdx.x, lane = t & 63, wid = t >> 6;
  __shared__ float red[8];
  size_t base = (size_t)r * DM;
  float v0 = h[base + t] + p0[base + t] + p1[base + t] + cb[t];
  float v1 = h[base + t + 256] + p0[base + t + 256] + p1[base + t + 256] + cb[t + 256];
  float v2 = h[base + t + 512] + p0[base + t + 512] + p1[base + t + 512] + cb[t + 512];
  h[base + t] = v0;
  h[base + t + 256] = v1;
  h[base + t + 512] = v2;
  float s = v0 + v1 + v2;
#pragma unroll
  for (int o = 32; o > 0; o >>= 1) s += __shfl_xor(s, o);
  if (lane == 0) red[wid] = s;
  __syncthreads();
  float mean = (red[0] + red[1] + red[2] + red[3]) * (1.f / 768.f);
  float d0 = v0 - mean, d1 = v1 - mean, d2 = v2 - mean;
  float q = d0 * d0 + d1 * d1 + d2 * d2;
#pragma unroll
  for (int o = 32; o > 0; o >>= 1) q += __shfl_xor(q, o);
  if (lane == 0) red[4 + wid] = q;
  __syncthreads();
  float var = (red[4] + red[5] + red[6] + red[7]) * (1.f / 768.f);
  float rstd = rsqrtf(var + 1e-5f);
  bf16* yr = y + base;
  yr[t] = __float2bfloat16(d0 * rstd * g[t] + bb[t]);
  yr[t + 256] = __float2bfloat16(d1 * rstd * g[t + 256] + bb[t + 256]);
  yr[t + 512] = __float2bfloat16(d2 * rstd * g[t + 512] + bb[t + 512]);
}

// ---------------- GEMM: 128x128 block, 4 waves x 64x64, BK=64, dbuf, swizzle ----
// MODE 0: fp32 + bias; MODE 2: exact GELU(bias+v) -> bf16; MODE 3: raw fp32
struct GemmPtrs {
  const short* bt[3];
  const float* bias[3];
  void* out[3];
  int aoff[3];
};

template <int MODE>
__global__ __launch_bounds__(256, 2) void k_gemm128(const short* __restrict__ A, GemmPtrs p,
                                                    int M, int N, int K, int lda, int ldb) {
  __shared__ short At[2][128 * 64];
  __shared__ short Bt[2][128 * 64];
  int z = blockIdx.z;
  const short* BT = p.bt[z];
  const float* bias = p.bias[z];
  A += p.aoff[z];
  int m0 = blockIdx.x * 128, n0 = blockIdx.y * 128;
  int t = threadIdx.x, lane = t & 63, wid = t >> 6;
  int wr = wid >> 1, wc = wid & 1;
  f32x4 acc[4][4];
#pragma unroll
  for (int a = 0; a < 4; a++)
#pragma unroll
    for (int c = 0; c < 4; c++) acc[a][c] = (f32x4){0.f, 0.f, 0.f, 0.f};

  int lrow8 = lane >> 3;
  int lseg = (lane & 7) ^ lrow8;  // pre-swizzled global source seg
  const short* gA[4];
  const short* gB[4];
#pragma unroll
  for (int i = 0; i < 4; i++) {
    int ar = m0 + wid * 32 + i * 8 + lrow8;
    if (ar >= M) ar = M - 1;
    gA[i] = A + (size_t)ar * lda + lseg * 8;
    int br = n0 + wid * 32 + i * 8 + lrow8;
    gB[i] = BT + (size_t)br * ldb + lseg * 8;
  }

  const int NIT = K >> 6;
#pragma unroll
  for (int i = 0; i < 4; i++) {
    gload16(gA[i], &At[0][(wid * 32 + i * 8) * 64]);
    gload16(gB[i], &Bt[0][(wid * 32 + i * 8) * 64]);
  }
  __syncthreads();

  int fr = lane & 15, q = lane >> 4;
  for (int it = 0; it < NIT; ++it) {
    int cur = it & 1;
    if (it + 1 < NIT) {
      int nxt = cur ^ 1;
      int k0 = (it + 1) << 6;
#pragma unroll
      for (int i = 0; i < 4; i++) {
        gload16(gA[i] + k0, &At[nxt][(wid * 32 + i * 8) * 64]);
        gload16(gB[i] + k0, &Bt[nxt][(wid * 32 + i * 8) * 64]);
      }
    }
    const short* Ab = At[cur];
    const short* Bb = Bt[cur];
#pragma unroll
    for (int kk = 0; kk < 2; kk++) {
      int sg = ((q + kk * 4) ^ (fr & 7)) * 8;
      short8 af[4], bf[4];
#pragma unroll
      for (int mr = 0; mr < 4; mr++)
        af[mr] = *(const short8*)&Ab[(wr * 64 + mr * 16 + fr) * 64 + sg];
#pragma unroll
      for (int nc = 0; nc < 4; nc++)
        bf[nc] = *(const short8*)&Bb[(wc * 64 + nc * 16 + fr) * 64 + sg];
#pragma unroll
      for (int mr = 0; mr < 4; mr++)
#pragma unroll
        for (int nc = 0; nc < 4; nc++)
          acc[mr][nc] = __builtin_amdgcn_mfma_f32_16x16x32_bf16(af[mr], bf[nc], acc[mr][nc], 0, 0, 0);
    }
    __syncthreads();
  }

  int rsub = q * 4;
#pragma unroll
  for (int nc = 0; nc < 4; nc++) {
    int col = n0 + wc * 64 + nc * 16 + fr;
    float bv = (MODE == 3) ? 0.f : bias[col];
#pragma unroll
    for (int mr = 0; mr < 4; mr++) {
#pragma unroll
      for (int e = 0; e < 4; e++) {
        int r = m0 + wr * 64 + mr * 16 + rsub + e;
        if (r < M) {
          float v = acc[mr][nc][e] + bv;
          if (MODE == 0 || MODE == 3) {
            ((float*)p.out[z])[(size_t)r * N + col] = v;
          } else {
            float gg = 0.5f * v * (1.f + erff(v * 0.70710678118654752f));
            ((bf16*)p.out[z])[(size_t)r * N + col] = __float2bfloat16(gg);
          }
        }
      }
    }
  }
}

// ---------------- attention: block per (b,h,qchunk) ----------------
__global__ __launch_bounds__(256) void k_attn(const float* __restrict__ Q,
                                              const float* __restrict__ Kb,
                                              const float* __restrict__ Vb,
                                              const float* __restrict__ gab,
                                              bf16* __restrict__ ctx) {
  int bh = blockIdx.x;
  int qc = blockIdx.y;
  int b = bh / NH, hh = bh % NH;
  __shared__ float Kl[129][36];
  __shared__ float Vl[129][36];
  __shared__ float pl[4][132];
  int t = threadIdx.x;
  for (int idx = t; idx < 129 * 8; idx += 256) {
    int ks = idx >> 3, seg = idx & 7;
    size_t src = ((size_t)(b * SQ + ks)) * DM + hh * 32 + seg * 4;
    *(f32x4*)&Kl[ks][seg * 4] = *(const f32x4*)&Kb[src];
    *(f32x4*)&Vl[ks][seg * 4] = *(const f32x4*)&Vb[src];
  }
  __syncthreads();
  int w = t >> 6, lane = t & 63;
  int gw = qc * 4 + w;  // 0..15
  const float scale = 0.17677669529663689f;  // 1/sqrt(32)
  int d4 = (lane & 7) * 4, kg = lane >> 3;
  for (int q = gw; q < SQ; q += 16) {
    const float* qrow = Q + ((size_t)(b * SQ + q)) * DM + hh * 32;
    f32x4 qv[8];
#pragma unroll
    for (int dq = 0; dq < 8; dq++) qv[dq] = *(const f32x4*)&qrow[dq * 4];
    const float* grow = gab + (((size_t)(b * NH + hh)) * SQ + q) * SQ;
    float sc0, sc1, sc2 = -1e30f;
    {
      f32x4 s4 = {0.f, 0.f, 0.f, 0.f};
#pragma unroll
      for (int dq = 0; dq < 8; dq++) s4 += qv[dq] * *(const f32x4*)&Kl[lane][dq * 4];
      sc0 = (s4[0] + s4[1] + s4[2] + s4[3]) * scale + grow[lane];
    }
    {
      f32x4 s4 = {0.f, 0.f, 0.f, 0.f};
#pragma unroll
      for (int dq = 0; dq < 8; dq++) s4 += qv[dq] * *(const f32x4*)&Kl[lane + 64][dq * 4];
      sc1 = (s4[0] + s4[1] + s4[2] + s4[3]) * scale + grow[lane + 64];
    }
    if (lane == 0) {
      f32x4 s4 = {0.f, 0.f, 0.f, 0.f};
#pragma unroll
      for (int dq = 0; dq < 8; dq++) s4 += qv[dq] * *(const f32x4*)&Kl[128][dq * 4];
      sc2 = (s4[0] + s4[1] + s4[2] + s4[3]) * scale + grow[128];
    }
    float m = fmaxf(sc0, fmaxf(sc1, sc2));
#pragma unroll
    for (int o = 32; o > 0; o >>= 1) m = fmaxf(m, __shfl_xor(m, o));
    float e0 = __expf(sc0 - m), e1 = __expf(sc1 - m);
    float e2 = (lane == 0) ? __expf(sc2 - m) : 0.f;
    float sum = e0 + e1 + e2;
#pragma unroll
    for (int o = 32; o > 0; o >>= 1) sum += __shfl_xor(sum, o);
    float inv = 1.f / sum;
    pl[w][lane] = e0 * inv;
    pl[w][lane + 64] = e1 * inv;
    if (lane == 0) pl[w][128] = e2 * inv;
    asm volatile("s_waitcnt lgkmcnt(0)" ::: "memory");
    // PV: lane = (kg, d4); accumulate 16 k's then reduce over kg
    f32x4 a4 = {0.f, 0.f, 0.f, 0.f};
    int kbase = kg * 16;
#pragma unroll
    for (int i = 0; i < 16; i++) {
      float pp = pl[w][kbase + i];
      a4 += pp * *(const f32x4*)&Vl[kbase + i][d4];
    }
#pragma unroll
    for (int off = 8; off < 64; off <<= 1) {
      a4[0] += __shfl_xor(a4[0], off);
      a4[1] += __shfl_xor(a4[1], off);
      a4[2] += __shfl_xor(a4[2], off);
      a4[3] += __shfl_xor(a4[3], off);
    }
    if (lane < 8) {
      f32x4 vt = *(const f32x4*)&Vl[128][d4];
      float p128 = pl[w][128];
      a4 += p128 * vt;
      bf16* crow = ctx + ((size_t)(b * SQ + q)) * DM + hh * 32 + d4;
      crow[0] = __float2bfloat16(a4[0]);
      crow[1] = __float2bfloat16(a4[1]);
      crow[2] = __float2bfloat16(a4[2]);
      crow[3] = __float2bfloat16(a4[3]);
    }
  }
}

// ---------------- final: h_row0 + p0 + p1 + cbias -> LN -> project ----------------
__global__ void k_final_add2(const float* __restrict__ h, const float* __restrict__ p0,
                             const float* __restrict__ p1, const float* __restrict__ cb,
                             const float* __restrict__ g, const float* __restrict__ bb,
                             const float* __restrict__ ow, const float* __restrict__ ob,
                             float* __restrict__ out) {
  int b = blockIdx.x;
  int t = threadIdx.x, lane = t & 63, wid = t >> 6;
  __shared__ float red[8];
  __shared__ float yn[768];
  size_t base = (size_t)(b * SQ) * DM;
  float v0 = h[base + t] + p0[base + t] + p1[base + t] + cb[t];
  float v1 = h[base + t + 256] + p0[base + t + 256] + p1[base + t + 256] + cb[t + 256];
  float v2 = h[base + t + 512] + p0[base + t + 512] + p1[base + t + 512] + cb[t + 512];
  float s = v0 + v1 + v2;
#pragma unroll
  for (int o = 32; o > 0; o >>= 1) s += __shfl_xor(s, o);
  if (lane == 0) red[wid] = s;
  __syncthreads();
  float mean = (red[0] + red[1] + red[2] + red[3]) * (1.f / 768.f);
  float d0 = v0 - mean, d1 = v1 - mean, d2 = v2 - mean;
  float q = d0 * d0 + d1 * d1 + d2 * d2;
#pragma unroll
  for (int o = 32; o > 0; o >>= 1) q += __shfl_xor(q, o);
  if (lane == 0) red[4 + wid] = q;
  __syncthreads();
  float var = (red[4] + red[5] + red[6] + red[7]) * (1.f / 768.f);
  float rstd = rsqrtf(var + 1e-5f);
  yn[t] = d0 * rstd * g[t] + bb[t];
  yn[t + 256] = d1 * rstd * g[t + 256] + bb[t + 256];
  yn[t + 512] = d2 * rstd * g[t + 512] + bb[t + 512];
  __syncthreads();
  if (t < 128) {
    float acc = ob[t];
    for (int d = 0; d < 768; d++) acc += yn[d] * ow[d * 128 + t];
    out[b * 128 + t] = acc;
  }
}

extern "C" void kernel_launch(void* const* d_in, const int* in_sizes, int n_in,
                              void* d_out, int out_size, void* d_ws, size_t ws_size,
                              hipStream_t stream) {
  (void)in_sizes; (void)n_in; (void)out_size;
  const int* x     = (const int*)d_in[0];
  const int* ind   = (const int*)d_in[1];
  const int* outd  = (const int*)d_in[2];
  const int* spos  = (const int*)d_in[3];
  const int* eidx  = (const int*)d_in[4];
  const float* ab   = (const float*)d_in[5];
  const float* atom = (const float*)d_in[6];
  const float* ide  = (const float*)d_in[7];
  const float* ode  = (const float*)d_in[8];
  const float* gtok = (const float*)d_in[9];
  const float* eemb = (const float*)d_in[10];
  const float* edemb= (const float*)d_in[11];
  const float* semb = (const float*)d_in[12];
  const float* virt = (const float*)d_in[13];
  const float* ln1g = (const float*)d_in[14];
  const float* ln1b = (const float*)d_in[15];
  const float* wq  = (const float*)d_in[16];
  const float* bq   = (const float*)d_in[17];
  const float* wk  = (const float*)d_in[18];
  const float* bk   = (const float*)d_in[19];
  const float* wv  = (const float*)d_in[20];
  const float* bv   = (const float*)d_in[21];
  const float* wo  = (const float*)d_in[22];
  const float* bo   = (const float*)d_in[23];
  const float* ln2g = (const float*)d_in[24];
  const float* ln2b = (const float*)d_in[25];
  const float* w1  = (const float*)d_in[26];
  const float* b1   = (const float*)d_in[27];
  const float* w2  = (const float*)d_in[28];
  const float* b2   = (const float*)d_in[29];
  const float* fg   = (const float*)d_in[30];
  const float* fb   = (const float*)d_in[31];
  const float* ow   = (const float*)d_in[32];
  const float* ob   = (const float*)d_in[33];
  float* out = (float*)d_out;

  const int DD2 = DM * DM;
  const size_t WQKVO = (size_t)DD2;
  const size_t WFF = (size_t)DM * DF;

  char* ws = (char*)d_ws;
  size_t off = 0;
  auto alloc = [&](size_t bytes) -> void* {
    void* p = ws + off;
    off += (bytes + 255) & ~(size_t)255;
    return p;
  };
  float* gab = (float*)alloc((size_t)NB * NH * SQ * SQ * 4);
  float* h   = (float*)alloc((size_t)MROWS * DM * 4);
  bf16* y    = (bf16*)alloc((size_t)MROWS * DM * 2);
  float* qb  = (float*)alloc((size_t)MROWS * DM * 4);
  float* kb2 = (float*)alloc((size_t)MROWS * DM * 4);
  float* vb2 = (float*)alloc((size_t)MROWS * DM * 4);
  bf16* ctx  = (bf16*)alloc((size_t)MROWS * DM * 2);
  bf16* t1   = (bf16*)alloc((size_t)MROWS * DF * 2);
  float* p0 = qb;
  float* p1 = kb2;

  size_t need_hoist = off + ((size_t)NLAY * 4 * WQKVO + 2 * (size_t)NLAY * WFF) * 2 + (1 << 20);
  bool hoist = ws_size >= need_hoist;
  short* wT  = (short*)alloc((hoist ? (size_t)NLAY * 4 * WQKVO : 4 * WQKVO) * 2);
  short* w1T = (short*)alloc((hoist ? (size_t)NLAY * WFF : WFF) * 2);
  short* w2T = (short*)alloc((hoist ? (size_t)NLAY * WFF : WFF) * 2);

  dim3 blk(256);
  k_nodefeat<<<dim3(NB * SQ), blk, 0, stream>>>(x, ind, outd, atom, ide, ode, gtok, h);
  k_gab_border<<<dim3(NB), blk, 0, stream>>>(ab, virt, gab);
  k_gab_edge<<<dim3(NB * ND * 2), blk, 0, stream>>>(spos, eidx, eemb, edemb, semb, ab, gab);

  if (hoist) {
    Ptrs4 pq; pq.p[0] = wq; pq.p[1] = wk; pq.p[2] = wv; pq.p[3] = wo;
    k_transpose<4><<<dim3(12, 12, 48), blk, 0, stream>>>(pq, wT, DM, DM, WQKVO);
    Ptrs4 pa; pa.p[0] = w1; pa.p[1] = pa.p[2] = pa.p[3] = w1;
    k_transpose<1><<<dim3(12, 48, 12), blk, 0, stream>>>(pa, w1T, DM, DF, WFF);
    Ptrs4 pb; pb.p[0] = w2; pb.p[1] = pb.p[2] = pb.p[3] = w2;
    k_transpose<1><<<dim3(48, 12, 12), blk, 0, stream>>>(pb, w2T, DF, DM, WFF);
  }

  for (int l = 0; l < NLAY; l++) {
    if (!hoist) {
      Ptrs4 pq;
      pq.p[0] = wq + (size_t)l * DD2; pq.p[1] = wk + (size_t)l * DD2;
      pq.p[2] = wv + (size_t)l * DD2; pq.p[3] = wo + (size_t)l * DD2;
      k_transpose<4><<<dim3(12, 12, 4), blk, 0, stream>>>(pq, wT, DM, DM, 0);
      Ptrs4 pa; pa.p[0] = w1 + (size_t)l * WFF; pa.p[1] = pa.p[2] = pa.p[3] = pa.p[0];
      k_transpose<1><<<dim3(12, 48, 1), blk, 0, stream>>>(pa, w1T, DM, DF, 0);
      Ptrs4 pb; pb.p[0] = w2 + (size_t)l * WFF; pb.p[1] = pb.p[2] = pb.p[3] = pb.p[0];
      k_transpose<1><<<dim3(48, 12, 1), blk, 0, stream>>>(pb, w2T, DF, DM, 0);
    }
    const short* wTl  = wT  + (hoist ? (size_t)l * 4 * WQKVO : 0);
    const short* w1Tl = w1T + (hoist ? (size_t)l * WFF : 0);
    const short* w2Tl = w2T + (hoist ? (size_t)l * WFF : 0);

    if (l == 0)
      k_ln<<<dim3(MROWS), blk, 0, stream>>>(h, ln1g, ln1b, y);

    GemmPtrs gq;
    gq.bt[0] = wTl; gq.bt[1] = wTl + DD2; gq.bt[2] = wTl + 2 * DD2;
    gq.bias[0] = bq + l * DM; gq.bias[1] = bk + l * DM; gq.bias[2] = bv + l * DM;
    gq.out[0] = qb; gq.out[1] = kb2; gq.out[2] = vb2;
    gq.aoff[0] = gq.aoff[1] = gq.aoff[2] = 0;
    k_gemm128<0><<<dim3(17, 6, 3), blk, 0, stream>>>((const short*)y, gq, MROWS, DM, DM, DM, DM);

    k_attn<<<dim3(NB * NH, 4), blk, 0, stream>>>(qb, kb2, vb2, gab, ctx);

    GemmPtrs go;  // Wo split-K: K=768 -> 2 x 384
    go.bt[0] = wTl + 3 * DD2; go.bt[1] = wTl + 3 * DD2 + 384;
    go.bias[0] = go.bias[1] = nullptr;
    go.out[0] = p0; go.out[1] = p1;
    go.aoff[0] = 0; go.aoff[1] = 384;
    go.bt[2] = go.bt[0]; go.out[2] = p0; go.aoff[2] = 0; go.bias[2] = nullptr;
    k_gemm128<3><<<dim3(17, 6, 2), blk, 0, stream>>>((const short*)ctx, go, MROWS, DM, 384, DM, DM);

    k_ln_add2<<<dim3(MROWS), blk, 0, stream>>>(h, p0, p1, bo + l * DM,
                                               ln2g + l * DM, ln2b + l * DM, y);

    GemmPtrs g1;
    g1.bt[0] = g1.bt[1] = g1.bt[2] = w1Tl;
    g1.bias[0] = g1.bias[1] = g1.bias[2] = b1 + l * DF;
    g1.out[0] = g1.out[1] = g1.out[2] = t1;
    g1.aoff[0] = g1.aoff[1] = g1.aoff[2] = 0;
    k_gemm128<2><<<dim3(17, 24, 1), blk, 0, stream>>>((const short*)y, g1, MROWS, DF, DM, DM, DM);

    GemmPtrs g2;  // FFN2 split-K: K=3072 -> 2 x 1536
    g2.bt[0] = w2Tl; g2.bt[1] = w2Tl + 1536;
    g2.bias[0] = g2.bias[1] = nullptr;
    g2.out[0] = p0; g2.out[1] = p1;
    g2.aoff[0] = 0; g2.aoff[1] = 1536;
    g2.bt[2] = g2.bt[0]; g2.out[2] = p0; g2.aoff[2] = 0; g2.bias[2] = nullptr;
    k_gemm128<3><<<dim3(17, 6, 2), blk, 0, stream>>>((const short*)t1, g2, MROWS, DM, 1536, DF, DF);

    if (l < NLAY - 1) {
      k_ln_add2<<<dim3(MROWS), blk, 0, stream>>>(h, p0, p1, b2 + l * DM,
                                                 ln1g + (l + 1) * DM, ln1b + (l + 1) * DM, y);
    } else {
      k_final_add2<<<dim3(NB), blk, 0, stream>>>(h, p0, p1, b2 + l * DM, fg, fb, ow, ob, out);
    }
  }
}

// Round 6
// 2099.409 us; speedup vs baseline: 1.8533x; 1.0361x over previous
//
#include <hip/hip_runtime.h>
#include <hip/hip_bf16.h>
#include <math.h>

typedef __hip_bfloat16 bf16;
typedef __attribute__((ext_vector_type(8))) short short8;
typedef __attribute__((ext_vector_type(4))) short short4v;
typedef __attribute__((ext_vector_type(4))) float f32x4;

constexpr int NB = 16;     // batch
constexpr int ND = 128;    // nodes N
constexpr int SQ = 129;    // S = N+1
constexpr int NH = 24;     // heads
constexpr int DM = 768;    // model dim
constexpr int DF = 3072;   // ffn dim
constexpr int NLAY = 12;
constexpr int MROWS = NB * SQ;  // 2064

__device__ __forceinline__ short f2bs(float f) {
  bf16 h = __float2bfloat16(f);
  return *(short*)&h;
}

__device__ __forceinline__ void gload16(const void* g, void* lds) {
  __builtin_amdgcn_global_load_lds(
      (const __attribute__((address_space(1))) unsigned int*)g,
      (__attribute__((address_space(3))) unsigned int*)lds, 16, 0, 0);
}

// ---------------- node features ----------------
__global__ void k_nodefeat(const int* __restrict__ x, const int* __restrict__ ind,
                           const int* __restrict__ outd,
                           const float* __restrict__ atom, const float* __restrict__ ide,
                           const float* __restrict__ ode, const float* __restrict__ gtok,
                           float* __restrict__ h) {
  int bs = blockIdx.x;
  int b = bs / SQ, s = bs % SQ;
  int t = threadIdx.x;
  float* hrow = h + (size_t)bs * DM;
  if (s == 0) {
    for (int c = t; c < DM; c += 256) hrow[c] = gtok[c];
  } else {
    int n = s - 1;
    const int* xr = x + (b * ND + n) * 9;
    int a0 = xr[0], a1 = xr[1], a2 = xr[2], a3 = xr[3], a4 = xr[4];
    int a5 = xr[5], a6 = xr[6], a7 = xr[7], a8 = xr[8];
    int ii = ind[b * ND + n], oo = outd[b * ND + n];
    for (int c = t; c < DM; c += 256) {
      float acc = ide[(size_t)ii * DM + c] + ode[(size_t)oo * DM + c];
      acc += atom[(size_t)a0 * DM + c];
      acc += atom[(size_t)a1 * DM + c];
      acc += atom[(size_t)a2 * DM + c];
      acc += atom[(size_t)a3 * DM + c];
      acc += atom[(size_t)a4 * DM + c];
      acc += atom[(size_t)a5 * DM + c];
      acc += atom[(size_t)a6 * DM + c];
      acc += atom[(size_t)a7 * DM + c];
      acc += atom[(size_t)a8 * DM + c];
      hrow[c] = acc;
    }
  }
}

// ---------------- gab: virtual-token borders ----------------
__global__ void k_gab_border(const float* __restrict__ ab, const float* __restrict__ virt,
                             float* __restrict__ gab) {
  int b = blockIdx.x;
  const int tot = NH * SQ + NH * ND;
  for (int idx = threadIdx.x; idx < tot; idx += 256) {
    if (idx < NH * SQ) {
      int hh = idx / SQ, j = idx % SQ;
      float v = 2.f * ab[((size_t)b * SQ + 0) * SQ + j] + virt[hh];
      gab[(((size_t)b * NH + hh) * SQ + 0) * SQ + j] = v;
    } else {
      int r = idx - NH * SQ;
      int hh = r / ND, i = r % ND + 1;
      float v = 2.f * ab[((size_t)b * SQ + i) * SQ + 0] + virt[hh];
      gab[(((size_t)b * NH + hh) * SQ + i) * SQ + 0] = v;
    }
  }
}

// ---------------- gab: spatial + multihop edge bias (MFMA) ----------------
__global__ __launch_bounds__(256) void k_gab_edge(
    const int* __restrict__ spos, const int* __restrict__ eidx,
    const float* __restrict__ eemb, const float* __restrict__ edemb,
    const float* __restrict__ semb, const float* __restrict__ ab,
    float* __restrict__ gab) {
  __shared__ int eidxs[960];       // 64 j x 5 d x 3 f
  __shared__ short ei2[64 * 136];  // bf16 [j][dh]
  __shared__ short edT[32 * 136];  // bf16 [k][dh]
  int bi = blockIdx.x;
  int half = bi & 1;
  int i = (bi >> 1) & 127;
  int b = bi >> 8;
  int j0 = half * 64;
  int t = threadIdx.x;
  const size_t rowbase = ((size_t)(b * ND + i)) * ND + j0;

  // stage eidx coalesced (j-contiguous)
  const int* esrc = eidx + rowbase * 15;
  for (int idx = t; idx < 960; idx += 256) eidxs[idx] = esrc[idx];
  // edT build: vectorized over k
  for (int u = t; u < 720; u += 256) {
    int dh = u / 6, kq = u % 6;
    f32x4 v = *(const f32x4*)&edemb[dh * 24 + kq * 4];
    edT[(kq * 4 + 0) * 136 + dh] = f2bs(v[0]);
    edT[(kq * 4 + 1) * 136 + dh] = f2bs(v[1]);
    edT[(kq * 4 + 2) * 136 + dh] = f2bs(v[2]);
    edT[(kq * 4 + 3) * 136 + dh] = f2bs(v[3]);
  }
  // edT pad zeros: k<24 dh in [120,136); k in [24,32) all dh
  for (int u = t; u < 1472; u += 256) {
    int k, dh;
    if (u < 384) { k = u >> 4; dh = 120 + (u & 15); }
    else { int v = u - 384; k = 24 + v / 136; dh = v % 136; }
    edT[k * 136 + dh] = 0;
  }
  __syncthreads();

  // ei2 build: thread-per-(j,d), f32x4 row reads
  {
    int j = t & 63, d = t >> 6;  // d = 0..3
#pragma unroll
    for (int pass = 0; pass < 2; pass++) {
      if (pass == 1) {
        if (t >= 64) break;
        j = t; d = 4;
      }
      const int* ep = &eidxs[j * 15 + d * 3];
      const float* r0 = eemb + (size_t)ep[0] * NH;
      const float* r1 = eemb + (size_t)ep[1] * NH;
      const float* r2 = eemb + (size_t)ep[2] * NH;
#pragma unroll
      for (int hq = 0; hq < 6; hq++) {
        f32x4 s = (*(const f32x4*)&r0[hq * 4] + *(const f32x4*)&r1[hq * 4] +
                   *(const f32x4*)&r2[hq * 4]) * (1.f / 3.f);
        short4v o;
        o[0] = f2bs(s[0]); o[1] = f2bs(s[1]); o[2] = f2bs(s[2]); o[3] = f2bs(s[3]);
        *(short4v*)&ei2[j * 136 + d * 24 + hq * 4] = o;
      }
    }
  }
  // ei2 K-pad zeros: dh in [120,128)
  for (int idx = t; idx < 64 * 8; idx += 256) {
    int j = idx >> 3;
    ei2[j * 136 + 120 + (idx & 7)] = 0;
  }
  __syncthreads();

  int lane = t & 63, w = t >> 6;
  int fr = lane & 15, q = lane >> 4, fo = q * 8;
  f32x4 acc0 = {0.f, 0.f, 0.f, 0.f}, acc1 = {0.f, 0.f, 0.f, 0.f};
#pragma unroll
  for (int kk = 0; kk < 4; kk++) {
    short8 af = *(const short8*)&ei2[(w * 16 + fr) * 136 + kk * 32 + fo];
    short8 b0 = *(const short8*)&edT[(fr) * 136 + kk * 32 + fo];
    short8 b1 = *(const short8*)&edT[(16 + fr) * 136 + kk * 32 + fo];
    acc0 = __builtin_amdgcn_mfma_f32_16x16x32_bf16(af, b0, acc0, 0, 0, 0);
    acc1 = __builtin_amdgcn_mfma_f32_16x16x32_bf16(af, b1, acc1, 0, 0, 0);
  }
#pragma unroll
  for (int e = 0; e < 4; e++) {
    int j = w * 16 + q * 4 + e;
    int sp = spos[rowbase + j];
    int spc = (sp == 0) ? 1 : sp;
    spc = (spc > 1) ? spc - 1 : spc;
    if (spc > 5) spc = 5;
    float rinv = 1.f / (float)spc;
    float a2 = 2.f * ab[((size_t)b * SQ + (i + 1)) * SQ + (j0 + j + 1)];
    size_t obase = (((size_t)b * NH) * SQ + (i + 1)) * SQ + (j0 + j + 1);
    {
      int k = fr;
      float v = a2 + semb[sp * NH + k] + acc0[e] * rinv;
      gab[obase + (size_t)k * SQ * SQ] = v;
    }
    if (fr < 8) {
      int k = 16 + fr;
      float v = a2 + semb[sp * NH + k] + acc1[e] * rinv;
      gab[obase + (size_t)k * SQ * SQ] = v;
    }
  }
}

// ---------------- weight transpose+cast: f32 [R,C] -> bf16 [C,R] ----------------
struct Ptrs4 { const float* p[4]; };

template <int NW>
__global__ void k_transpose(Ptrs4 ps, short* __restrict__ dst, int R, int C,
                            size_t sstride) {
  __shared__ short tile[64][68];
  int z = blockIdx.z;
  const float* src = ps.p[z % NW] + (size_t)(z / NW) * sstride;
  short* d = dst + (size_t)z * (size_t)R * C;
  int r0 = blockIdx.x * 64, c0 = blockIdx.y * 64;
  int t = threadIdx.x;
  int tr = t >> 4, tc = (t & 15) * 4;
#pragma unroll
  for (int i = 0; i < 4; i++) {
    int r = tr + i * 16;
    f32x4 v = *(const f32x4*)(src + (size_t)(r0 + r) * C + c0 + tc);
    tile[r][tc + 0] = f2bs(v[0]);
    tile[r][tc + 1] = f2bs(v[1]);
    tile[r][tc + 2] = f2bs(v[2]);
    tile[r][tc + 3] = f2bs(v[3]);
  }
  __syncthreads();
#pragma unroll
  for (int i = 0; i < 4; i++) {
    int rr = tr + i * 16;
    short4v o;
    o[0] = tile[tc + 0][rr];
    o[1] = tile[tc + 1][rr];
    o[2] = tile[tc + 2][rr];
    o[3] = tile[tc + 3][rr];
    *(short4v*)(d + (size_t)(c0 + rr) * R + r0 + tc) = o;
  }
}

// ---------------- LayerNorm: fp32 row -> bf16 row ----------------
__global__ void k_ln(const float* __restrict__ h, const float* __restrict__ g,
                     const float* __restrict__ bb, bf16* __restrict__ y) {
  int r = blockIdx.x;
  int t = threadIdx.x, lane = t & 63, wid = t >> 6;
  __shared__ float red[8];
  const float* row = h + (size_t)r * DM;
  float v0 = row[t], v1 = row[t + 256], v2 = row[t + 512];
  float s = v0 + v1 + v2;
#pragma unroll
  for (int o = 32; o > 0; o >>= 1) s += __shfl_xor(s, o);
  if (lane == 0) red[wid] = s;
  __syncthreads();
  float mean = (red[0] + red[1] + red[2] + red[3]) * (1.f / 768.f);
  float d0 = v0 - mean, d1 = v1 - mean, d2 = v2 - mean;
  float q = d0 * d0 + d1 * d1 + d2 * d2;
#pragma unroll
  for (int o = 32; o > 0; o >>= 1) q += __shfl_xor(q, o);
  if (lane == 0) red[4 + wid] = q;
  __syncthreads();
  float var = (red[4] + red[5] + red[6] + red[7]) * (1.f / 768.f);
  float rstd = rsqrtf(var + 1e-5f);
  bf16* yr = y + (size_t)r * DM;
  yr[t] = __float2bfloat16(d0 * rstd * g[t] + bb[t]);
  yr[t + 256] = __float2bfloat16(d1 * rstd * g[t + 256] + bb[t + 256]);
  yr[t + 512] = __float2bfloat16(d2 * rstd * g[t + 512] + bb[t + 512]);
}

// ---------------- fused: h += p0+p1+cbias; y = LN(h) ----------------
__global__ void k_ln_add2(float* __restrict__ h, const float* __restrict__ p0,
                          const float* __restrict__ p1, const float* __restrict__ cb,
                          const float* __restrict__ g, const float* __restrict__ bb,
                          bf16* __restrict__ y) {
  int r = blockIdx.x;
  int t = threadIdx.x, lane = t & 63, wid = t >> 6;
  __shared__ float red[8];
  size_t base = (size_t)r * DM;
  float v0 = h[base + t] + p0[base + t] + p1[base + t] + cb[t];
  float v1 = h[base + t + 256] + p0[base + t + 256] + p1[base + t + 256] + cb[t + 256];
  float v2 = h[base + t + 512] + p0[base + t + 512] + p1[base + t + 512] + cb[t + 512];
  h[base + t] = v0;
  h[base + t + 256] = v1;
  h[base + t + 512] = v2;
  float s = v0 + v1 + v2;
#pragma unroll
  for (int o = 32; o > 0; o >>= 1) s += __shfl_xor(s, o);
  if (lane == 0) red[wid] = s;
  __syncthreads();
  float mean = (red[0] + red[1] + red[2] + red[3]) * (1.f / 768.f);
  float d0 = v0 - mean, d1 = v1 - mean, d2 = v2 - mean;
  float q = d0 * d0 + d1 * d1 + d2 * d2;
#pragma unroll
  for (int o = 32; o > 0; o >>= 1) q += __shfl_xor(q, o);
  if (lane == 0) red[4 + wid] = q;
  __syncthreads();
  float var = (red[4] + red[5] + red[6] + red[7]) * (1.f / 768.f);
  float rstd = rsqrtf(var + 1e-5f);
  bf16* yr = y + base;
  yr[t] = __float2bfloat16(d0 * rstd * g[t] + bb[t]);
  yr[t + 256] = __float2bfloat16(d1 * rstd * g[t + 256] + bb[t + 256]);
  yr[t + 512] = __float2bfloat16(d2 * rstd * g[t + 512] + bb[t + 512]);
}

// ---------------- GEMM common ----------------
struct GemmPtrs {
  const short* bt[3];
  const float* bias[3];
  void* out[3];
  int aoff[3];
};

// 128x128 block, 4 waves x 64x64, BK=64, dbuf, swizzle (QKV / FFN1)
template <int MODE>
__global__ __launch_bounds__(256, 2) void k_gemm128(const short* __restrict__ A, GemmPtrs p,
                                                    int M, int N, int K, int lda, int ldb) {
  __shared__ short At[2][128 * 64];
  __shared__ short Bt[2][128 * 64];
  int z = blockIdx.z;
  const short* BT = p.bt[z];
  const float* bias = p.bias[z];
  A += p.aoff[z];
  int m0 = blockIdx.x * 128, n0 = blockIdx.y * 128;
  int t = threadIdx.x, lane = t & 63, wid = t >> 6;
  int wr = wid >> 1, wc = wid & 1;
  f32x4 acc[4][4];
#pragma unroll
  for (int a = 0; a < 4; a++)
#pragma unroll
    for (int c = 0; c < 4; c++) acc[a][c] = (f32x4){0.f, 0.f, 0.f, 0.f};

  int lrow8 = lane >> 3;
  int lseg = (lane & 7) ^ lrow8;
  const short* gA[4];
  const short* gB[4];
#pragma unroll
  for (int i = 0; i < 4; i++) {
    int ar = m0 + wid * 32 + i * 8 + lrow8;
    if (ar >= M) ar = M - 1;
    gA[i] = A + (size_t)ar * lda + lseg * 8;
    int br = n0 + wid * 32 + i * 8 + lrow8;
    gB[i] = BT + (size_t)br * ldb + lseg * 8;
  }

  const int NIT = K >> 6;
#pragma unroll
  for (int i = 0; i < 4; i++) {
    gload16(gA[i], &At[0][(wid * 32 + i * 8) * 64]);
    gload16(gB[i], &Bt[0][(wid * 32 + i * 8) * 64]);
  }
  __syncthreads();

  int fr = lane & 15, q = lane >> 4;
  for (int it = 0; it < NIT; ++it) {
    int cur = it & 1;
    if (it + 1 < NIT) {
      int nxt = cur ^ 1;
      int k0 = (it + 1) << 6;
#pragma unroll
      for (int i = 0; i < 4; i++) {
        gload16(gA[i] + k0, &At[nxt][(wid * 32 + i * 8) * 64]);
        gload16(gB[i] + k0, &Bt[nxt][(wid * 32 + i * 8) * 64]);
      }
    }
    const short* Ab = At[cur];
    const short* Bb = Bt[cur];
#pragma unroll
    for (int kk = 0; kk < 2; kk++) {
      int sg = ((q + kk * 4) ^ (fr & 7)) * 8;
      short8 af[4], bf[4];
#pragma unroll
      for (int mr = 0; mr < 4; mr++)
        af[mr] = *(const short8*)&Ab[(wr * 64 + mr * 16 + fr) * 64 + sg];
#pragma unroll
      for (int nc = 0; nc < 4; nc++)
        bf[nc] = *(const short8*)&Bb[(wc * 64 + nc * 16 + fr) * 64 + sg];
#pragma unroll
      for (int mr = 0; mr < 4; mr++)
#pragma unroll
        for (int nc = 0; nc < 4; nc++)
          acc[mr][nc] = __builtin_amdgcn_mfma_f32_16x16x32_bf16(af[mr], bf[nc], acc[mr][nc], 0, 0, 0);
    }
    __syncthreads();
  }

  int rsub = q * 4;
#pragma unroll
  for (int nc = 0; nc < 4; nc++) {
    int col = n0 + wc * 64 + nc * 16 + fr;
    float bv = (MODE == 3) ? 0.f : bias[col];
#pragma unroll
    for (int mr = 0; mr < 4; mr++) {
#pragma unroll
      for (int e = 0; e < 4; e++) {
        int r = m0 + wr * 64 + mr * 16 + rsub + e;
        if (r < M) {
          float v = acc[mr][nc][e] + bv;
          if (MODE == 0 || MODE == 3) {
            ((float*)p.out[z])[(size_t)r * N + col] = v;
          } else {
            float gg = 0.5f * v * (1.f + erff(v * 0.70710678118654752f));
            ((bf16*)p.out[z])[(size_t)r * N + col] = __float2bfloat16(gg);
          }
        }
      }
    }
  }
}

// 64x128 block, 4 waves x 32x64, BK=64, dbuf, swizzle (Wo / FFN2 split-K fill)
template <int MODE>
__global__ __launch_bounds__(256, 3) void k_gemm64(const short* __restrict__ A, GemmPtrs p,
                                                   int M, int N, int K, int lda, int ldb) {
  __shared__ short At[2][64 * 64];
  __shared__ short Bt[2][128 * 64];
  int z = blockIdx.z;
  const short* BT = p.bt[z];
  const float* bias = p.bias[z];
  A += p.aoff[z];
  int m0 = blockIdx.x * 64, n0 = blockIdx.y * 128;
  int t = threadIdx.x, lane = t & 63, wid = t >> 6;
  int wr = wid >> 1, wc = wid & 1;
  f32x4 acc[2][4];
#pragma unroll
  for (int a = 0; a < 2; a++)
#pragma unroll
    for (int c = 0; c < 4; c++) acc[a][c] = (f32x4){0.f, 0.f, 0.f, 0.f};

  int lrow8 = lane >> 3;
  int lseg = (lane & 7) ^ lrow8;
  const short* gA[2];
  const short* gB[4];
#pragma unroll
  for (int i = 0; i < 2; i++) {
    int ar = m0 + wid * 16 + i * 8 + lrow8;
    if (ar >= M) ar = M - 1;
    gA[i] = A + (size_t)ar * lda + lseg * 8;
  }
#pragma unroll
  for (int i = 0; i < 4; i++) {
    int br = n0 + wid * 32 + i * 8 + lrow8;
    gB[i] = BT + (size_t)br * ldb + lseg * 8;
  }

  const int NIT = K >> 6;
#pragma unroll
  for (int i = 0; i < 2; i++) gload16(gA[i], &At[0][(wid * 16 + i * 8) * 64]);
#pragma unroll
  for (int i = 0; i < 4; i++) gload16(gB[i], &Bt[0][(wid * 32 + i * 8) * 64]);
  __syncthreads();

  int fr = lane & 15, q = lane >> 4;
  for (int it = 0; it < NIT; ++it) {
    int cur = it & 1;
    if (it + 1 < NIT) {
      int nxt = cur ^ 1;
      int k0 = (it + 1) << 6;
#pragma unroll
      for (int i = 0; i < 2; i++) gload16(gA[i] + k0, &At[nxt][(wid * 16 + i * 8) * 64]);
#pragma unroll
      for (int i = 0; i < 4; i++) gload16(gB[i] + k0, &Bt[nxt][(wid * 32 + i * 8) * 64]);
    }
    const short* Ab = At[cur];
    const short* Bb = Bt[cur];
#pragma unroll
    for (int kk = 0; kk < 2; kk++) {
      int sg = ((q + kk * 4) ^ (fr & 7)) * 8;
      short8 af[2], bf[4];
#pragma unroll
      for (int mr = 0; mr < 2; mr++)
        af[mr] = *(const short8*)&Ab[(wr * 32 + mr * 16 + fr) * 64 + sg];
#pragma unroll
      for (int nc = 0; nc < 4; nc++)
        bf[nc] = *(const short8*)&Bb[(wc * 64 + nc * 16 + fr) * 64 + sg];
#pragma unroll
      for (int mr = 0; mr < 2; mr++)
#pragma unroll
        for (int nc = 0; nc < 4; nc++)
          acc[mr][nc] = __builtin_amdgcn_mfma_f32_16x16x32_bf16(af[mr], bf[nc], acc[mr][nc], 0, 0, 0);
    }
    __syncthreads();
  }

  int rsub = q * 4;
#pragma unroll
  for (int nc = 0; nc < 4; nc++) {
    int col = n0 + wc * 64 + nc * 16 + fr;
    float bv = (MODE == 3) ? 0.f : bias[col];
#pragma unroll
    for (int mr = 0; mr < 2; mr++) {
#pragma unroll
      for (int e = 0; e < 4; e++) {
        int r = m0 + wr * 32 + mr * 16 + rsub + e;
        if (r < M) {
          float v = acc[mr][nc][e] + bv;
          if (MODE == 0 || MODE == 3) {
            ((float*)p.out[z])[(size_t)r * N + col] = v;
          } else {
            float gg = 0.5f * v * (1.f + erff(v * 0.70710678118654752f));
            ((bf16*)p.out[z])[(size_t)r * N + col] = __float2bfloat16(gg);
          }
        }
      }
    }
  }
}

// ---------------- attention: block per (b,h,qchunk), conflict-free LDS ----------------
__global__ __launch_bounds__(256) void k_attn(const float* __restrict__ Q,
                                              const float* __restrict__ Kb,
                                              const float* __restrict__ Vb,
                                              const float* __restrict__ gab,
                                              bf16* __restrict__ ctx) {
  int bh = blockIdx.x;
  int qc = blockIdx.y;
  int b = bh / NH, hh = bh % NH;
  __shared__ float Kl[129][33];
  __shared__ float Vl[129][33];
  __shared__ float pl[4][132];
  int t = threadIdx.x;
  for (int idx = t; idx < 129 * 8; idx += 256) {
    int ks = idx >> 3, seg = idx & 7;
    size_t src = ((size_t)(b * SQ + ks)) * DM + hh * 32 + seg * 4;
    f32x4 kv = *(const f32x4*)&Kb[src];
    f32x4 vv = *(const f32x4*)&Vb[src];
    int dd = seg * 4;
    Kl[ks][dd] = kv[0]; Kl[ks][dd + 1] = kv[1]; Kl[ks][dd + 2] = kv[2]; Kl[ks][dd + 3] = kv[3];
    Vl[ks][dd] = vv[0]; Vl[ks][dd + 1] = vv[1]; Vl[ks][dd + 2] = vv[2]; Vl[ks][dd + 3] = vv[3];
  }
  __syncthreads();
  int w = t >> 6, lane = t & 63;
  int gw = qc * 4 + w;  // 0..15
  const float scale = 0.17677669529663689f;  // 1/sqrt(32)
  int kg = lane >> 5, dd = lane & 31;
  for (int q = gw; q < SQ; q += 16) {
    const float* qrow = Q + ((size_t)(b * SQ + q)) * DM + hh * 32;
    float qv[32];
#pragma unroll
    for (int d = 0; d < 32; d += 4) {
      f32x4 v4 = *(const f32x4*)&qrow[d];
      qv[d] = v4[0]; qv[d + 1] = v4[1]; qv[d + 2] = v4[2]; qv[d + 3] = v4[3];
    }
    const float* grow = gab + (((size_t)(b * NH + hh)) * SQ + q) * SQ;
    float s0a = 0.f, s0b = 0.f, s1a = 0.f, s1b = 0.f;
#pragma unroll
    for (int d = 0; d < 32; d += 2) {
      s0a += qv[d] * Kl[lane][d];
      s0b += qv[d + 1] * Kl[lane][d + 1];
      s1a += qv[d] * Kl[lane + 64][d];
      s1b += qv[d + 1] * Kl[lane + 64][d + 1];
    }
    float sc0 = (s0a + s0b) * scale + grow[lane];
    float sc1 = (s1a + s1b) * scale + grow[lane + 64];
    float sc2 = -1e30f;
    if (lane == 0) {
      float sa = 0.f, sb = 0.f;
#pragma unroll
      for (int d = 0; d < 32; d += 2) { sa += qv[d] * Kl[128][d]; sb += qv[d + 1] * Kl[128][d + 1]; }
      sc2 = (sa + sb) * scale + grow[128];
    }
    float m = fmaxf(sc0, fmaxf(sc1, sc2));
#pragma unroll
    for (int o = 32; o > 0; o >>= 1) m = fmaxf(m, __shfl_xor(m, o));
    float e0 = __expf(sc0 - m), e1 = __expf(sc1 - m);
    float e2 = (lane == 0) ? __expf(sc2 - m) : 0.f;
    float sum = e0 + e1 + e2;
#pragma unroll
    for (int o = 32; o > 0; o >>= 1) sum += __shfl_xor(sum, o);
    float inv = 1.f / sum;
    pl[w][lane] = e0 * inv;
    pl[w][lane + 64] = e1 * inv;
    if (lane == 0) pl[w][128] = e2 * inv;
    asm volatile("s_waitcnt lgkmcnt(0)" ::: "memory");
    // PV: lane = (kg in {0,1}, dd in 0..31); banks (33k+dd) conflict-free
    float a = 0.f;
    int kbase = kg * 64;
#pragma unroll 8
    for (int i = 0; i < 64; i++) a += pl[w][kbase + i] * Vl[kbase + i][dd];
    a += __shfl_xor(a, 32);
    if (lane < 32) {
      a += pl[w][128] * Vl[128][dd];
      ctx[((size_t)(b * SQ + q)) * DM + hh * 32 + dd] = __float2bfloat16(a);
    }
  }
}

// ---------------- final: h_row0 + p0 + p1 + cbias -> LN -> project ----------------
__global__ void k_final_add2(const float* __restrict__ h, const float* __restrict__ p0,
                             const float* __restrict__ p1, const float* __restrict__ cb,
                             const float* __restrict__ g, const float* __restrict__ bb,
                             const float* __restrict__ ow, const float* __restrict__ ob,
                             float* __restrict__ out) {
  int b = blockIdx.x;
  int t = threadIdx.x, lane = t & 63, wid = t >> 6;
  __shared__ float red[8];
  __shared__ float yn[768];
  size_t base = (size_t)(b * SQ) * DM;
  float v0 = h[base + t] + p0[base + t] + p1[base + t] + cb[t];
  float v1 = h[base + t + 256] + p0[base + t + 256] + p1[base + t + 256] + cb[t + 256];
  float v2 = h[base + t + 512] + p0[base + t + 512] + p1[base + t + 512] + cb[t + 512];
  float s = v0 + v1 + v2;
#pragma unroll
  for (int o = 32; o > 0; o >>= 1) s += __shfl_xor(s, o);
  if (lane == 0) red[wid] = s;
  __syncthreads();
  float mean = (red[0] + red[1] + red[2] + red[3]) * (1.f / 768.f);
  float d0 = v0 - mean, d1 = v1 - mean, d2 = v2 - mean;
  float q = d0 * d0 + d1 * d1 + d2 * d2;
#pragma unroll
  for (int o = 32; o > 0; o >>= 1) q += __shfl_xor(q, o);
  if (lane == 0) red[4 + wid] = q;
  __syncthreads();
  float var = (red[4] + red[5] + red[6] + red[7]) * (1.f / 768.f);
  float rstd = rsqrtf(var + 1e-5f);
  yn[t] = d0 * rstd * g[t] + bb[t];
  yn[t + 256] = d1 * rstd * g[t + 256] + bb[t + 256];
  yn[t + 512] = d2 * rstd * g[t + 512] + bb[t + 512];
  __syncthreads();
  if (t < 128) {
    float acc = ob[t];
    for (int d = 0; d < 768; d++) acc += yn[d] * ow[d * 128 + t];
    out[b * 128 + t] = acc;
  }
}

extern "C" void kernel_launch(void* const* d_in, const int* in_sizes, int n_in,
                              void* d_out, int out_size, void* d_ws, size_t ws_size,
                              hipStream_t stream) {
  (void)in_sizes; (void)n_in; (void)out_size;
  const int* x     = (const int*)d_in[0];
  const int* ind   = (const int*)d_in[1];
  const int* outd  = (const int*)d_in[2];
  const int* spos  = (const int*)d_in[3];
  const int* eidx  = (const int*)d_in[4];
  const float* ab   = (const float*)d_in[5];
  const float* atom = (const float*)d_in[6];
  const float* ide  = (const float*)d_in[7];
  const float* ode  = (const float*)d_in[8];
  const float* gtok = (const float*)d_in[9];
  const float* eemb = (const float*)d_in[10];
  const float* edemb= (const float*)d_in[11];
  const float* semb = (const float*)d_in[12];
  const float* virt = (const float*)d_in[13];
  const float* ln1g = (const float*)d_in[14];
  const float* ln1b = (const float*)d_in[15];
  const float* wq  = (const float*)d_in[16];
  const float* bq   = (const float*)d_in[17];
  const float* wk  = (const float*)d_in[18];
  const float* bk   = (const float*)d_in[19];
  const float* wv  = (const float*)d_in[20];
  const float* bv   = (const float*)d_in[21];
  const float* wo  = (const float*)d_in[22];
  const float* bo   = (const float*)d_in[23];
  const float* ln2g = (const float*)d_in[24];
  const float* ln2b = (const float*)d_in[25];
  const float* w1  = (const float*)d_in[26];
  const float* b1   = (const float*)d_in[27];
  const float* w2  = (const float*)d_in[28];
  const float* b2   = (const float*)d_in[29];
  const float* fg   = (const float*)d_in[30];
  const float* fb   = (const float*)d_in[31];
  const float* ow   = (const float*)d_in[32];
  const float* ob   = (const float*)d_in[33];
  float* out = (float*)d_out;

  const int DD2 = DM * DM;
  const size_t WQKVO = (size_t)DD2;
  const size_t WFF = (size_t)DM * DF;

  char* ws = (char*)d_ws;
  size_t off = 0;
  auto alloc = [&](size_t bytes) -> void* {
    void* p = ws + off;
    off += (bytes + 255) & ~(size_t)255;
    return p;
  };
  float* gab = (float*)alloc((size_t)NB * NH * SQ * SQ * 4);
  float* h   = (float*)alloc((size_t)MROWS * DM * 4);
  bf16* y    = (bf16*)alloc((size_t)MROWS * DM * 2);
  float* qb  = (float*)alloc((size_t)MROWS * DM * 4);
  float* kb2 = (float*)alloc((size_t)MROWS * DM * 4);
  float* vb2 = (float*)alloc((size_t)MROWS * DM * 4);
  bf16* ctx  = (bf16*)alloc((size_t)MROWS * DM * 2);
  bf16* t1   = (bf16*)alloc((size_t)MROWS * DF * 2);
  float* p0 = qb;
  float* p1 = kb2;

  size_t need_hoist = off + ((size_t)NLAY * 4 * WQKVO + 2 * (size_t)NLAY * WFF) * 2 + (1 << 20);
  bool hoist = ws_size >= need_hoist;
  short* wT  = (short*)alloc((hoist ? (size_t)NLAY * 4 * WQKVO : 4 * WQKVO) * 2);
  short* w1T = (short*)alloc((hoist ? (size_t)NLAY * WFF : WFF) * 2);
  short* w2T = (short*)alloc((hoist ? (size_t)NLAY * WFF : WFF) * 2);

  dim3 blk(256);
  k_nodefeat<<<dim3(NB * SQ), blk, 0, stream>>>(x, ind, outd, atom, ide, ode, gtok, h);
  k_gab_border<<<dim3(NB), blk, 0, stream>>>(ab, virt, gab);
  k_gab_edge<<<dim3(NB * ND * 2), blk, 0, stream>>>(spos, eidx, eemb, edemb, semb, ab, gab);

  if (hoist) {
    Ptrs4 pq; pq.p[0] = wq; pq.p[1] = wk; pq.p[2] = wv; pq.p[3] = wo;
    k_transpose<4><<<dim3(12, 12, 48), blk, 0, stream>>>(pq, wT, DM, DM, WQKVO);
    Ptrs4 pa; pa.p[0] = w1; pa.p[1] = pa.p[2] = pa.p[3] = w1;
    k_transpose<1><<<dim3(12, 48, 12), blk, 0, stream>>>(pa, w1T, DM, DF, WFF);
    Ptrs4 pb; pb.p[0] = w2; pb.p[1] = pb.p[2] = pb.p[3] = w2;
    k_transpose<1><<<dim3(48, 12, 12), blk, 0, stream>>>(pb, w2T, DF, DM, WFF);
  }

  for (int l = 0; l < NLAY; l++) {
    if (!hoist) {
      Ptrs4 pq;
      pq.p[0] = wq + (size_t)l * DD2; pq.p[1] = wk + (size_t)l * DD2;
      pq.p[2] = wv + (size_t)l * DD2; pq.p[3] = wo + (size_t)l * DD2;
      k_transpose<4><<<dim3(12, 12, 4), blk, 0, stream>>>(pq, wT, DM, DM, 0);
      Ptrs4 pa; pa.p[0] = w1 + (size_t)l * WFF; pa.p[1] = pa.p[2] = pa.p[3] = pa.p[0];
      k_transpose<1><<<dim3(12, 48, 1), blk, 0, stream>>>(pa, w1T, DM, DF, 0);
      Ptrs4 pb; pb.p[0] = w2 + (size_t)l * WFF; pb.p[1] = pb.p[2] = pb.p[3] = pb.p[0];
      k_transpose<1><<<dim3(48, 12, 1), blk, 0, stream>>>(pb, w2T, DF, DM, 0);
    }
    const short* wTl  = wT  + (hoist ? (size_t)l * 4 * WQKVO : 0);
    const short* w1Tl = w1T + (hoist ? (size_t)l * WFF : 0);
    const short* w2Tl = w2T + (hoist ? (size_t)l * WFF : 0);

    if (l == 0)
      k_ln<<<dim3(MROWS), blk, 0, stream>>>(h, ln1g, ln1b, y);

    GemmPtrs gq;
    gq.bt[0] = wTl; gq.bt[1] = wTl + DD2; gq.bt[2] = wTl + 2 * DD2;
    gq.bias[0] = bq + l * DM; gq.bias[1] = bk + l * DM; gq.bias[2] = bv + l * DM;
    gq.out[0] = qb; gq.out[1] = kb2; gq.out[2] = vb2;
    gq.aoff[0] = gq.aoff[1] = gq.aoff[2] = 0;
    k_gemm128<0><<<dim3(17, 6, 3), blk, 0, stream>>>((const short*)y, gq, MROWS, DM, DM, DM, DM);

    k_attn<<<dim3(NB * NH, 4), blk, 0, stream>>>(qb, kb2, vb2, gab, ctx);

    GemmPtrs go;  // Wo split-K: K=768 -> 2 x 384, 64-row tiles for fill
    go.bt[0] = wTl + 3 * DD2; go.bt[1] = wTl + 3 * DD2 + 384;
    go.bias[0] = go.bias[1] = nullptr;
    go.out[0] = p0; go.out[1] = p1;
    go.aoff[0] = 0; go.aoff[1] = 384;
    go.bt[2] = go.bt[0]; go.out[2] = p0; go.aoff[2] = 0; go.bias[2] = nullptr;
    k_gemm64<3><<<dim3(33, 6, 2), blk, 0, stream>>>((const short*)ctx, go, MROWS, DM, 384, DM, DM);

    k_ln_add2<<<dim3(MROWS), blk, 0, stream>>>(h, p0, p1, bo + l * DM,
                                               ln2g + l * DM, ln2b + l * DM, y);

    GemmPtrs g1;
    g1.bt[0] = g1.bt[1] = g1.bt[2] = w1Tl;
    g1.bias[0] = g1.bias[1] = g1.bias[2] = b1 + l * DF;
    g1.out[0] = g1.out[1] = g1.out[2] = t1;
    g1.aoff[0] = g1.aoff[1] = g1.aoff[2] = 0;
    k_gemm128<2><<<dim3(17, 24, 1), blk, 0, stream>>>((const short*)y, g1, MROWS, DF, DM, DM, DM);

    GemmPtrs g2;  // FFN2 split-K: K=3072 -> 2 x 1536, 64-row tiles for fill
    g2.bt[0] = w2Tl; g2.bt[1] = w2Tl + 1536;
    g2.bias[0] = g2.bias[1] = nullptr;
    g2.out[0] = p0; g2.out[1] = p1;
    g2.aoff[0] = 0; g2.aoff[1] = 1536;
    g2.bt[2] = g2.bt[0]; g2.out[2] = p0; g2.aoff[2] = 0; g2.bias[2] = nullptr;
    k_gemm64<3><<<dim3(33, 6, 2), blk, 0, stream>>>((const short*)t1, g2, MROWS, DM, 1536, DF, DF);

    if (l < NLAY - 1) {
      k_ln_add2<<<dim3(MROWS), blk, 0, stream>>>(h, p0, p1, b2 + l * DM,
                                                 ln1g + (l + 1) * DM, ln1b + (l + 1) * DM, y);
    } else {
      k_final_add2<<<dim3(NB), blk, 0, stream>>>(h, p0, p1, b2 + l * DM, fg, fb, ow, ob, out);
    }
  }
}

// Round 7
// 2096.387 us; speedup vs baseline: 1.8559x; 1.0014x over previous
//
#include <hip/hip_runtime.h>
#include <hip/hip_bf16.h>
#include <math.h>

typedef __hip_bfloat16 bf16;
typedef __attribute__((ext_vector_type(8))) short short8;
typedef __attribute__((ext_vector_type(4))) short short4v;
typedef __attribute__((ext_vector_type(4))) float f32x4;

constexpr int NB = 16;     // batch
constexpr int ND = 128;    // nodes N
constexpr int SQ = 129;    // S = N+1
constexpr int NH = 24;     // heads
constexpr int DM = 768;    // model dim
constexpr int DF = 3072;   // ffn dim
constexpr int NLAY = 12;
constexpr int MROWS = NB * SQ;  // 2064

__device__ __forceinline__ short f2bs(float f) {
  bf16 h = __float2bfloat16(f);
  return *(short*)&h;
}

__device__ __forceinline__ void gload16(const void* g, void* lds) {
  __builtin_amdgcn_global_load_lds(
      (const __attribute__((address_space(1))) unsigned int*)g,
      (__attribute__((address_space(3))) unsigned int*)lds, 16, 0, 0);
}

// ---------------- node features ----------------
__global__ void k_nodefeat(const int* __restrict__ x, const int* __restrict__ ind,
                           const int* __restrict__ outd,
                           const float* __restrict__ atom, const float* __restrict__ ide,
                           const float* __restrict__ ode, const float* __restrict__ gtok,
                           float* __restrict__ h) {
  int bs = blockIdx.x;
  int b = bs / SQ, s = bs % SQ;
  int t = threadIdx.x;
  float* hrow = h + (size_t)bs * DM;
  if (s == 0) {
    for (int c = t; c < DM; c += 256) hrow[c] = gtok[c];
  } else {
    int n = s - 1;
    const int* xr = x + (b * ND + n) * 9;
    int a0 = xr[0], a1 = xr[1], a2 = xr[2], a3 = xr[3], a4 = xr[4];
    int a5 = xr[5], a6 = xr[6], a7 = xr[7], a8 = xr[8];
    int ii = ind[b * ND + n], oo = outd[b * ND + n];
    for (int c = t; c < DM; c += 256) {
      float acc = ide[(size_t)ii * DM + c] + ode[(size_t)oo * DM + c];
      acc += atom[(size_t)a0 * DM + c];
      acc += atom[(size_t)a1 * DM + c];
      acc += atom[(size_t)a2 * DM + c];
      acc += atom[(size_t)a3 * DM + c];
      acc += atom[(size_t)a4 * DM + c];
      acc += atom[(size_t)a5 * DM + c];
      acc += atom[(size_t)a6 * DM + c];
      acc += atom[(size_t)a7 * DM + c];
      acc += atom[(size_t)a8 * DM + c];
      hrow[c] = acc;
    }
  }
}

// ---------------- gab: virtual-token borders ----------------
__global__ void k_gab_border(const float* __restrict__ ab, const float* __restrict__ virt,
                             float* __restrict__ gab) {
  int b = blockIdx.x;
  const int tot = NH * SQ + NH * ND;
  for (int idx = threadIdx.x; idx < tot; idx += 256) {
    if (idx < NH * SQ) {
      int hh = idx / SQ, j = idx % SQ;
      float v = 2.f * ab[((size_t)b * SQ + 0) * SQ + j] + virt[hh];
      gab[(((size_t)b * NH + hh) * SQ + 0) * SQ + j] = v;
    } else {
      int r = idx - NH * SQ;
      int hh = r / ND, i = r % ND + 1;
      float v = 2.f * ab[((size_t)b * SQ + i) * SQ + 0] + virt[hh];
      gab[(((size_t)b * NH + hh) * SQ + i) * SQ + 0] = v;
    }
  }
}

// ---------------- gab: spatial + multihop edge bias (MFMA, coalesced writes) ----
__global__ __launch_bounds__(256) void k_gab_edge(
    const int* __restrict__ spos, const int* __restrict__ eidx,
    const float* __restrict__ eemb, const float* __restrict__ edemb,
    const float* __restrict__ semb, const float* __restrict__ ab,
    float* __restrict__ gab) {
  __shared__ int eidxs[960];       // 64 j x 5 d x 3 f
  __shared__ short ei2[64 * 136];  // bf16 [j][dh]
  __shared__ short edT[32 * 136];  // bf16 [k][dh]
  __shared__ float ot[24][65];     // raw MFMA out [k][j], padded
  __shared__ float rinvA[64], a2A[64];
  __shared__ int spA[64];
  int bi = blockIdx.x;
  int half = bi & 1;
  int i = (bi >> 1) & 127;
  int b = bi >> 8;
  int j0 = half * 64;
  int t = threadIdx.x;
  const size_t rowbase = ((size_t)(b * ND + i)) * ND + j0;

  // stage eidx coalesced (j-contiguous)
  const int* esrc = eidx + rowbase * 15;
  for (int idx = t; idx < 960; idx += 256) eidxs[idx] = esrc[idx];
  // edT build: vectorized over k
  for (int u = t; u < 720; u += 256) {
    int dh = u / 6, kq = u % 6;
    f32x4 v = *(const f32x4*)&edemb[dh * 24 + kq * 4];
    edT[(kq * 4 + 0) * 136 + dh] = f2bs(v[0]);
    edT[(kq * 4 + 1) * 136 + dh] = f2bs(v[1]);
    edT[(kq * 4 + 2) * 136 + dh] = f2bs(v[2]);
    edT[(kq * 4 + 3) * 136 + dh] = f2bs(v[3]);
  }
  // edT pad zeros: k<24 dh in [120,136); k in [24,32) all dh
  for (int u = t; u < 1472; u += 256) {
    int k, dh;
    if (u < 384) { k = u >> 4; dh = 120 + (u & 15); }
    else { int v = u - 384; k = 24 + v / 136; dh = v % 136; }
    edT[k * 136 + dh] = 0;
  }
  // per-j metadata
  if (t < 64) {
    int j = t;
    int sp = spos[rowbase + j];
    int spc = (sp == 0) ? 1 : sp;
    spc = (spc > 1) ? spc - 1 : spc;
    if (spc > 5) spc = 5;
    spA[j] = sp;
    rinvA[j] = 1.f / (float)spc;
    a2A[j] = 2.f * ab[((size_t)b * SQ + (i + 1)) * SQ + (j0 + j + 1)];
  }
  __syncthreads();

  // ei2 build: thread-per-(j,d), f32x4 row reads
  {
    int j = t & 63, d = t >> 6;  // d = 0..3
#pragma unroll
    for (int pass = 0; pass < 2; pass++) {
      if (pass == 1) {
        if (t >= 64) break;
        j = t; d = 4;
      }
      const int* ep = &eidxs[j * 15 + d * 3];
      const float* r0 = eemb + (size_t)ep[0] * NH;
      const float* r1 = eemb + (size_t)ep[1] * NH;
      const float* r2 = eemb + (size_t)ep[2] * NH;
#pragma unroll
      for (int hq = 0; hq < 6; hq++) {
        f32x4 s = (*(const f32x4*)&r0[hq * 4] + *(const f32x4*)&r1[hq * 4] +
                   *(const f32x4*)&r2[hq * 4]) * (1.f / 3.f);
        short4v o;
        o[0] = f2bs(s[0]); o[1] = f2bs(s[1]); o[2] = f2bs(s[2]); o[3] = f2bs(s[3]);
        *(short4v*)&ei2[j * 136 + d * 24 + hq * 4] = o;
      }
    }
  }
  // ei2 K-pad zeros: dh in [120,128)
  for (int idx = t; idx < 64 * 8; idx += 256) {
    int j = idx >> 3;
    ei2[j * 136 + 120 + (idx & 7)] = 0;
  }
  __syncthreads();

  int lane = t & 63, w = t >> 6;
  int fr = lane & 15, q = lane >> 4, fo = q * 8;
  f32x4 acc0 = {0.f, 0.f, 0.f, 0.f}, acc1 = {0.f, 0.f, 0.f, 0.f};
#pragma unroll
  for (int kk = 0; kk < 4; kk++) {
    short8 af = *(const short8*)&ei2[(w * 16 + fr) * 136 + kk * 32 + fo];
    short8 b0 = *(const short8*)&edT[(fr) * 136 + kk * 32 + fo];
    short8 b1 = *(const short8*)&edT[(16 + fr) * 136 + kk * 32 + fo];
    acc0 = __builtin_amdgcn_mfma_f32_16x16x32_bf16(af, b0, acc0, 0, 0, 0);
    acc1 = __builtin_amdgcn_mfma_f32_16x16x32_bf16(af, b1, acc1, 0, 0, 0);
  }
  // dump raw acc into ot[k][j]
#pragma unroll
  for (int e = 0; e < 4; e++) {
    int j = w * 16 + q * 4 + e;
    ot[fr][j] = acc0[e];
    if (fr < 8) ot[16 + fr][j] = acc1[e];
  }
  __syncthreads();
  // coalesced write: consecutive threads -> consecutive j within a k-plane
  size_t obase = (((size_t)b * NH) * SQ + (i + 1)) * SQ + (j0 + 1);
  for (int idx = t; idx < 24 * 64; idx += 256) {
    int k = idx >> 6, j = idx & 63;
    float v = a2A[j] + semb[spA[j] * NH + k] + ot[k][j] * rinvA[j];
    gab[obase + (size_t)k * SQ * SQ + j] = v;
  }
}

// ---------------- weight transpose+cast: f32 [R,C] -> bf16 [C,R] ----------------
struct Ptrs4 { const float* p[4]; };

template <int NW>
__global__ void k_transpose(Ptrs4 ps, short* __restrict__ dst, int R, int C,
                            size_t sstride) {
  __shared__ short tile[64][68];
  int z = blockIdx.z;
  const float* src = ps.p[z % NW] + (size_t)(z / NW) * sstride;
  short* d = dst + (size_t)z * (size_t)R * C;
  int r0 = blockIdx.x * 64, c0 = blockIdx.y * 64;
  int t = threadIdx.x;
  int tr = t >> 4, tc = (t & 15) * 4;
#pragma unroll
  for (int i = 0; i < 4; i++) {
    int r = tr + i * 16;
    f32x4 v = *(const f32x4*)(src + (size_t)(r0 + r) * C + c0 + tc);
    tile[r][tc + 0] = f2bs(v[0]);
    tile[r][tc + 1] = f2bs(v[1]);
    tile[r][tc + 2] = f2bs(v[2]);
    tile[r][tc + 3] = f2bs(v[3]);
  }
  __syncthreads();
#pragma unroll
  for (int i = 0; i < 4; i++) {
    int rr = tr + i * 16;
    short4v o;
    o[0] = tile[tc + 0][rr];
    o[1] = tile[tc + 1][rr];
    o[2] = tile[tc + 2][rr];
    o[3] = tile[tc + 3][rr];
    *(short4v*)(d + (size_t)(c0 + rr) * R + r0 + tc) = o;
  }
}

// ---------------- LayerNorm: fp32 row -> bf16 row ----------------
__global__ void k_ln(const float* __restrict__ h, const float* __restrict__ g,
                     const float* __restrict__ bb, bf16* __restrict__ y) {
  int r = blockIdx.x;
  int t = threadIdx.x, lane = t & 63, wid = t >> 6;
  __shared__ float red[8];
  const float* row = h + (size_t)r * DM;
  float v0 = row[t], v1 = row[t + 256], v2 = row[t + 512];
  float s = v0 + v1 + v2;
#pragma unroll
  for (int o = 32; o > 0; o >>= 1) s += __shfl_xor(s, o);
  if (lane == 0) red[wid] = s;
  __syncthreads();
  float mean = (red[0] + red[1] + red[2] + red[3]) * (1.f / 768.f);
  float d0 = v0 - mean, d1 = v1 - mean, d2 = v2 - mean;
  float q = d0 * d0 + d1 * d1 + d2 * d2;
#pragma unroll
  for (int o = 32; o > 0; o >>= 1) q += __shfl_xor(q, o);
  if (lane == 0) red[4 + wid] = q;
  __syncthreads();
  float var = (red[4] + red[5] + red[6] + red[7]) * (1.f / 768.f);
  float rstd = rsqrtf(var + 1e-5f);
  bf16* yr = y + (size_t)r * DM;
  yr[t] = __float2bfloat16(d0 * rstd * g[t] + bb[t]);
  yr[t + 256] = __float2bfloat16(d1 * rstd * g[t + 256] + bb[t + 256]);
  yr[t + 512] = __float2bfloat16(d2 * rstd * g[t + 512] + bb[t + 512]);
}

// ---------------- fused: h += p0+p1+cbias; y = LN(h) ----------------
__global__ void k_ln_add2(float* __restrict__ h, const float* __restrict__ p0,
                          const float* __restrict__ p1, const float* __restrict__ cb,
                          const float* __restrict__ g, const float* __restrict__ bb,
                          bf16* __restrict__ y) {
  int r = blockIdx.x;
  int t = threadIdx.x, lane = t & 63, wid = t >> 6;
  __shared__ float red[8];
  size_t base = (size_t)r * DM;
  float v0 = h[base + t] + p0[base + t] + p1[base + t] + cb[t];
  float v1 = h[base + t + 256] + p0[base + t + 256] + p1[base + t + 256] + cb[t + 256];
  float v2 = h[base + t + 512] + p0[base + t + 512] + p1[base + t + 512] + cb[t + 512];
  h[base + t] = v0;
  h[base + t + 256] = v1;
  h[base + t + 512] = v2;
  float s = v0 + v1 + v2;
#pragma unroll
  for (int o = 32; o > 0; o >>= 1) s += __shfl_xor(s, o);
  if (lane == 0) red[wid] = s;
  __syncthreads();
  float mean = (red[0] + red[1] + red[2] + red[3]) * (1.f / 768.f);
  float d0 = v0 - mean, d1 = v1 - mean, d2 = v2 - mean;
  float q = d0 * d0 + d1 * d1 + d2 * d2;
#pragma unroll
  for (int o = 32; o > 0; o >>= 1) q += __shfl_xor(q, o);
  if (lane == 0) red[4 + wid] = q;
  __syncthreads();
  float var = (red[4] + red[5] + red[6] + red[7]) * (1.f / 768.f);
  float rstd = rsqrtf(var + 1e-5f);
  bf16* yr = y + base;
  yr[t] = __float2bfloat16(d0 * rstd * g[t] + bb[t]);
  yr[t + 256] = __float2bfloat16(d1 * rstd * g[t + 256] + bb[t + 256]);
  yr[t + 512] = __float2bfloat16(d2 * rstd * g[t + 512] + bb[t + 512]);
}

// ---------------- GEMM common ----------------
struct GemmPtrs {
  const short* bt[3];
  const float* bias[3];
  void* out[3];
  int aoff[3];
};

// 128x128 block, 4 waves x 64x64, BK=64, dbuf, swizzle (QKV / FFN1)
template <int MODE>
__global__ __launch_bounds__(256, 2) void k_gemm128(const short* __restrict__ A, GemmPtrs p,
                                                    int M, int N, int K, int lda, int ldb) {
  __shared__ short At[2][128 * 64];
  __shared__ short Bt[2][128 * 64];
  int z = blockIdx.z;
  const short* BT = p.bt[z];
  const float* bias = p.bias[z];
  A += p.aoff[z];
  int m0 = blockIdx.x * 128, n0 = blockIdx.y * 128;
  int t = threadIdx.x, lane = t & 63, wid = t >> 6;
  int wr = wid >> 1, wc = wid & 1;
  f32x4 acc[4][4];
#pragma unroll
  for (int a = 0; a < 4; a++)
#pragma unroll
    for (int c = 0; c < 4; c++) acc[a][c] = (f32x4){0.f, 0.f, 0.f, 0.f};

  int lrow8 = lane >> 3;
  int lseg = (lane & 7) ^ lrow8;
  const short* gA[4];
  const short* gB[4];
#pragma unroll
  for (int i = 0; i < 4; i++) {
    int ar = m0 + wid * 32 + i * 8 + lrow8;
    if (ar >= M) ar = M - 1;
    gA[i] = A + (size_t)ar * lda + lseg * 8;
    int br = n0 + wid * 32 + i * 8 + lrow8;
    gB[i] = BT + (size_t)br * ldb + lseg * 8;
  }

  const int NIT = K >> 6;
#pragma unroll
  for (int i = 0; i < 4; i++) {
    gload16(gA[i], &At[0][(wid * 32 + i * 8) * 64]);
    gload16(gB[i], &Bt[0][(wid * 32 + i * 8) * 64]);
  }
  __syncthreads();

  int fr = lane & 15, q = lane >> 4;
  for (int it = 0; it < NIT; ++it) {
    int cur = it & 1;
    if (it + 1 < NIT) {
      int nxt = cur ^ 1;
      int k0 = (it + 1) << 6;
#pragma unroll
      for (int i = 0; i < 4; i++) {
        gload16(gA[i] + k0, &At[nxt][(wid * 32 + i * 8) * 64]);
        gload16(gB[i] + k0, &Bt[nxt][(wid * 32 + i * 8) * 64]);
      }
    }
    const short* Ab = At[cur];
    const short* Bb = Bt[cur];
#pragma unroll
    for (int kk = 0; kk < 2; kk++) {
      int sg = ((q + kk * 4) ^ (fr & 7)) * 8;
      short8 af[4], bf[4];
#pragma unroll
      for (int mr = 0; mr < 4; mr++)
        af[mr] = *(const short8*)&Ab[(wr * 64 + mr * 16 + fr) * 64 + sg];
#pragma unroll
      for (int nc = 0; nc < 4; nc++)
        bf[nc] = *(const short8*)&Bb[(wc * 64 + nc * 16 + fr) * 64 + sg];
#pragma unroll
      for (int mr = 0; mr < 4; mr++)
#pragma unroll
        for (int nc = 0; nc < 4; nc++)
          acc[mr][nc] = __builtin_amdgcn_mfma_f32_16x16x32_bf16(af[mr], bf[nc], acc[mr][nc], 0, 0, 0);
    }
    __syncthreads();
  }

  int rsub = q * 4;
#pragma unroll
  for (int nc = 0; nc < 4; nc++) {
    int col = n0 + wc * 64 + nc * 16 + fr;
    float bv = (MODE == 3) ? 0.f : bias[col];
#pragma unroll
    for (int mr = 0; mr < 4; mr++) {
#pragma unroll
      for (int e = 0; e < 4; e++) {
        int r = m0 + wr * 64 + mr * 16 + rsub + e;
        if (r < M) {
          float v = acc[mr][nc][e] + bv;
          if (MODE == 0 || MODE == 3) {
            ((float*)p.out[z])[(size_t)r * N + col] = v;
          } else {
            float gg = 0.5f * v * (1.f + erff(v * 0.70710678118654752f));
            ((bf16*)p.out[z])[(size_t)r * N + col] = __float2bfloat16(gg);
          }
        }
      }
    }
  }
}

// 64x128 block, 4 waves x 32x64, BK=64, dbuf, swizzle (Wo / FFN2 split-K fill)
template <int MODE>
__global__ __launch_bounds__(256, 3) void k_gemm64(const short* __restrict__ A, GemmPtrs p,
                                                   int M, int N, int K, int lda, int ldb) {
  __shared__ short At[2][64 * 64];
  __shared__ short Bt[2][128 * 64];
  int z = blockIdx.z;
  const short* BT = p.bt[z];
  const float* bias = p.bias[z];
  A += p.aoff[z];
  int m0 = blockIdx.x * 64, n0 = blockIdx.y * 128;
  int t = threadIdx.x, lane = t & 63, wid = t >> 6;
  int wr = wid >> 1, wc = wid & 1;
  f32x4 acc[2][4];
#pragma unroll
  for (int a = 0; a < 2; a++)
#pragma unroll
    for (int c = 0; c < 4; c++) acc[a][c] = (f32x4){0.f, 0.f, 0.f, 0.f};

  int lrow8 = lane >> 3;
  int lseg = (lane & 7) ^ lrow8;
  const short* gA[2];
  const short* gB[4];
#pragma unroll
  for (int i = 0; i < 2; i++) {
    int ar = m0 + wid * 16 + i * 8 + lrow8;
    if (ar >= M) ar = M - 1;
    gA[i] = A + (size_t)ar * lda + lseg * 8;
  }
#pragma unroll
  for (int i = 0; i < 4; i++) {
    int br = n0 + wid * 32 + i * 8 + lrow8;
    gB[i] = BT + (size_t)br * ldb + lseg * 8;
  }

  const int NIT = K >> 6;
#pragma unroll
  for (int i = 0; i < 2; i++) gload16(gA[i], &At[0][(wid * 16 + i * 8) * 64]);
#pragma unroll
  for (int i = 0; i < 4; i++) gload16(gB[i], &Bt[0][(wid * 32 + i * 8) * 64]);
  __syncthreads();

  int fr = lane & 15, q = lane >> 4;
  for (int it = 0; it < NIT; ++it) {
    int cur = it & 1;
    if (it + 1 < NIT) {
      int nxt = cur ^ 1;
      int k0 = (it + 1) << 6;
#pragma unroll
      for (int i = 0; i < 2; i++) gload16(gA[i] + k0, &At[nxt][(wid * 16 + i * 8) * 64]);
#pragma unroll
      for (int i = 0; i < 4; i++) gload16(gB[i] + k0, &Bt[nxt][(wid * 32 + i * 8) * 64]);
    }
    const short* Ab = At[cur];
    const short* Bb = Bt[cur];
#pragma unroll
    for (int kk = 0; kk < 2; kk++) {
      int sg = ((q + kk * 4) ^ (fr & 7)) * 8;
      short8 af[2], bf[4];
#pragma unroll
      for (int mr = 0; mr < 2; mr++)
        af[mr] = *(const short8*)&Ab[(wr * 32 + mr * 16 + fr) * 64 + sg];
#pragma unroll
      for (int nc = 0; nc < 4; nc++)
        bf[nc] = *(const short8*)&Bb[(wc * 64 + nc * 16 + fr) * 64 + sg];
#pragma unroll
      for (int mr = 0; mr < 2; mr++)
#pragma unroll
        for (int nc = 0; nc < 4; nc++)
          acc[mr][nc] = __builtin_amdgcn_mfma_f32_16x16x32_bf16(af[mr], bf[nc], acc[mr][nc], 0, 0, 0);
    }
    __syncthreads();
  }

  int rsub = q * 4;
#pragma unroll
  for (int nc = 0; nc < 4; nc++) {
    int col = n0 + wc * 64 + nc * 16 + fr;
    float bv = (MODE == 3) ? 0.f : bias[col];
#pragma unroll
    for (int mr = 0; mr < 2; mr++) {
#pragma unroll
      for (int e = 0; e < 4; e++) {
        int r = m0 + wr * 32 + mr * 16 + rsub + e;
        if (r < M) {
          float v = acc[mr][nc][e] + bv;
          if (MODE == 0 || MODE == 3) {
            ((float*)p.out[z])[(size_t)r * N + col] = v;
          } else {
            float gg = 0.5f * v * (1.f + erff(v * 0.70710678118654752f));
            ((bf16*)p.out[z])[(size_t)r * N + col] = __float2bfloat16(gg);
          }
        }
      }
    }
  }
}

// ---------------- attention: block per (b,h,qchunk), conflict-free LDS ----------------
__global__ __launch_bounds__(256) void k_attn(const float* __restrict__ Q,
                                              const float* __restrict__ Kb,
                                              const float* __restrict__ Vb,
                                              const float* __restrict__ gab,
                                              bf16* __restrict__ ctx) {
  int bh = blockIdx.x;
  int qc = blockIdx.y;  // 0..1
  int b = bh / NH, hh = bh % NH;
  __shared__ float Kl[129][33];
  __shared__ float Vl[129][33];
  __shared__ float pl[4][132];
  int t = threadIdx.x;
  for (int idx = t; idx < 129 * 8; idx += 256) {
    int ks = idx >> 3, seg = idx & 7;
    size_t src = ((size_t)(b * SQ + ks)) * DM + hh * 32 + seg * 4;
    f32x4 kv = *(const f32x4*)&Kb[src];
    f32x4 vv = *(const f32x4*)&Vb[src];
    int dd = seg * 4;
    Kl[ks][dd] = kv[0]; Kl[ks][dd + 1] = kv[1]; Kl[ks][dd + 2] = kv[2]; Kl[ks][dd + 3] = kv[3];
    Vl[ks][dd] = vv[0]; Vl[ks][dd + 1] = vv[1]; Vl[ks][dd + 2] = vv[2]; Vl[ks][dd + 3] = vv[3];
  }
  __syncthreads();
  int w = t >> 6, lane = t & 63;
  int gw = qc * 4 + w;  // 0..7
  const float scale = 0.17677669529663689f;  // 1/sqrt(32)
  int kg = lane >> 5, dd = lane & 31;
  for (int q = gw; q < SQ; q += 8) {
    const float* qrow = Q + ((size_t)(b * SQ + q)) * DM + hh * 32;
    float qv[32];
#pragma unroll
    for (int d = 0; d < 32; d += 4) {
      f32x4 v4 = *(const f32x4*)&qrow[d];
      qv[d] = v4[0]; qv[d + 1] = v4[1]; qv[d + 2] = v4[2]; qv[d + 3] = v4[3];
    }
    const float* grow = gab + (((size_t)(b * NH + hh)) * SQ + q) * SQ;
    float s0a = 0.f, s0b = 0.f, s1a = 0.f, s1b = 0.f;
#pragma unroll
    for (int d = 0; d < 32; d += 2) {
      s0a += qv[d] * Kl[lane][d];
      s0b += qv[d + 1] * Kl[lane][d + 1];
      s1a += qv[d] * Kl[lane + 64][d];
      s1b += qv[d + 1] * Kl[lane + 64][d + 1];
    }
    float sc0 = (s0a + s0b) * scale + grow[lane];
    float sc1 = (s1a + s1b) * scale + grow[lane + 64];
    float sc2 = -1e30f;
    if (lane == 0) {
      float sa = 0.f, sb = 0.f;
#pragma unroll
      for (int d = 0; d < 32; d += 2) { sa += qv[d] * Kl[128][d]; sb += qv[d + 1] * Kl[128][d + 1]; }
      sc2 = (sa + sb) * scale + grow[128];
    }
    float m = fmaxf(sc0, fmaxf(sc1, sc2));
#pragma unroll
    for (int o = 32; o > 0; o >>= 1) m = fmaxf(m, __shfl_xor(m, o));
    float e0 = __expf(sc0 - m), e1 = __expf(sc1 - m);
    float e2 = (lane == 0) ? __expf(sc2 - m) : 0.f;
    float sum = e0 + e1 + e2;
#pragma unroll
    for (int o = 32; o > 0; o >>= 1) sum += __shfl_xor(sum, o);
    float inv = 1.f / sum;
    pl[w][lane] = e0 * inv;
    pl[w][lane + 64] = e1 * inv;
    if (lane == 0) pl[w][128] = e2 * inv;
    asm volatile("s_waitcnt lgkmcnt(0)" ::: "memory");
    float a = 0.f;
    int kbase = kg * 64;
#pragma unroll 8
    for (int i = 0; i < 64; i++) a += pl[w][kbase + i] * Vl[kbase + i][dd];
    a += __shfl_xor(a, 32);
    if (lane < 32) {
      a += pl[w][128] * Vl[128][dd];
      ctx[((size_t)(b * SQ + q)) * DM + hh * 32 + dd] = __float2bfloat16(a);
    }
  }
}

// ---------------- final: h_row0 + p0 + p1 + cbias -> LN -> project ----------------
__global__ void k_final_add2(const float* __restrict__ h, const float* __restrict__ p0,
                             const float* __restrict__ p1, const float* __restrict__ cb,
                             const float* __restrict__ g, const float* __restrict__ bb,
                             const float* __restrict__ ow, const float* __restrict__ ob,
                             float* __restrict__ out) {
  int b = blockIdx.x;
  int t = threadIdx.x, lane = t & 63, wid = t >> 6;
  __shared__ float red[8];
  __shared__ float yn[768];
  size_t base = (size_t)(b * SQ) * DM;
  float v0 = h[base + t] + p0[base + t] + p1[base + t] + cb[t];
  float v1 = h[base + t + 256] + p0[base + t + 256] + p1[base + t + 256] + cb[t + 256];
  float v2 = h[base + t + 512] + p0[base + t + 512] + p1[base + t + 512] + cb[t + 512];
  float s = v0 + v1 + v2;
#pragma unroll
  for (int o = 32; o > 0; o >>= 1) s += __shfl_xor(s, o);
  if (lane == 0) red[wid] = s;
  __syncthreads();
  float mean = (red[0] + red[1] + red[2] + red[3]) * (1.f / 768.f);
  float d0 = v0 - mean, d1 = v1 - mean, d2 = v2 - mean;
  float q = d0 * d0 + d1 * d1 + d2 * d2;
#pragma unroll
  for (int o = 32; o > 0; o >>= 1) q += __shfl_xor(q, o);
  if (lane == 0) red[4 + wid] = q;
  __syncthreads();
  float var = (red[4] + red[5] + red[6] + red[7]) * (1.f / 768.f);
  float rstd = rsqrtf(var + 1e-5f);
  yn[t] = d0 * rstd * g[t] + bb[t];
  yn[t + 256] = d1 * rstd * g[t + 256] + bb[t + 256];
  yn[t + 512] = d2 * rstd * g[t + 512] + bb[t + 512];
  __syncthreads();
  if (t < 128) {
    float acc = ob[t];
    for (int d = 0; d < 768; d++) acc += yn[d] * ow[d * 128 + t];
    out[b * 128 + t] = acc;
  }
}

extern "C" void kernel_launch(void* const* d_in, const int* in_sizes, int n_in,
                              void* d_out, int out_size, void* d_ws, size_t ws_size,
                              hipStream_t stream) {
  (void)in_sizes; (void)n_in; (void)out_size;
  const int* x     = (const int*)d_in[0];
  const int* ind   = (const int*)d_in[1];
  const int* outd  = (const int*)d_in[2];
  const int* spos  = (const int*)d_in[3];
  const int* eidx  = (const int*)d_in[4];
  const float* ab   = (const float*)d_in[5];
  const float* atom = (const float*)d_in[6];
  const float* ide  = (const float*)d_in[7];
  const float* ode  = (const float*)d_in[8];
  const float* gtok = (const float*)d_in[9];
  const float* eemb = (const float*)d_in[10];
  const float* edemb= (const float*)d_in[11];
  const float* semb = (const float*)d_in[12];
  const float* virt = (const float*)d_in[13];
  const float* ln1g = (const float*)d_in[14];
  const float* ln1b = (const float*)d_in[15];
  const float* wq  = (const float*)d_in[16];
  const float* bq   = (const float*)d_in[17];
  const float* wk  = (const float*)d_in[18];
  const float* bk   = (const float*)d_in[19];
  const float* wv  = (const float*)d_in[20];
  const float* bv   = (const float*)d_in[21];
  const float* wo  = (const float*)d_in[22];
  const float* bo   = (const float*)d_in[23];
  const float* ln2g = (const float*)d_in[24];
  const float* ln2b = (const float*)d_in[25];
  const float* w1  = (const float*)d_in[26];
  const float* b1   = (const float*)d_in[27];
  const float* w2  = (const float*)d_in[28];
  const float* b2   = (const float*)d_in[29];
  const float* fg   = (const float*)d_in[30];
  const float* fb   = (const float*)d_in[31];
  const float* ow   = (const float*)d_in[32];
  const float* ob   = (const float*)d_in[33];
  float* out = (float*)d_out;

  const int DD2 = DM * DM;
  const size_t WQKVO = (size_t)DD2;
  const size_t WFF = (size_t)DM * DF;

  char* ws = (char*)d_ws;
  size_t off = 0;
  auto alloc = [&](size_t bytes) -> void* {
    void* p = ws + off;
    off += (bytes + 255) & ~(size_t)255;
    return p;
  };
  float* gab = (float*)alloc((size_t)NB * NH * SQ * SQ * 4);
  float* h   = (float*)alloc((size_t)MROWS * DM * 4);
  bf16* y    = (bf16*)alloc((size_t)MROWS * DM * 2);
  float* qb  = (float*)alloc((size_t)MROWS * DM * 4);
  float* kb2 = (float*)alloc((size_t)MROWS * DM * 4);
  float* vb2 = (float*)alloc((size_t)MROWS * DM * 4);
  bf16* ctx  = (bf16*)alloc((size_t)MROWS * DM * 2);
  bf16* t1   = (bf16*)alloc((size_t)MROWS * DF * 2);
  float* p0 = qb;
  float* p1 = kb2;

  size_t need_hoist = off + ((size_t)NLAY * 4 * WQKVO + 2 * (size_t)NLAY * WFF) * 2 + (1 << 20);
  bool hoist = ws_size >= need_hoist;
  short* wT  = (short*)alloc((hoist ? (size_t)NLAY * 4 * WQKVO : 4 * WQKVO) * 2);
  short* w1T = (short*)alloc((hoist ? (size_t)NLAY * WFF : WFF) * 2);
  short* w2T = (short*)alloc((hoist ? (size_t)NLAY * WFF : WFF) * 2);

  dim3 blk(256);
  k_nodefeat<<<dim3(NB * SQ), blk, 0, stream>>>(x, ind, outd, atom, ide, ode, gtok, h);
  k_gab_border<<<dim3(NB), blk, 0, stream>>>(ab, virt, gab);
  k_gab_edge<<<dim3(NB * ND * 2), blk, 0, stream>>>(spos, eidx, eemb, edemb, semb, ab, gab);

  if (hoist) {
    Ptrs4 pq; pq.p[0] = wq; pq.p[1] = wk; pq.p[2] = wv; pq.p[3] = wo;
    k_transpose<4><<<dim3(12, 12, 48), blk, 0, stream>>>(pq, wT, DM, DM, WQKVO);
    Ptrs4 pa; pa.p[0] = w1; pa.p[1] = pa.p[2] = pa.p[3] = w1;
    k_transpose<1><<<dim3(12, 48, 12), blk, 0, stream>>>(pa, w1T, DM, DF, WFF);
    Ptrs4 pb; pb.p[0] = w2; pb.p[1] = pb.p[2] = pb.p[3] = w2;
    k_transpose<1><<<dim3(48, 12, 12), blk, 0, stream>>>(pb, w2T, DF, DM, WFF);
  }

  for (int l = 0; l < NLAY; l++) {
    if (!hoist) {
      Ptrs4 pq;
      pq.p[0] = wq + (size_t)l * DD2; pq.p[1] = wk + (size_t)l * DD2;
      pq.p[2] = wv + (size_t)l * DD2; pq.p[3] = wo + (size_t)l * DD2;
      k_transpose<4><<<dim3(12, 12, 4), blk, 0, stream>>>(pq, wT, DM, DM, 0);
      Ptrs4 pa; pa.p[0] = w1 + (size_t)l * WFF; pa.p[1] = pa.p[2] = pa.p[3] = pa.p[0];
      k_transpose<1><<<dim3(12, 48, 1), blk, 0, stream>>>(pa, w1T, DM, DF, 0);
      Ptrs4 pb; pb.p[0] = w2 + (size_t)l * WFF; pb.p[1] = pb.p[2] = pb.p[3] = pb.p[0];
      k_transpose<1><<<dim3(48, 12, 1), blk, 0, stream>>>(pb, w2T, DF, DM, 0);
    }
    const short* wTl  = wT  + (hoist ? (size_t)l * 4 * WQKVO : 0);
    const short* w1Tl = w1T + (hoist ? (size_t)l * WFF : 0);
    const short* w2Tl = w2T + (hoist ? (size_t)l * WFF : 0);

    if (l == 0)
      k_ln<<<dim3(MROWS), blk, 0, stream>>>(h, ln1g, ln1b, y);

    GemmPtrs gq;
    gq.bt[0] = wTl; gq.bt[1] = wTl + DD2; gq.bt[2] = wTl + 2 * DD2;
    gq.bias[0] = bq + l * DM; gq.bias[1] = bk + l * DM; gq.bias[2] = bv + l * DM;
    gq.out[0] = qb; gq.out[1] = kb2; gq.out[2] = vb2;
    gq.aoff[0] = gq.aoff[1] = gq.aoff[2] = 0;
    k_gemm128<0><<<dim3(17, 6, 3), blk, 0, stream>>>((const short*)y, gq, MROWS, DM, DM, DM, DM);

    k_attn<<<dim3(NB * NH, 2), blk, 0, stream>>>(qb, kb2, vb2, gab, ctx);

    GemmPtrs go;  // Wo split-K: K=768 -> 2 x 384, 64-row tiles for fill
    go.bt[0] = wTl + 3 * DD2; go.bt[1] = wTl + 3 * DD2 + 384;
    go.bias[0] = go.bias[1] = nullptr;
    go.out[0] = p0; go.out[1] = p1;
    go.aoff[0] = 0; go.aoff[1] = 384;
    go.bt[2] = go.bt[0]; go.out[2] = p0; go.aoff[2] = 0; go.bias[2] = nullptr;
    k_gemm64<3><<<dim3(33, 6, 2), blk, 0, stream>>>((const short*)ctx, go, MROWS, DM, 384, DM, DM);

    k_ln_add2<<<dim3(MROWS), blk, 0, stream>>>(h, p0, p1, bo + l * DM,
                                               ln2g + l * DM, ln2b + l * DM, y);

    GemmPtrs g1;
    g1.bt[0] = g1.bt[1] = g1.bt[2] = w1Tl;
    g1.bias[0] = g1.bias[1] = g1.bias[2] = b1 + l * DF;
    g1.out[0] = g1.out[1] = g1.out[2] = t1;
    g1.aoff[0] = g1.aoff[1] = g1.aoff[2] = 0;
    k_gemm128<2><<<dim3(17, 24, 1), blk, 0, stream>>>((const short*)y, g1, MROWS, DF, DM, DM, DM);

    GemmPtrs g2;  // FFN2 split-K: K=3072 -> 2 x 1536, 64-row tiles for fill
    g2.bt[0] = w2Tl; g2.bt[1] = w2Tl + 1536;
    g2.bias[0] = g2.bias[1] = nullptr;
    g2.out[0] = p0; g2.out[1] = p1;
    g2.aoff[0] = 0; g2.aoff[1] = 1536;
    g2.bt[2] = g2.bt[0]; g2.out[2] = p0; g2.aoff[2] = 0; g2.bias[2] = nullptr;
    k_gemm64<3><<<dim3(33, 6, 2), blk, 0, stream>>>((const short*)t1, g2, MROWS, DM, 1536, DF, DF);

    if (l < NLAY - 1) {
      k_ln_add2<<<dim3(MROWS), blk, 0, stream>>>(h, p0, p1, b2 + l * DM,
                                                 ln1g + (l + 1) * DM, ln1b + (l + 1) * DM, y);
    } else {
      k_final_add2<<<dim3(NB), blk, 0, stream>>>(h, p0, p1, b2 + l * DM, fg, fb, ow, ob, out);
    }
  }
}

// Round 8
// 1702.105 us; speedup vs baseline: 2.2858x; 1.2316x over previous
//
#include <hip/hip_runtime.h>
#include <hip/hip_bf16.h>
#include <math.h>

typedef __hip_bfloat16 bf16;
typedef __attribute__((ext_vector_type(8))) short short8;
typedef __attribute__((ext_vector_type(4))) short short4v;
typedef __attribute__((ext_vector_type(4))) float f32x4;

constexpr int NB = 16;     // batch
constexpr int ND = 128;    // nodes N
constexpr int SQ = 129;    // S = N+1
constexpr int NH = 24;     // heads
constexpr int DM = 768;    // model dim
constexpr int DF = 3072;   // ffn dim
constexpr int NLAY = 12;
constexpr int MROWS = NB * SQ;  // 2064

__device__ __forceinline__ short f2bs(float f) {
  bf16 h = __float2bfloat16(f);
  return *(short*)&h;
}

__device__ __forceinline__ void gload16(const void* g, void* lds) {
  __builtin_amdgcn_global_load_lds(
      (const __attribute__((address_space(1))) unsigned int*)g,
      (__attribute__((address_space(3))) unsigned int*)lds, 16, 0, 0);
}

// ---------------- node features ----------------
__global__ void k_nodefeat(const int* __restrict__ x, const int* __restrict__ ind,
                           const int* __restrict__ outd,
                           const float* __restrict__ atom, const float* __restrict__ ide,
                           const float* __restrict__ ode, const float* __restrict__ gtok,
                           float* __restrict__ h) {
  int bs = blockIdx.x;
  int b = bs / SQ, s = bs % SQ;
  int t = threadIdx.x;
  float* hrow = h + (size_t)bs * DM;
  if (s == 0) {
    for (int c = t; c < DM; c += 256) hrow[c] = gtok[c];
  } else {
    int n = s - 1;
    const int* xr = x + (b * ND + n) * 9;
    int a0 = xr[0], a1 = xr[1], a2 = xr[2], a3 = xr[3], a4 = xr[4];
    int a5 = xr[5], a6 = xr[6], a7 = xr[7], a8 = xr[8];
    int ii = ind[b * ND + n], oo = outd[b * ND + n];
    for (int c = t; c < DM; c += 256) {
      float acc = ide[(size_t)ii * DM + c] + ode[(size_t)oo * DM + c];
      acc += atom[(size_t)a0 * DM + c];
      acc += atom[(size_t)a1 * DM + c];
      acc += atom[(size_t)a2 * DM + c];
      acc += atom[(size_t)a3 * DM + c];
      acc += atom[(size_t)a4 * DM + c];
      acc += atom[(size_t)a5 * DM + c];
      acc += atom[(size_t)a6 * DM + c];
      acc += atom[(size_t)a7 * DM + c];
      acc += atom[(size_t)a8 * DM + c];
      hrow[c] = acc;
    }
  }
}

// ---------------- gab: virtual-token borders ----------------
__global__ void k_gab_border(const float* __restrict__ ab, const float* __restrict__ virt,
                             float* __restrict__ gab) {
  int b = blockIdx.x;
  const int tot = NH * SQ + NH * ND;
  for (int idx = threadIdx.x; idx < tot; idx += 256) {
    if (idx < NH * SQ) {
      int hh = idx / SQ, j = idx % SQ;
      float v = 2.f * ab[((size_t)b * SQ + 0) * SQ + j] + virt[hh];
      gab[(((size_t)b * NH + hh) * SQ + 0) * SQ + j] = v;
    } else {
      int r = idx - NH * SQ;
      int hh = r / ND, i = r % ND + 1;
      float v = 2.f * ab[((size_t)b * SQ + i) * SQ + 0] + virt[hh];
      gab[(((size_t)b * NH + hh) * SQ + i) * SQ + 0] = v;
    }
  }
}

// ---------------- gab: spatial + multihop edge bias (MFMA, coalesced writes) ----
__global__ __launch_bounds__(256) void k_gab_edge(
    const int* __restrict__ spos, const int* __restrict__ eidx,
    const float* __restrict__ eemb, const float* __restrict__ edemb,
    const float* __restrict__ semb, const float* __restrict__ ab,
    float* __restrict__ gab) {
  __shared__ int eidxs[960];       // 64 j x 5 d x 3 f
  __shared__ short ei2[64 * 136];  // bf16 [j][dh]
  __shared__ short edT[32 * 136];  // bf16 [k][dh]
  __shared__ float ot[24][65];     // raw MFMA out [k][j], padded
  __shared__ float rinvA[64], a2A[64];
  __shared__ int spA[64];
  int bi = blockIdx.x;
  int half = bi & 1;
  int i = (bi >> 1) & 127;
  int b = bi >> 8;
  int j0 = half * 64;
  int t = threadIdx.x;
  const size_t rowbase = ((size_t)(b * ND + i)) * ND + j0;

  const int* esrc = eidx + rowbase * 15;
  for (int idx = t; idx < 960; idx += 256) eidxs[idx] = esrc[idx];
  for (int u = t; u < 720; u += 256) {
    int dh = u / 6, kq = u % 6;
    f32x4 v = *(const f32x4*)&edemb[dh * 24 + kq * 4];
    edT[(kq * 4 + 0) * 136 + dh] = f2bs(v[0]);
    edT[(kq * 4 + 1) * 136 + dh] = f2bs(v[1]);
    edT[(kq * 4 + 2) * 136 + dh] = f2bs(v[2]);
    edT[(kq * 4 + 3) * 136 + dh] = f2bs(v[3]);
  }
  for (int u = t; u < 1472; u += 256) {
    int k, dh;
    if (u < 384) { k = u >> 4; dh = 120 + (u & 15); }
    else { int v = u - 384; k = 24 + v / 136; dh = v % 136; }
    edT[k * 136 + dh] = 0;
  }
  if (t < 64) {
    int j = t;
    int sp = spos[rowbase + j];
    int spc = (sp == 0) ? 1 : sp;
    spc = (spc > 1) ? spc - 1 : spc;
    if (spc > 5) spc = 5;
    spA[j] = sp;
    rinvA[j] = 1.f / (float)spc;
    a2A[j] = 2.f * ab[((size_t)b * SQ + (i + 1)) * SQ + (j0 + j + 1)];
  }
  __syncthreads();

  {
    int j = t & 63, d = t >> 6;
#pragma unroll
    for (int pass = 0; pass < 2; pass++) {
      if (pass == 1) {
        if (t >= 64) break;
        j = t; d = 4;
      }
      const int* ep = &eidxs[j * 15 + d * 3];
      const float* r0 = eemb + (size_t)ep[0] * NH;
      const float* r1 = eemb + (size_t)ep[1] * NH;
      const float* r2 = eemb + (size_t)ep[2] * NH;
#pragma unroll
      for (int hq = 0; hq < 6; hq++) {
        f32x4 s = (*(const f32x4*)&r0[hq * 4] + *(const f32x4*)&r1[hq * 4] +
                   *(const f32x4*)&r2[hq * 4]) * (1.f / 3.f);
        short4v o;
        o[0] = f2bs(s[0]); o[1] = f2bs(s[1]); o[2] = f2bs(s[2]); o[3] = f2bs(s[3]);
        *(short4v*)&ei2[j * 136 + d * 24 + hq * 4] = o;
      }
    }
  }
  for (int idx = t; idx < 64 * 8; idx += 256) {
    int j = idx >> 3;
    ei2[j * 136 + 120 + (idx & 7)] = 0;
  }
  __syncthreads();

  int lane = t & 63, w = t >> 6;
  int fr = lane & 15, q = lane >> 4, fo = q * 8;
  f32x4 acc0 = {0.f, 0.f, 0.f, 0.f}, acc1 = {0.f, 0.f, 0.f, 0.f};
#pragma unroll
  for (int kk = 0; kk < 4; kk++) {
    short8 af = *(const short8*)&ei2[(w * 16 + fr) * 136 + kk * 32 + fo];
    short8 b0 = *(const short8*)&edT[(fr) * 136 + kk * 32 + fo];
    short8 b1 = *(const short8*)&edT[(16 + fr) * 136 + kk * 32 + fo];
    acc0 = __builtin_amdgcn_mfma_f32_16x16x32_bf16(af, b0, acc0, 0, 0, 0);
    acc1 = __builtin_amdgcn_mfma_f32_16x16x32_bf16(af, b1, acc1, 0, 0, 0);
  }
#pragma unroll
  for (int e = 0; e < 4; e++) {
    int j = w * 16 + q * 4 + e;
    ot[fr][j] = acc0[e];
    if (fr < 8) ot[16 + fr][j] = acc1[e];
  }
  __syncthreads();
  size_t obase = (((size_t)b * NH) * SQ + (i + 1)) * SQ + (j0 + 1);
  for (int idx = t; idx < 24 * 64; idx += 256) {
    int k = idx >> 6, j = idx & 63;
    float v = a2A[j] + semb[spA[j] * NH + k] + ot[k][j] * rinvA[j];
    gab[obase + (size_t)k * SQ * SQ + j] = v;
  }
}

// ---------------- weight transpose+cast: f32 [R,C] -> bf16 [C,R] ----------------
struct Ptrs4 { const float* p[4]; };

template <int NW>
__global__ void k_transpose(Ptrs4 ps, short* __restrict__ dst, int R, int C,
                            size_t sstride) {
  __shared__ short tile[64][68];
  int z = blockIdx.z;
  const float* src = ps.p[z % NW] + (size_t)(z / NW) * sstride;
  short* d = dst + (size_t)z * (size_t)R * C;
  int r0 = blockIdx.x * 64, c0 = blockIdx.y * 64;
  int t = threadIdx.x;
  int tr = t >> 4, tc = (t & 15) * 4;
#pragma unroll
  for (int i = 0; i < 4; i++) {
    int r = tr + i * 16;
    f32x4 v = *(const f32x4*)(src + (size_t)(r0 + r) * C + c0 + tc);
    tile[r][tc + 0] = f2bs(v[0]);
    tile[r][tc + 1] = f2bs(v[1]);
    tile[r][tc + 2] = f2bs(v[2]);
    tile[r][tc + 3] = f2bs(v[3]);
  }
  __syncthreads();
#pragma unroll
  for (int i = 0; i < 4; i++) {
    int rr = tr + i * 16;
    short4v o;
    o[0] = tile[tc + 0][rr];
    o[1] = tile[tc + 1][rr];
    o[2] = tile[tc + 2][rr];
    o[3] = tile[tc + 3][rr];
    *(short4v*)(d + (size_t)(c0 + rr) * R + r0 + tc) = o;
  }
}

// ---------------- LayerNorm: fp32 row -> bf16 row ----------------
__global__ void k_ln(const float* __restrict__ h, const float* __restrict__ g,
                     const float* __restrict__ bb, bf16* __restrict__ y) {
  int r = blockIdx.x;
  int t = threadIdx.x, lane = t & 63, wid = t >> 6;
  __shared__ float red[8];
  const float* row = h + (size_t)r * DM;
  float v0 = row[t], v1 = row[t + 256], v2 = row[t + 512];
  float s = v0 + v1 + v2;
#pragma unroll
  for (int o = 32; o > 0; o >>= 1) s += __shfl_xor(s, o);
  if (lane == 0) red[wid] = s;
  __syncthreads();
  float mean = (red[0] + red[1] + red[2] + red[3]) * (1.f / 768.f);
  float d0 = v0 - mean, d1 = v1 - mean, d2 = v2 - mean;
  float q = d0 * d0 + d1 * d1 + d2 * d2;
#pragma unroll
  for (int o = 32; o > 0; o >>= 1) q += __shfl_xor(q, o);
  if (lane == 0) red[4 + wid] = q;
  __syncthreads();
  float var = (red[4] + red[5] + red[6] + red[7]) * (1.f / 768.f);
  float rstd = rsqrtf(var + 1e-5f);
  bf16* yr = y + (size_t)r * DM;
  yr[t] = __float2bfloat16(d0 * rstd * g[t] + bb[t]);
  yr[t + 256] = __float2bfloat16(d1 * rstd * g[t + 256] + bb[t + 256]);
  yr[t + 512] = __float2bfloat16(d2 * rstd * g[t + 512] + bb[t + 512]);
}

// ---------------- fused: h += p0+p1+cbias; y = LN(h) ----------------
__global__ void k_ln_add2(float* __restrict__ h, const float* __restrict__ p0,
                          const float* __restrict__ p1, const float* __restrict__ cb,
                          const float* __restrict__ g, const float* __restrict__ bb,
                          bf16* __restrict__ y) {
  int r = blockIdx.x;
  int t = threadIdx.x, lane = t & 63, wid = t >> 6;
  __shared__ float red[8];
  size_t base = (size_t)r * DM;
  float v0 = h[base + t] + p0[base + t] + p1[base + t] + cb[t];
  float v1 = h[base + t + 256] + p0[base + t + 256] + p1[base + t + 256] + cb[t + 256];
  float v2 = h[base + t + 512] + p0[base + t + 512] + p1[base + t + 512] + cb[t + 512];
  h[base + t] = v0;
  h[base + t + 256] = v1;
  h[base + t + 512] = v2;
  float s = v0 + v1 + v2;
#pragma unroll
  for (int o = 32; o > 0; o >>= 1) s += __shfl_xor(s, o);
  if (lane == 0) red[wid] = s;
  __syncthreads();
  float mean = (red[0] + red[1] + red[2] + red[3]) * (1.f / 768.f);
  float d0 = v0 - mean, d1 = v1 - mean, d2 = v2 - mean;
  float q = d0 * d0 + d1 * d1 + d2 * d2;
#pragma unroll
  for (int o = 32; o > 0; o >>= 1) q += __shfl_xor(q, o);
  if (lane == 0) red[4 + wid] = q;
  __syncthreads();
  float var = (red[4] + red[5] + red[6] + red[7]) * (1.f / 768.f);
  float rstd = rsqrtf(var + 1e-5f);
  bf16* yr = y + base;
  yr[t] = __float2bfloat16(d0 * rstd * g[t] + bb[t]);
  yr[t + 256] = __float2bfloat16(d1 * rstd * g[t + 256] + bb[t + 256]);
  yr[t + 512] = __float2bfloat16(d2 * rstd * g[t + 512] + bb[t + 512]);
}

// ---------------- GEMM common ----------------
// MODE 0: fp32+bias; MODE 2: GELU->bf16; MODE 3: raw fp32; MODE 4: bf16+bias
struct GemmPtrs {
  const short* bt[3];
  const float* bias[3];
  void* out[3];
  int aoff[3];
};

template <int MODE>
__device__ __forceinline__ void gemm_store(void* outp, size_t idx, float v) {
  if (MODE == 0 || MODE == 3) {
    ((float*)outp)[idx] = v;
  } else if (MODE == 4) {
    ((bf16*)outp)[idx] = __float2bfloat16(v);
  } else {
    float gg = 0.5f * v * (1.f + erff(v * 0.70710678118654752f));
    ((bf16*)outp)[idx] = __float2bfloat16(gg);
  }
}

// 128x128 block, 4 waves x 64x64, BK=64, dbuf, swizzle (QKV / FFN1)
template <int MODE>
__global__ __launch_bounds__(256, 2) void k_gemm128(const short* __restrict__ A, GemmPtrs p,
                                                    int M, int N, int K, int lda, int ldb) {
  __shared__ short At[2][128 * 64];
  __shared__ short Bt[2][128 * 64];
  int z = blockIdx.z;
  const short* BT = p.bt[z];
  const float* bias = p.bias[z];
  A += p.aoff[z];
  int m0 = blockIdx.x * 128, n0 = blockIdx.y * 128;
  int t = threadIdx.x, lane = t & 63, wid = t >> 6;
  int wr = wid >> 1, wc = wid & 1;
  f32x4 acc[4][4];
#pragma unroll
  for (int a = 0; a < 4; a++)
#pragma unroll
    for (int c = 0; c < 4; c++) acc[a][c] = (f32x4){0.f, 0.f, 0.f, 0.f};

  int lrow8 = lane >> 3;
  int lseg = (lane & 7) ^ lrow8;
  const short* gA[4];
  const short* gB[4];
#pragma unroll
  for (int i = 0; i < 4; i++) {
    int ar = m0 + wid * 32 + i * 8 + lrow8;
    if (ar >= M) ar = M - 1;
    gA[i] = A + (size_t)ar * lda + lseg * 8;
    int br = n0 + wid * 32 + i * 8 + lrow8;
    gB[i] = BT + (size_t)br * ldb + lseg * 8;
  }

  const int NIT = K >> 6;
#pragma unroll
  for (int i = 0; i < 4; i++) {
    gload16(gA[i], &At[0][(wid * 32 + i * 8) * 64]);
    gload16(gB[i], &Bt[0][(wid * 32 + i * 8) * 64]);
  }
  __syncthreads();

  int fr = lane & 15, q = lane >> 4;
  for (int it = 0; it < NIT; ++it) {
    int cur = it & 1;
    if (it + 1 < NIT) {
      int nxt = cur ^ 1;
      int k0 = (it + 1) << 6;
#pragma unroll
      for (int i = 0; i < 4; i++) {
        gload16(gA[i] + k0, &At[nxt][(wid * 32 + i * 8) * 64]);
        gload16(gB[i] + k0, &Bt[nxt][(wid * 32 + i * 8) * 64]);
      }
    }
    const short* Ab = At[cur];
    const short* Bb = Bt[cur];
#pragma unroll
    for (int kk = 0; kk < 2; kk++) {
      int sg = ((q + kk * 4) ^ (fr & 7)) * 8;
      short8 af[4], bf[4];
#pragma unroll
      for (int mr = 0; mr < 4; mr++)
        af[mr] = *(const short8*)&Ab[(wr * 64 + mr * 16 + fr) * 64 + sg];
#pragma unroll
      for (int nc = 0; nc < 4; nc++)
        bf[nc] = *(const short8*)&Bb[(wc * 64 + nc * 16 + fr) * 64 + sg];
#pragma unroll
      for (int mr = 0; mr < 4; mr++)
#pragma unroll
        for (int nc = 0; nc < 4; nc++)
          acc[mr][nc] = __builtin_amdgcn_mfma_f32_16x16x32_bf16(af[mr], bf[nc], acc[mr][nc], 0, 0, 0);
    }
    __syncthreads();
  }

  int rsub = q * 4;
#pragma unroll
  for (int nc = 0; nc < 4; nc++) {
    int col = n0 + wc * 64 + nc * 16 + fr;
    float bv = (MODE == 3) ? 0.f : bias[col];
#pragma unroll
    for (int mr = 0; mr < 4; mr++) {
#pragma unroll
      for (int e = 0; e < 4; e++) {
        int r = m0 + wr * 64 + mr * 16 + rsub + e;
        if (r < M) gemm_store<MODE>(p.out[z], (size_t)r * N + col, acc[mr][nc][e] + bv);
      }
    }
  }
}

// 64x128 block, 4 waves x 32x64, BK=64, dbuf, swizzle (Wo / FFN2 split-K fill)
template <int MODE>
__global__ __launch_bounds__(256, 3) void k_gemm64(const short* __restrict__ A, GemmPtrs p,
                                                   int M, int N, int K, int lda, int ldb) {
  __shared__ short At[2][64 * 64];
  __shared__ short Bt[2][128 * 64];
  int z = blockIdx.z;
  const short* BT = p.bt[z];
  const float* bias = p.bias[z];
  A += p.aoff[z];
  int m0 = blockIdx.x * 64, n0 = blockIdx.y * 128;
  int t = threadIdx.x, lane = t & 63, wid = t >> 6;
  int wr = wid >> 1, wc = wid & 1;
  f32x4 acc[2][4];
#pragma unroll
  for (int a = 0; a < 2; a++)
#pragma unroll
    for (int c = 0; c < 4; c++) acc[a][c] = (f32x4){0.f, 0.f, 0.f, 0.f};

  int lrow8 = lane >> 3;
  int lseg = (lane & 7) ^ lrow8;
  const short* gA[2];
  const short* gB[4];
#pragma unroll
  for (int i = 0; i < 2; i++) {
    int ar = m0 + wid * 16 + i * 8 + lrow8;
    if (ar >= M) ar = M - 1;
    gA[i] = A + (size_t)ar * lda + lseg * 8;
  }
#pragma unroll
  for (int i = 0; i < 4; i++) {
    int br = n0 + wid * 32 + i * 8 + lrow8;
    gB[i] = BT + (size_t)br * ldb + lseg * 8;
  }

  const int NIT = K >> 6;
#pragma unroll
  for (int i = 0; i < 2; i++) gload16(gA[i], &At[0][(wid * 16 + i * 8) * 64]);
#pragma unroll
  for (int i = 0; i < 4; i++) gload16(gB[i], &Bt[0][(wid * 32 + i * 8) * 64]);
  __syncthreads();

  int fr = lane & 15, q = lane >> 4;
  for (int it = 0; it < NIT; ++it) {
    int cur = it & 1;
    if (it + 1 < NIT) {
      int nxt = cur ^ 1;
      int k0 = (it + 1) << 6;
#pragma unroll
      for (int i = 0; i < 2; i++) gload16(gA[i] + k0, &At[nxt][(wid * 16 + i * 8) * 64]);
#pragma unroll
      for (int i = 0; i < 4; i++) gload16(gB[i] + k0, &Bt[nxt][(wid * 32 + i * 8) * 64]);
    }
    const short* Ab = At[cur];
    const short* Bb = Bt[cur];
#pragma unroll
    for (int kk = 0; kk < 2; kk++) {
      int sg = ((q + kk * 4) ^ (fr & 7)) * 8;
      short8 af[2], bf[4];
#pragma unroll
      for (int mr = 0; mr < 2; mr++)
        af[mr] = *(const short8*)&Ab[(wr * 32 + mr * 16 + fr) * 64 + sg];
#pragma unroll
      for (int nc = 0; nc < 4; nc++)
        bf[nc] = *(const short8*)&Bb[(wc * 64 + nc * 16 + fr) * 64 + sg];
#pragma unroll
      for (int mr = 0; mr < 2; mr++)
#pragma unroll
        for (int nc = 0; nc < 4; nc++)
          acc[mr][nc] = __builtin_amdgcn_mfma_f32_16x16x32_bf16(af[mr], bf[nc], acc[mr][nc], 0, 0, 0);
    }
    __syncthreads();
  }

  int rsub = q * 4;
#pragma unroll
  for (int nc = 0; nc < 4; nc++) {
    int col = n0 + wc * 64 + nc * 16 + fr;
    float bv = (MODE == 3) ? 0.f : bias[col];
#pragma unroll
    for (int mr = 0; mr < 2; mr++) {
#pragma unroll
      for (int e = 0; e < 4; e++) {
        int r = m0 + wr * 32 + mr * 16 + rsub + e;
        if (r < M) gemm_store<MODE>(p.out[z], (size_t)r * N + col, acc[mr][nc][e] + bv);
      }
    }
  }
}

// ---------------- attention: MFMA flash, one block per (b,h) ----------------
__global__ __launch_bounds__(256) void k_attn(const bf16* __restrict__ Q,
                                              const bf16* __restrict__ Kb,
                                              const bf16* __restrict__ Vb,
                                              const float* __restrict__ gab,
                                              bf16* __restrict__ ctx) {
  __shared__ short Ql[144 * 40];   // [row][k], rows 129+ zeroed
  __shared__ short Kl[144 * 40];   // [kk][k], rows 129+ zeroed
  __shared__ short Vt[32 * 168];   // [d][kk], kk 128+ zeroed
  __shared__ short Pc[144 * 40];   // P chunk [row][kk_local], wave-private rows
  int bh = blockIdx.x;
  int b = bh / NH, hh = bh % NH;
  int t = threadIdx.x;
  // zero Vt tail (kk in [128,168))
  for (int idx = t; idx < 32 * 40; idx += 256) {
    int d = idx / 40, kk = 128 + (idx % 40);
    Vt[d * 168 + kk] = 0;
  }
  // stage Q,K (129 rows x 4 segs of 8 bf16)
  for (int idx = t; idx < 129 * 4; idx += 256) {
    int s = idx >> 2, seg = idx & 3;
    size_t src = ((size_t)(b * SQ + s)) * DM + hh * 32 + seg * 8;
    *(short8*)&Ql[s * 40 + seg * 8] = *(const short8*)((const short*)Q + src);
    *(short8*)&Kl[s * 40 + seg * 8] = *(const short8*)((const short*)Kb + src);
  }
  // zero Q,K pad rows 129..143
  for (int idx = t; idx < 15 * 4; idx += 256) {
    int s = 129 + (idx >> 2), seg = idx & 3;
    short8 zz = {0, 0, 0, 0, 0, 0, 0, 0};
    *(short8*)&Ql[s * 40 + seg * 8] = zz;
    *(short8*)&Kl[s * 40 + seg * 8] = zz;
  }
  // V transpose into Vt[d][kk]
  for (int idx = t; idx < 129 * 4; idx += 256) {
    int kk = idx >> 2, seg = idx & 3;
    size_t src = ((size_t)(b * SQ + kk)) * DM + hh * 32 + seg * 8;
    short8 v = *(const short8*)((const short*)Vb + src);
#pragma unroll
    for (int j = 0; j < 8; j++) Vt[(seg * 8 + j) * 168 + kk] = v[j];
  }
  __syncthreads();

  int lane = t & 63, w = t >> 6;
  int c16 = lane & 15, q4 = lane >> 4;
  const float scale = 0.17677669529663689f;  // 1/sqrt(32)
  const float* gabp = gab + (((size_t)(b * NH + hh)) * SQ) * SQ;

  for (int mt = w; mt < 9; mt += 4) {
    // QK^T: 9 n-tiles, K=32 -> 1 MFMA each
    f32x4 sc[9];
    short8 aq = *(const short8*)&Ql[(mt * 16 + c16) * 40 + q4 * 8];
#pragma unroll
    for (int nt = 0; nt < 9; nt++) {
      short8 bk = *(const short8*)&Kl[(nt * 16 + c16) * 40 + q4 * 8];
      f32x4 zz = {0.f, 0.f, 0.f, 0.f};
      sc[nt] = __builtin_amdgcn_mfma_f32_16x16x32_bf16(aq, bk, zz, 0, 0, 0);
    }
    // bias + mask + softmax (per C-row e; cols live across 16 lanes x 9 tiles)
#pragma unroll
    for (int e = 0; e < 4; e++) {
      int row = mt * 16 + q4 * 4 + e;
      int rr = row < 129 ? row : 128;
      const float* grow = gabp + (size_t)rr * SQ;
      float mloc = -1e30f;
#pragma unroll
      for (int nt = 0; nt < 9; nt++) {
        int col = nt * 16 + c16;
        float s = (col < 129) ? (sc[nt][e] * scale + grow[col]) : -1e30f;
        sc[nt][e] = s;
        mloc = fmaxf(mloc, s);
      }
#pragma unroll
      for (int o = 1; o < 16; o <<= 1) mloc = fmaxf(mloc, __shfl_xor(mloc, o));
      float sum = 0.f;
#pragma unroll
      for (int nt = 0; nt < 9; nt++) {
        float pp = __expf(sc[nt][e] - mloc);
        sc[nt][e] = pp;
        sum += pp;
      }
#pragma unroll
      for (int o = 1; o < 16; o <<= 1) sum += __shfl_xor(sum, o);
      float inv = 1.f / sum;
#pragma unroll
      for (int nt = 0; nt < 9; nt++) sc[nt][e] *= inv;
    }
    // PV over 5 k-chunks of 32 (kk 129+ handled by zeros)
    f32x4 oacc0 = {0.f, 0.f, 0.f, 0.f}, oacc1 = {0.f, 0.f, 0.f, 0.f};
#pragma unroll
    for (int c = 0; c < 5; c++) {
#pragma unroll
      for (int u = 0; u < 2; u++) {
        int nt = c * 2 + u;
        if (nt < 9) {
#pragma unroll
          for (int e = 0; e < 4; e++)
            Pc[(mt * 16 + q4 * 4 + e) * 40 + u * 16 + c16] = f2bs(sc[nt][e]);
        } else {
#pragma unroll
          for (int e = 0; e < 4; e++)
            Pc[(mt * 16 + q4 * 4 + e) * 40 + u * 16 + c16] = 0;
        }
      }
      asm volatile("s_waitcnt lgkmcnt(0)" ::: "memory");
      __builtin_amdgcn_sched_barrier(0);
      short8 ap = *(const short8*)&Pc[(mt * 16 + c16) * 40 + q4 * 8];
      short8 bv0 = *(const short8*)&Vt[(c16) * 168 + c * 32 + q4 * 8];
      short8 bv1 = *(const short8*)&Vt[(16 + c16) * 168 + c * 32 + q4 * 8];
      oacc0 = __builtin_amdgcn_mfma_f32_16x16x32_bf16(ap, bv0, oacc0, 0, 0, 0);
      oacc1 = __builtin_amdgcn_mfma_f32_16x16x32_bf16(ap, bv1, oacc1, 0, 0, 0);
    }
    // store ctx rows < 129
#pragma unroll
    for (int e = 0; e < 4; e++) {
      int row = mt * 16 + q4 * 4 + e;
      if (row < 129) {
        size_t obase = ((size_t)(b * SQ + row)) * DM + hh * 32;
        ctx[obase + c16] = __float2bfloat16(oacc0[e]);
        ctx[obase + 16 + c16] = __float2bfloat16(oacc1[e]);
      }
    }
  }
}

// ---------------- final: h_row0 + p0 + p1 + cbias -> LN -> project ----------------
__global__ void k_final_add2(const float* __restrict__ h, const float* __restrict__ p0,
                             const float* __restrict__ p1, const float* __restrict__ cb,
                             const float* __restrict__ g, const float* __restrict__ bb,
                             const float* __restrict__ ow, const float* __restrict__ ob,
                             float* __restrict__ out) {
  int b = blockIdx.x;
  int t = threadIdx.x, lane = t & 63, wid = t >> 6;
  __shared__ float red[8];
  __shared__ float yn[768];
  size_t base = (size_t)(b * SQ) * DM;
  float v0 = h[base + t] + p0[base + t] + p1[base + t] + cb[t];
  float v1 = h[base + t + 256] + p0[base + t + 256] + p1[base + t + 256] + cb[t + 256];
  float v2 = h[base + t + 512] + p0[base + t + 512] + p1[base + t + 512] + cb[t + 512];
  float s = v0 + v1 + v2;
#pragma unroll
  for (int o = 32; o > 0; o >>= 1) s += __shfl_xor(s, o);
  if (lane == 0) red[wid] = s;
  __syncthreads();
  float mean = (red[0] + red[1] + red[2] + red[3]) * (1.f / 768.f);
  float d0 = v0 - mean, d1 = v1 - mean, d2 = v2 - mean;
  float q = d0 * d0 + d1 * d1 + d2 * d2;
#pragma unroll
  for (int o = 32; o > 0; o >>= 1) q += __shfl_xor(q, o);
  if (lane == 0) red[4 + wid] = q;
  __syncthreads();
  float var = (red[4] + red[5] + red[6] + red[7]) * (1.f / 768.f);
  float rstd = rsqrtf(var + 1e-5f);
  yn[t] = d0 * rstd * g[t] + bb[t];
  yn[t + 256] = d1 * rstd * g[t + 256] + bb[t + 256];
  yn[t + 512] = d2 * rstd * g[t + 512] + bb[t + 512];
  __syncthreads();
  if (t < 128) {
    float acc = ob[t];
    for (int d = 0; d < 768; d++) acc += yn[d] * ow[d * 128 + t];
    out[b * 128 + t] = acc;
  }
}

extern "C" void kernel_launch(void* const* d_in, const int* in_sizes, int n_in,
                              void* d_out, int out_size, void* d_ws, size_t ws_size,
                              hipStream_t stream) {
  (void)in_sizes; (void)n_in; (void)out_size;
  const int* x     = (const int*)d_in[0];
  const int* ind   = (const int*)d_in[1];
  const int* outd  = (const int*)d_in[2];
  const int* spos  = (const int*)d_in[3];
  const int* eidx  = (const int*)d_in[4];
  const float* ab   = (const float*)d_in[5];
  const float* atom = (const float*)d_in[6];
  const float* ide  = (const float*)d_in[7];
  const float* ode  = (const float*)d_in[8];
  const float* gtok = (const float*)d_in[9];
  const float* eemb = (const float*)d_in[10];
  const float* edemb= (const float*)d_in[11];
  const float* semb = (const float*)d_in[12];
  const float* virt = (const float*)d_in[13];
  const float* ln1g = (const float*)d_in[14];
  const float* ln1b = (const float*)d_in[15];
  const float* wq  = (const float*)d_in[16];
  const float* bq   = (const float*)d_in[17];
  const float* wk  = (const float*)d_in[18];
  const float* bk   = (const float*)d_in[19];
  const float* wv  = (const float*)d_in[20];
  const float* bv   = (const float*)d_in[21];
  const float* wo  = (const float*)d_in[22];
  const float* bo   = (const float*)d_in[23];
  const float* ln2g = (const float*)d_in[24];
  const float* ln2b = (const float*)d_in[25];
  const float* w1  = (const float*)d_in[26];
  const float* b1   = (const float*)d_in[27];
  const float* w2  = (const float*)d_in[28];
  const float* b2   = (const float*)d_in[29];
  const float* fg   = (const float*)d_in[30];
  const float* fb   = (const float*)d_in[31];
  const float* ow   = (const float*)d_in[32];
  const float* ob   = (const float*)d_in[33];
  float* out = (float*)d_out;

  const int DD2 = DM * DM;
  const size_t WQKVO = (size_t)DD2;
  const size_t WFF = (size_t)DM * DF;

  char* ws = (char*)d_ws;
  size_t off = 0;
  auto alloc = [&](size_t bytes) -> void* {
    void* p = ws + off;
    off += (bytes + 255) & ~(size_t)255;
    return p;
  };
  float* gab = (float*)alloc((size_t)NB * NH * SQ * SQ * 4);
  float* h   = (float*)alloc((size_t)MROWS * DM * 4);
  bf16* y    = (bf16*)alloc((size_t)MROWS * DM * 2);
  bf16* qb   = (bf16*)alloc((size_t)MROWS * DM * 2);
  bf16* kb2  = (bf16*)alloc((size_t)MROWS * DM * 2);
  bf16* vb2  = (bf16*)alloc((size_t)MROWS * DM * 2);
  bf16* ctx  = (bf16*)alloc((size_t)MROWS * DM * 2);
  bf16* t1   = (bf16*)alloc((size_t)MROWS * DF * 2);
  float* p0  = (float*)alloc((size_t)MROWS * DM * 4);
  float* p1  = (float*)alloc((size_t)MROWS * DM * 4);

  size_t need_hoist = off + ((size_t)NLAY * 4 * WQKVO + 2 * (size_t)NLAY * WFF) * 2 + (1 << 20);
  bool hoist = ws_size >= need_hoist;
  short* wT  = (short*)alloc((hoist ? (size_t)NLAY * 4 * WQKVO : 4 * WQKVO) * 2);
  short* w1T = (short*)alloc((hoist ? (size_t)NLAY * WFF : WFF) * 2);
  short* w2T = (short*)alloc((hoist ? (size_t)NLAY * WFF : WFF) * 2);

  dim3 blk(256);
  k_nodefeat<<<dim3(NB * SQ), blk, 0, stream>>>(x, ind, outd, atom, ide, ode, gtok, h);
  k_gab_border<<<dim3(NB), blk, 0, stream>>>(ab, virt, gab);
  k_gab_edge<<<dim3(NB * ND * 2), blk, 0, stream>>>(spos, eidx, eemb, edemb, semb, ab, gab);

  if (hoist) {
    Ptrs4 pq; pq.p[0] = wq; pq.p[1] = wk; pq.p[2] = wv; pq.p[3] = wo;
    k_transpose<4><<<dim3(12, 12, 48), blk, 0, stream>>>(pq, wT, DM, DM, WQKVO);
    Ptrs4 pa; pa.p[0] = w1; pa.p[1] = pa.p[2] = pa.p[3] = w1;
    k_transpose<1><<<dim3(12, 48, 12), blk, 0, stream>>>(pa, w1T, DM, DF, WFF);
    Ptrs4 pb; pb.p[0] = w2; pb.p[1] = pb.p[2] = pb.p[3] = w2;
    k_transpose<1><<<dim3(48, 12, 12), blk, 0, stream>>>(pb, w2T, DF, DM, WFF);
  }

  for (int l = 0; l < NLAY; l++) {
    if (!hoist) {
      Ptrs4 pq;
      pq.p[0] = wq + (size_t)l * DD2; pq.p[1] = wk + (size_t)l * DD2;
      pq.p[2] = wv + (size_t)l * DD2; pq.p[3] = wo + (size_t)l * DD2;
      k_transpose<4><<<dim3(12, 12, 4), blk, 0, stream>>>(pq, wT, DM, DM, 0);
      Ptrs4 pa; pa.p[0] = w1 + (size_t)l * WFF; pa.p[1] = pa.p[2] = pa.p[3] = pa.p[0];
      k_transpose<1><<<dim3(12, 48, 1), blk, 0, stream>>>(pa, w1T, DM, DF, 0);
      Ptrs4 pb; pb.p[0] = w2 + (size_t)l * WFF; pb.p[1] = pb.p[2] = pb.p[3] = pb.p[0];
      k_transpose<1><<<dim3(48, 12, 1), blk, 0, stream>>>(pb, w2T, DF, DM, 0);
    }
    const short* wTl  = wT  + (hoist ? (size_t)l * 4 * WQKVO : 0);
    const short* w1Tl = w1T + (hoist ? (size_t)l * WFF : 0);
    const short* w2Tl = w2T + (hoist ? (size_t)l * WFF : 0);

    if (l == 0)
      k_ln<<<dim3(MROWS), blk, 0, stream>>>(h, ln1g, ln1b, y);

    GemmPtrs gq;
    gq.bt[0] = wTl; gq.bt[1] = wTl + DD2; gq.bt[2] = wTl + 2 * DD2;
    gq.bias[0] = bq + l * DM; gq.bias[1] = bk + l * DM; gq.bias[2] = bv + l * DM;
    gq.out[0] = qb; gq.out[1] = kb2; gq.out[2] = vb2;
    gq.aoff[0] = gq.aoff[1] = gq.aoff[2] = 0;
    k_gemm128<4><<<dim3(17, 6, 3), blk, 0, stream>>>((const short*)y, gq, MROWS, DM, DM, DM, DM);

    k_attn<<<dim3(NB * NH), blk, 0, stream>>>(qb, kb2, vb2, gab, ctx);

    GemmPtrs go;  // Wo split-K: K=768 -> 2 x 384
    go.bt[0] = wTl + 3 * DD2; go.bt[1] = wTl + 3 * DD2 + 384;
    go.bias[0] = go.bias[1] = nullptr;
    go.out[0] = p0; go.out[1] = p1;
    go.aoff[0] = 0; go.aoff[1] = 384;
    go.bt[2] = go.bt[0]; go.out[2] = p0; go.aoff[2] = 0; go.bias[2] = nullptr;
    k_gemm64<3><<<dim3(33, 6, 2), blk, 0, stream>>>((const short*)ctx, go, MROWS, DM, 384, DM, DM);

    k_ln_add2<<<dim3(MROWS), blk, 0, stream>>>(h, p0, p1, bo + l * DM,
                                               ln2g + l * DM, ln2b + l * DM, y);

    GemmPtrs g1;
    g1.bt[0] = g1.bt[1] = g1.bt[2] = w1Tl;
    g1.bias[0] = g1.bias[1] = g1.bias[2] = b1 + l * DF;
    g1.out[0] = g1.out[1] = g1.out[2] = t1;
    g1.aoff[0] = g1.aoff[1] = g1.aoff[2] = 0;
    k_gemm128<2><<<dim3(17, 24, 1), blk, 0, stream>>>((const short*)y, g1, MROWS, DF, DM, DM, DM);

    GemmPtrs g2;  // FFN2 split-K: K=3072 -> 2 x 1536
    g2.bt[0] = w2Tl; g2.bt[1] = w2Tl + 1536;
    g2.bias[0] = g2.bias[1] = nullptr;
    g2.out[0] = p0; g2.out[1] = p1;
    g2.aoff[0] = 0; g2.aoff[1] = 1536;
    g2.bt[2] = g2.bt[0]; g2.out[2] = p0; g2.aoff[2] = 0; g2.bias[2] = nullptr;
    k_gemm64<3><<<dim3(33, 6, 2), blk, 0, stream>>>((const short*)t1, g2, MROWS, DM, 1536, DF, DF);

    if (l < NLAY - 1) {
      k_ln_add2<<<dim3(MROWS), blk, 0, stream>>>(h, p0, p1, b2 + l * DM,
                                                 ln1g + (l + 1) * DM, ln1b + (l + 1) * DM, y);
    } else {
      k_final_add2<<<dim3(NB), blk, 0, stream>>>(h, p0, p1, b2 + l * DM, fg, fb, ow, ob, out);
    }
  }
}

// Round 9
// 1697.608 us; speedup vs baseline: 2.2919x; 1.0026x over previous
//
#include <hip/hip_runtime.h>
#include <hip/hip_bf16.h>
#include <math.h>

typedef __hip_bfloat16 bf16;
typedef __attribute__((ext_vector_type(8))) short short8;
typedef __attribute__((ext_vector_type(4))) short short4v;
typedef __attribute__((ext_vector_type(4))) float f32x4;

constexpr int NB = 16;     // batch
constexpr int ND = 128;    // nodes N
constexpr int SQ = 129;    // S = N+1
constexpr int NH = 24;     // heads
constexpr int DM = 768;    // model dim
constexpr int DF = 3072;   // ffn dim
constexpr int NLAY = 12;
constexpr int MROWS = NB * SQ;  // 2064

__device__ __forceinline__ short f2bs(float f) {
  bf16 h = __float2bfloat16(f);
  return *(short*)&h;
}

__device__ __forceinline__ void gload16(const void* g, void* lds) {
  __builtin_amdgcn_global_load_lds(
      (const __attribute__((address_space(1))) unsigned int*)g,
      (__attribute__((address_space(3))) unsigned int*)lds, 16, 0, 0);
}

// ---------------- node features ----------------
__global__ void k_nodefeat(const int* __restrict__ x, const int* __restrict__ ind,
                           const int* __restrict__ outd,
                           const float* __restrict__ atom, const float* __restrict__ ide,
                           const float* __restrict__ ode, const float* __restrict__ gtok,
                           float* __restrict__ h) {
  int bs = blockIdx.x;
  int b = bs / SQ, s = bs % SQ;
  int t = threadIdx.x;
  float* hrow = h + (size_t)bs * DM;
  if (s == 0) {
    for (int c = t; c < DM; c += 256) hrow[c] = gtok[c];
  } else {
    int n = s - 1;
    const int* xr = x + (b * ND + n) * 9;
    int a0 = xr[0], a1 = xr[1], a2 = xr[2], a3 = xr[3], a4 = xr[4];
    int a5 = xr[5], a6 = xr[6], a7 = xr[7], a8 = xr[8];
    int ii = ind[b * ND + n], oo = outd[b * ND + n];
    for (int c = t; c < DM; c += 256) {
      float acc = ide[(size_t)ii * DM + c] + ode[(size_t)oo * DM + c];
      acc += atom[(size_t)a0 * DM + c];
      acc += atom[(size_t)a1 * DM + c];
      acc += atom[(size_t)a2 * DM + c];
      acc += atom[(size_t)a3 * DM + c];
      acc += atom[(size_t)a4 * DM + c];
      acc += atom[(size_t)a5 * DM + c];
      acc += atom[(size_t)a6 * DM + c];
      acc += atom[(size_t)a7 * DM + c];
      acc += atom[(size_t)a8 * DM + c];
      hrow[c] = acc;
    }
  }
}

// ---------------- gab: virtual-token borders ----------------
__global__ void k_gab_border(const float* __restrict__ ab, const float* __restrict__ virt,
                             float* __restrict__ gab) {
  int b = blockIdx.x;
  const int tot = NH * SQ + NH * ND;
  for (int idx = threadIdx.x; idx < tot; idx += 256) {
    if (idx < NH * SQ) {
      int hh = idx / SQ, j = idx % SQ;
      float v = 2.f * ab[((size_t)b * SQ + 0) * SQ + j] + virt[hh];
      gab[(((size_t)b * NH + hh) * SQ + 0) * SQ + j] = v;
    } else {
      int r = idx - NH * SQ;
      int hh = r / ND, i = r % ND + 1;
      float v = 2.f * ab[((size_t)b * SQ + i) * SQ + 0] + virt[hh];
      gab[(((size_t)b * NH + hh) * SQ + i) * SQ + 0] = v;
    }
  }
}

// ---------------- gab: spatial + multihop edge bias (MFMA, coalesced writes) ----
__global__ __launch_bounds__(256) void k_gab_edge(
    const int* __restrict__ spos, const int* __restrict__ eidx,
    const float* __restrict__ eemb, const float* __restrict__ edemb,
    const float* __restrict__ semb, const float* __restrict__ ab,
    float* __restrict__ gab) {
  __shared__ int eidxs[960];       // 64 j x 5 d x 3 f
  __shared__ short ei2[64 * 136];  // bf16 [j][dh]
  __shared__ short edT[32 * 136];  // bf16 [k][dh]
  __shared__ float ot[24][65];     // raw MFMA out [k][j], padded
  __shared__ float rinvA[64], a2A[64];
  __shared__ int spA[64];
  int bi = blockIdx.x;
  int half = bi & 1;
  int i = (bi >> 1) & 127;
  int b = bi >> 8;
  int j0 = half * 64;
  int t = threadIdx.x;
  const size_t rowbase = ((size_t)(b * ND + i)) * ND + j0;

  const int* esrc = eidx + rowbase * 15;
  for (int idx = t; idx < 960; idx += 256) eidxs[idx] = esrc[idx];
  for (int u = t; u < 720; u += 256) {
    int dh = u / 6, kq = u % 6;
    f32x4 v = *(const f32x4*)&edemb[dh * 24 + kq * 4];
    edT[(kq * 4 + 0) * 136 + dh] = f2bs(v[0]);
    edT[(kq * 4 + 1) * 136 + dh] = f2bs(v[1]);
    edT[(kq * 4 + 2) * 136 + dh] = f2bs(v[2]);
    edT[(kq * 4 + 3) * 136 + dh] = f2bs(v[3]);
  }
  for (int u = t; u < 1472; u += 256) {
    int k, dh;
    if (u < 384) { k = u >> 4; dh = 120 + (u & 15); }
    else { int v = u - 384; k = 24 + v / 136; dh = v % 136; }
    edT[k * 136 + dh] = 0;
  }
  if (t < 64) {
    int j = t;
    int sp = spos[rowbase + j];
    int spc = (sp == 0) ? 1 : sp;
    spc = (spc > 1) ? spc - 1 : spc;
    if (spc > 5) spc = 5;
    spA[j] = sp;
    rinvA[j] = 1.f / (float)spc;
    a2A[j] = 2.f * ab[((size_t)b * SQ + (i + 1)) * SQ + (j0 + j + 1)];
  }
  __syncthreads();

  {
    int j = t & 63, d = t >> 6;
#pragma unroll
    for (int pass = 0; pass < 2; pass++) {
      if (pass == 1) {
        if (t >= 64) break;
        j = t; d = 4;
      }
      const int* ep = &eidxs[j * 15 + d * 3];
      const float* r0 = eemb + (size_t)ep[0] * NH;
      const float* r1 = eemb + (size_t)ep[1] * NH;
      const float* r2 = eemb + (size_t)ep[2] * NH;
#pragma unroll
      for (int hq = 0; hq < 6; hq++) {
        f32x4 s = (*(const f32x4*)&r0[hq * 4] + *(const f32x4*)&r1[hq * 4] +
                   *(const f32x4*)&r2[hq * 4]) * (1.f / 3.f);
        short4v o;
        o[0] = f2bs(s[0]); o[1] = f2bs(s[1]); o[2] = f2bs(s[2]); o[3] = f2bs(s[3]);
        *(short4v*)&ei2[j * 136 + d * 24 + hq * 4] = o;
      }
    }
  }
  for (int idx = t; idx < 64 * 8; idx += 256) {
    int j = idx >> 3;
    ei2[j * 136 + 120 + (idx & 7)] = 0;
  }
  __syncthreads();

  int lane = t & 63, w = t >> 6;
  int fr = lane & 15, q = lane >> 4, fo = q * 8;
  f32x4 acc0 = {0.f, 0.f, 0.f, 0.f}, acc1 = {0.f, 0.f, 0.f, 0.f};
#pragma unroll
  for (int kk = 0; kk < 4; kk++) {
    short8 af = *(const short8*)&ei2[(w * 16 + fr) * 136 + kk * 32 + fo];
    short8 b0 = *(const short8*)&edT[(fr) * 136 + kk * 32 + fo];
    short8 b1 = *(const short8*)&edT[(16 + fr) * 136 + kk * 32 + fo];
    acc0 = __builtin_amdgcn_mfma_f32_16x16x32_bf16(af, b0, acc0, 0, 0, 0);
    acc1 = __builtin_amdgcn_mfma_f32_16x16x32_bf16(af, b1, acc1, 0, 0, 0);
  }
#pragma unroll
  for (int e = 0; e < 4; e++) {
    int j = w * 16 + q * 4 + e;
    ot[fr][j] = acc0[e];
    if (fr < 8) ot[16 + fr][j] = acc1[e];
  }
  __syncthreads();
  size_t obase = (((size_t)b * NH) * SQ + (i + 1)) * SQ + (j0 + 1);
  for (int idx = t; idx < 24 * 64; idx += 256) {
    int k = idx >> 6, j = idx & 63;
    float v = a2A[j] + semb[spA[j] * NH + k] + ot[k][j] * rinvA[j];
    gab[obase + (size_t)k * SQ * SQ + j] = v;
  }
}

// ---------------- weight transpose+cast: f32 [R,C] -> bf16 [C,R] ----------------
struct Ptrs4 { const float* p[4]; };

template <int NW>
__global__ void k_transpose(Ptrs4 ps, short* __restrict__ dst, int R, int C,
                            size_t sstride) {
  __shared__ short tile[64][68];
  int z = blockIdx.z;
  const float* src = ps.p[z % NW] + (size_t)(z / NW) * sstride;
  short* d = dst + (size_t)z * (size_t)R * C;
  int r0 = blockIdx.x * 64, c0 = blockIdx.y * 64;
  int t = threadIdx.x;
  int tr = t >> 4, tc = (t & 15) * 4;
#pragma unroll
  for (int i = 0; i < 4; i++) {
    int r = tr + i * 16;
    f32x4 v = *(const f32x4*)(src + (size_t)(r0 + r) * C + c0 + tc);
    tile[r][tc + 0] = f2bs(v[0]);
    tile[r][tc + 1] = f2bs(v[1]);
    tile[r][tc + 2] = f2bs(v[2]);
    tile[r][tc + 3] = f2bs(v[3]);
  }
  __syncthreads();
#pragma unroll
  for (int i = 0; i < 4; i++) {
    int rr = tr + i * 16;
    short4v o;
    o[0] = tile[tc + 0][rr];
    o[1] = tile[tc + 1][rr];
    o[2] = tile[tc + 2][rr];
    o[3] = tile[tc + 3][rr];
    *(short4v*)(d + (size_t)(c0 + rr) * R + r0 + tc) = o;
  }
}

// ---------------- LayerNorm: fp32 row -> bf16 row ----------------
__global__ void k_ln(const float* __restrict__ h, const float* __restrict__ g,
                     const float* __restrict__ bb, bf16* __restrict__ y) {
  int r = blockIdx.x;
  int t = threadIdx.x, lane = t & 63, wid = t >> 6;
  __shared__ float red[8];
  const float* row = h + (size_t)r * DM;
  float v0 = row[t], v1 = row[t + 256], v2 = row[t + 512];
  float s = v0 + v1 + v2;
#pragma unroll
  for (int o = 32; o > 0; o >>= 1) s += __shfl_xor(s, o);
  if (lane == 0) red[wid] = s;
  __syncthreads();
  float mean = (red[0] + red[1] + red[2] + red[3]) * (1.f / 768.f);
  float d0 = v0 - mean, d1 = v1 - mean, d2 = v2 - mean;
  float q = d0 * d0 + d1 * d1 + d2 * d2;
#pragma unroll
  for (int o = 32; o > 0; o >>= 1) q += __shfl_xor(q, o);
  if (lane == 0) red[4 + wid] = q;
  __syncthreads();
  float var = (red[4] + red[5] + red[6] + red[7]) * (1.f / 768.f);
  float rstd = rsqrtf(var + 1e-5f);
  bf16* yr = y + (size_t)r * DM;
  yr[t] = __float2bfloat16(d0 * rstd * g[t] + bb[t]);
  yr[t + 256] = __float2bfloat16(d1 * rstd * g[t + 256] + bb[t + 256]);
  yr[t + 512] = __float2bfloat16(d2 * rstd * g[t + 512] + bb[t + 512]);
}

// ---------------- fused: h += p0+p1+cbias; y = LN(h) ----------------
__global__ void k_ln_add2(float* __restrict__ h, const float* __restrict__ p0,
                          const float* __restrict__ p1, const float* __restrict__ cb,
                          const float* __restrict__ g, const float* __restrict__ bb,
                          bf16* __restrict__ y) {
  int r = blockIdx.x;
  int t = threadIdx.x, lane = t & 63, wid = t >> 6;
  __shared__ float red[8];
  size_t base = (size_t)r * DM;
  float v0 = h[base + t] + p0[base + t] + p1[base + t] + cb[t];
  float v1 = h[base + t + 256] + p0[base + t + 256] + p1[base + t + 256] + cb[t + 256];
  float v2 = h[base + t + 512] + p0[base + t + 512] + p1[base + t + 512] + cb[t + 512];
  h[base + t] = v0;
  h[base + t + 256] = v1;
  h[base + t + 512] = v2;
  float s = v0 + v1 + v2;
#pragma unroll
  for (int o = 32; o > 0; o >>= 1) s += __shfl_xor(s, o);
  if (lane == 0) red[wid] = s;
  __syncthreads();
  float mean = (red[0] + red[1] + red[2] + red[3]) * (1.f / 768.f);
  float d0 = v0 - mean, d1 = v1 - mean, d2 = v2 - mean;
  float q = d0 * d0 + d1 * d1 + d2 * d2;
#pragma unroll
  for (int o = 32; o > 0; o >>= 1) q += __shfl_xor(q, o);
  if (lane == 0) red[4 + wid] = q;
  __syncthreads();
  float var = (red[4] + red[5] + red[6] + red[7]) * (1.f / 768.f);
  float rstd = rsqrtf(var + 1e-5f);
  bf16* yr = y + base;
  yr[t] = __float2bfloat16(d0 * rstd * g[t] + bb[t]);
  yr[t + 256] = __float2bfloat16(d1 * rstd * g[t + 256] + bb[t + 256]);
  yr[t + 512] = __float2bfloat16(d2 * rstd * g[t + 512] + bb[t + 512]);
}

// ---------------- GEMM common ----------------
// MODE 0: fp32+bias; MODE 2: GELU->bf16; MODE 3: raw fp32; MODE 4: bf16+bias
struct GemmPtrs {
  const short* bt[3];
  const float* bias[3];
  void* out[3];
  int aoff[3];
};

template <int MODE>
__device__ __forceinline__ void gemm_store(void* outp, size_t idx, float v) {
  if (MODE == 0 || MODE == 3) {
    ((float*)outp)[idx] = v;
  } else if (MODE == 4) {
    ((bf16*)outp)[idx] = __float2bfloat16(v);
  } else {
    float gg = 0.5f * v * (1.f + erff(v * 0.70710678118654752f));
    ((bf16*)outp)[idx] = __float2bfloat16(gg);
  }
}

// 128x128 block, 4 waves x 64x64, BK=64, SINGLE-buffer (m97-style), swizzle.
// 32KB LDS -> 3 blocks/CU.
template <int MODE>
__global__ __launch_bounds__(256, 3) void k_gemm128(const short* __restrict__ A, GemmPtrs p,
                                                    int M, int N, int K, int lda, int ldb) {
  __shared__ short At[128 * 64];
  __shared__ short Bt[128 * 64];
  int z = blockIdx.z;
  const short* BT = p.bt[z];
  const float* bias = p.bias[z];
  A += p.aoff[z];
  int m0 = blockIdx.x * 128, n0 = blockIdx.y * 128;
  int t = threadIdx.x, lane = t & 63, wid = t >> 6;
  int wr = wid >> 1, wc = wid & 1;
  f32x4 acc[4][4];
#pragma unroll
  for (int a = 0; a < 4; a++)
#pragma unroll
    for (int c = 0; c < 4; c++) acc[a][c] = (f32x4){0.f, 0.f, 0.f, 0.f};

  int lrow8 = lane >> 3;
  int lseg = (lane & 7) ^ lrow8;
  const short* gA[4];
  const short* gB[4];
#pragma unroll
  for (int i = 0; i < 4; i++) {
    int ar = m0 + wid * 32 + i * 8 + lrow8;
    if (ar >= M) ar = M - 1;
    gA[i] = A + (size_t)ar * lda + lseg * 8;
    int br = n0 + wid * 32 + i * 8 + lrow8;
    gB[i] = BT + (size_t)br * ldb + lseg * 8;
  }

  const int NIT = K >> 6;
  int fr = lane & 15, q = lane >> 4;
  for (int it = 0; it < NIT; ++it) {
    int k0 = it << 6;
#pragma unroll
    for (int i = 0; i < 4; i++) {
      gload16(gA[i] + k0, &At[(wid * 32 + i * 8) * 64]);
      gload16(gB[i] + k0, &Bt[(wid * 32 + i * 8) * 64]);
    }
    __syncthreads();
#pragma unroll
    for (int kk = 0; kk < 2; kk++) {
      int sg = ((q + kk * 4) ^ (fr & 7)) * 8;
      short8 af[4], bf[4];
#pragma unroll
      for (int mr = 0; mr < 4; mr++)
        af[mr] = *(const short8*)&At[(wr * 64 + mr * 16 + fr) * 64 + sg];
#pragma unroll
      for (int nc = 0; nc < 4; nc++)
        bf[nc] = *(const short8*)&Bt[(wc * 64 + nc * 16 + fr) * 64 + sg];
#pragma unroll
      for (int mr = 0; mr < 4; mr++)
#pragma unroll
        for (int nc = 0; nc < 4; nc++)
          acc[mr][nc] = __builtin_amdgcn_mfma_f32_16x16x32_bf16(af[mr], bf[nc], acc[mr][nc], 0, 0, 0);
    }
    __syncthreads();
  }

  int rsub = q * 4;
#pragma unroll
  for (int nc = 0; nc < 4; nc++) {
    int col = n0 + wc * 64 + nc * 16 + fr;
    float bv = (MODE == 3) ? 0.f : bias[col];
#pragma unroll
    for (int mr = 0; mr < 4; mr++) {
#pragma unroll
      for (int e = 0; e < 4; e++) {
        int r = m0 + wr * 64 + mr * 16 + rsub + e;
        if (r < M) gemm_store<MODE>(p.out[z], (size_t)r * N + col, acc[mr][nc][e] + bv);
      }
    }
  }
}

// 64x128 block, 4 waves x 32x64, BK=64, SINGLE-buffer, swizzle. 24KB -> 4 blocks/CU.
template <int MODE>
__global__ __launch_bounds__(256, 4) void k_gemm64(const short* __restrict__ A, GemmPtrs p,
                                                   int M, int N, int K, int lda, int ldb) {
  __shared__ short At[64 * 64];
  __shared__ short Bt[128 * 64];
  int z = blockIdx.z;
  const short* BT = p.bt[z];
  const float* bias = p.bias[z];
  A += p.aoff[z];
  int m0 = blockIdx.x * 64, n0 = blockIdx.y * 128;
  int t = threadIdx.x, lane = t & 63, wid = t >> 6;
  int wr = wid >> 1, wc = wid & 1;
  f32x4 acc[2][4];
#pragma unroll
  for (int a = 0; a < 2; a++)
#pragma unroll
    for (int c = 0; c < 4; c++) acc[a][c] = (f32x4){0.f, 0.f, 0.f, 0.f};

  int lrow8 = lane >> 3;
  int lseg = (lane & 7) ^ lrow8;
  const short* gA[2];
  const short* gB[4];
#pragma unroll
  for (int i = 0; i < 2; i++) {
    int ar = m0 + wid * 16 + i * 8 + lrow8;
    if (ar >= M) ar = M - 1;
    gA[i] = A + (size_t)ar * lda + lseg * 8;
  }
#pragma unroll
  for (int i = 0; i < 4; i++) {
    int br = n0 + wid * 32 + i * 8 + lrow8;
    gB[i] = BT + (size_t)br * ldb + lseg * 8;
  }

  const int NIT = K >> 6;
  int fr = lane & 15, q = lane >> 4;
  for (int it = 0; it < NIT; ++it) {
    int k0 = it << 6;
#pragma unroll
    for (int i = 0; i < 2; i++) gload16(gA[i] + k0, &At[(wid * 16 + i * 8) * 64]);
#pragma unroll
    for (int i = 0; i < 4; i++) gload16(gB[i] + k0, &Bt[(wid * 32 + i * 8) * 64]);
    __syncthreads();
#pragma unroll
    for (int kk = 0; kk < 2; kk++) {
      int sg = ((q + kk * 4) ^ (fr & 7)) * 8;
      short8 af[2], bf[4];
#pragma unroll
      for (int mr = 0; mr < 2; mr++)
        af[mr] = *(const short8*)&At[(wr * 32 + mr * 16 + fr) * 64 + sg];
#pragma unroll
      for (int nc = 0; nc < 4; nc++)
        bf[nc] = *(const short8*)&Bt[(wc * 64 + nc * 16 + fr) * 64 + sg];
#pragma unroll
      for (int mr = 0; mr < 2; mr++)
#pragma unroll
        for (int nc = 0; nc < 4; nc++)
          acc[mr][nc] = __builtin_amdgcn_mfma_f32_16x16x32_bf16(af[mr], bf[nc], acc[mr][nc], 0, 0, 0);
    }
    __syncthreads();
  }

  int rsub = q * 4;
#pragma unroll
  for (int nc = 0; nc < 4; nc++) {
    int col = n0 + wc * 64 + nc * 16 + fr;
    float bv = (MODE == 3) ? 0.f : bias[col];
#pragma unroll
    for (int mr = 0; mr < 2; mr++) {
#pragma unroll
      for (int e = 0; e < 4; e++) {
        int r = m0 + wr * 32 + mr * 16 + rsub + e;
        if (r < M) gemm_store<MODE>(p.out[z], (size_t)r * N + col, acc[mr][nc][e] + bv);
      }
    }
  }
}

// ---------------- attention: MFMA flash, one block per (b,h) ----------------
__global__ __launch_bounds__(256) void k_attn(const bf16* __restrict__ Q,
                                              const bf16* __restrict__ Kb,
                                              const bf16* __restrict__ Vb,
                                              const float* __restrict__ gab,
                                              bf16* __restrict__ ctx) {
  __shared__ short Ql[144 * 40];   // [row][k], rows 129+ zeroed
  __shared__ short Kl[144 * 40];   // [kk][k], rows 129+ zeroed
  __shared__ short Vt[32 * 168];   // [d][kk], kk 128+ zeroed
  __shared__ short Pc[144 * 40];   // P chunk [row][kk_local], wave-private rows
  int bh = blockIdx.x;
  int b = bh / NH, hh = bh % NH;
  int t = threadIdx.x;
  for (int idx = t; idx < 32 * 40; idx += 256) {
    int d = idx / 40, kk = 128 + (idx % 40);
    Vt[d * 168 + kk] = 0;
  }
  for (int idx = t; idx < 129 * 4; idx += 256) {
    int s = idx >> 2, seg = idx & 3;
    size_t src = ((size_t)(b * SQ + s)) * DM + hh * 32 + seg * 8;
    *(short8*)&Ql[s * 40 + seg * 8] = *(const short8*)((const short*)Q + src);
    *(short8*)&Kl[s * 40 + seg * 8] = *(const short8*)((const short*)Kb + src);
  }
  for (int idx = t; idx < 15 * 4; idx += 256) {
    int s = 129 + (idx >> 2), seg = idx & 3;
    short8 zz = {0, 0, 0, 0, 0, 0, 0, 0};
    *(short8*)&Ql[s * 40 + seg * 8] = zz;
    *(short8*)&Kl[s * 40 + seg * 8] = zz;
  }
  for (int idx = t; idx < 129 * 4; idx += 256) {
    int kk = idx >> 2, seg = idx & 3;
    size_t src = ((size_t)(b * SQ + kk)) * DM + hh * 32 + seg * 8;
    short8 v = *(const short8*)((const short*)Vb + src);
#pragma unroll
    for (int j = 0; j < 8; j++) Vt[(seg * 8 + j) * 168 + kk] = v[j];
  }
  __syncthreads();

  int lane = t & 63, w = t >> 6;
  int c16 = lane & 15, q4 = lane >> 4;
  const float scale = 0.17677669529663689f;  // 1/sqrt(32)
  const float* gabp = gab + (((size_t)(b * NH + hh)) * SQ) * SQ;

  for (int mt = w; mt < 9; mt += 4) {
    f32x4 sc[9];
    short8 aq = *(const short8*)&Ql[(mt * 16 + c16) * 40 + q4 * 8];
#pragma unroll
    for (int nt = 0; nt < 9; nt++) {
      short8 bk = *(const short8*)&Kl[(nt * 16 + c16) * 40 + q4 * 8];
      f32x4 zz = {0.f, 0.f, 0.f, 0.f};
      sc[nt] = __builtin_amdgcn_mfma_f32_16x16x32_bf16(aq, bk, zz, 0, 0, 0);
    }
#pragma unroll
    for (int e = 0; e < 4; e++) {
      int row = mt * 16 + q4 * 4 + e;
      int rr = row < 129 ? row : 128;
      const float* grow = gabp + (size_t)rr * SQ;
      float mloc = -1e30f;
#pragma unroll
      for (int nt = 0; nt < 9; nt++) {
        int col = nt * 16 + c16;
        float s = (col < 129) ? (sc[nt][e] * scale + grow[col]) : -1e30f;
        sc[nt][e] = s;
        mloc = fmaxf(mloc, s);
      }
#pragma unroll
      for (int o = 1; o < 16; o <<= 1) mloc = fmaxf(mloc, __shfl_xor(mloc, o));
      float sum = 0.f;
#pragma unroll
      for (int nt = 0; nt < 9; nt++) {
        float pp = __expf(sc[nt][e] - mloc);
        sc[nt][e] = pp;
        sum += pp;
      }
#pragma unroll
      for (int o = 1; o < 16; o <<= 1) sum += __shfl_xor(sum, o);
      float inv = 1.f / sum;
#pragma unroll
      for (int nt = 0; nt < 9; nt++) sc[nt][e] *= inv;
    }
    f32x4 oacc0 = {0.f, 0.f, 0.f, 0.f}, oacc1 = {0.f, 0.f, 0.f, 0.f};
#pragma unroll
    for (int c = 0; c < 5; c++) {
#pragma unroll
      for (int u = 0; u < 2; u++) {
        int nt = c * 2 + u;
        if (nt < 9) {
#pragma unroll
          for (int e = 0; e < 4; e++)
            Pc[(mt * 16 + q4 * 4 + e) * 40 + u * 16 + c16] = f2bs(sc[nt][e]);
        } else {
#pragma unroll
          for (int e = 0; e < 4; e++)
            Pc[(mt * 16 + q4 * 4 + e) * 40 + u * 16 + c16] = 0;
        }
      }
      asm volatile("s_waitcnt lgkmcnt(0)" ::: "memory");
      __builtin_amdgcn_sched_barrier(0);
      short8 ap = *(const short8*)&Pc[(mt * 16 + c16) * 40 + q4 * 8];
      short8 bv0 = *(const short8*)&Vt[(c16) * 168 + c * 32 + q4 * 8];
      short8 bv1 = *(const short8*)&Vt[(16 + c16) * 168 + c * 32 + q4 * 8];
      oacc0 = __builtin_amdgcn_mfma_f32_16x16x32_bf16(ap, bv0, oacc0, 0, 0, 0);
      oacc1 = __builtin_amdgcn_mfma_f32_16x16x32_bf16(ap, bv1, oacc1, 0, 0, 0);
    }
#pragma unroll
    for (int e = 0; e < 4; e++) {
      int row = mt * 16 + q4 * 4 + e;
      if (row < 129) {
        size_t obase = ((size_t)(b * SQ + row)) * DM + hh * 32;
        ctx[obase + c16] = __float2bfloat16(oacc0[e]);
        ctx[obase + 16 + c16] = __float2bfloat16(oacc1[e]);
      }
    }
  }
}

// ---------------- final: h_row0 + p0 + p1 + cbias -> LN -> project ----------------
__global__ void k_final_add2(const float* __restrict__ h, const float* __restrict__ p0,
                             const float* __restrict__ p1, const float* __restrict__ cb,
                             const float* __restrict__ g, const float* __restrict__ bb,
                             const float* __restrict__ ow, const float* __restrict__ ob,
                             float* __restrict__ out) {
  int b = blockIdx.x;
  int t = threadIdx.x, lane = t & 63, wid = t >> 6;
  __shared__ float red[8];
  __shared__ float yn[768];
  size_t base = (size_t)(b * SQ) * DM;
  float v0 = h[base + t] + p0[base + t] + p1[base + t] + cb[t];
  float v1 = h[base + t + 256] + p0[base + t + 256] + p1[base + t + 256] + cb[t + 256];
  float v2 = h[base + t + 512] + p0[base + t + 512] + p1[base + t + 512] + cb[t + 512];
  float s = v0 + v1 + v2;
#pragma unroll
  for (int o = 32; o > 0; o >>= 1) s += __shfl_xor(s, o);
  if (lane == 0) red[wid] = s;
  __syncthreads();
  float mean = (red[0] + red[1] + red[2] + red[3]) * (1.f / 768.f);
  float d0 = v0 - mean, d1 = v1 - mean, d2 = v2 - mean;
  float q = d0 * d0 + d1 * d1 + d2 * d2;
#pragma unroll
  for (int o = 32; o > 0; o >>= 1) q += __shfl_xor(q, o);
  if (lane == 0) red[4 + wid] = q;
  __syncthreads();
  float var = (red[4] + red[5] + red[6] + red[7]) * (1.f / 768.f);
  float rstd = rsqrtf(var + 1e-5f);
  yn[t] = d0 * rstd * g[t] + bb[t];
  yn[t + 256] = d1 * rstd * g[t + 256] + bb[t + 256];
  yn[t + 512] = d2 * rstd * g[t + 512] + bb[t + 512];
  __syncthreads();
  if (t < 128) {
    float acc = ob[t];
    for (int d = 0; d < 768; d++) acc += yn[d] * ow[d * 128 + t];
    out[b * 128 + t] = acc;
  }
}

extern "C" void kernel_launch(void* const* d_in, const int* in_sizes, int n_in,
                              void* d_out, int out_size, void* d_ws, size_t ws_size,
                              hipStream_t stream) {
  (void)in_sizes; (void)n_in; (void)out_size;
  const int* x     = (const int*)d_in[0];
  const int* ind   = (const int*)d_in[1];
  const int* outd  = (const int*)d_in[2];
  const int* spos  = (const int*)d_in[3];
  const int* eidx  = (const int*)d_in[4];
  const float* ab   = (const float*)d_in[5];
  const float* atom = (const float*)d_in[6];
  const float* ide  = (const float*)d_in[7];
  const float* ode  = (const float*)d_in[8];
  const float* gtok = (const float*)d_in[9];
  const float* eemb = (const float*)d_in[10];
  const float* edemb= (const float*)d_in[11];
  const float* semb = (const float*)d_in[12];
  const float* virt = (const float*)d_in[13];
  const float* ln1g = (const float*)d_in[14];
  const float* ln1b = (const float*)d_in[15];
  const float* wq  = (const float*)d_in[16];
  const float* bq   = (const float*)d_in[17];
  const float* wk  = (const float*)d_in[18];
  const float* bk   = (const float*)d_in[19];
  const float* wv  = (const float*)d_in[20];
  const float* bv   = (const float*)d_in[21];
  const float* wo  = (const float*)d_in[22];
  const float* bo   = (const float*)d_in[23];
  const float* ln2g = (const float*)d_in[24];
  const float* ln2b = (const float*)d_in[25];
  const float* w1  = (const float*)d_in[26];
  const float* b1   = (const float*)d_in[27];
  const float* w2  = (const float*)d_in[28];
  const float* b2   = (const float*)d_in[29];
  const float* fg   = (const float*)d_in[30];
  const float* fb   = (const float*)d_in[31];
  const float* ow   = (const float*)d_in[32];
  const float* ob   = (const float*)d_in[33];
  float* out = (float*)d_out;

  const int DD2 = DM * DM;
  const size_t WQKVO = (size_t)DD2;
  const size_t WFF = (size_t)DM * DF;

  char* ws = (char*)d_ws;
  size_t off = 0;
  auto alloc = [&](size_t bytes) -> void* {
    void* p = ws + off;
    off += (bytes + 255) & ~(size_t)255;
    return p;
  };
  float* gab = (float*)alloc((size_t)NB * NH * SQ * SQ * 4);
  float* h   = (float*)alloc((size_t)MROWS * DM * 4);
  bf16* y    = (bf16*)alloc((size_t)MROWS * DM * 2);
  bf16* qb   = (bf16*)alloc((size_t)MROWS * DM * 2);
  bf16* kb2  = (bf16*)alloc((size_t)MROWS * DM * 2);
  bf16* vb2  = (bf16*)alloc((size_t)MROWS * DM * 2);
  bf16* ctx  = (bf16*)alloc((size_t)MROWS * DM * 2);
  bf16* t1   = (bf16*)alloc((size_t)MROWS * DF * 2);
  float* p0  = (float*)alloc((size_t)MROWS * DM * 4);
  float* p1  = (float*)alloc((size_t)MROWS * DM * 4);

  size_t need_hoist = off + ((size_t)NLAY * 4 * WQKVO + 2 * (size_t)NLAY * WFF) * 2 + (1 << 20);
  bool hoist = ws_size >= need_hoist;
  short* wT  = (short*)alloc((hoist ? (size_t)NLAY * 4 * WQKVO : 4 * WQKVO) * 2);
  short* w1T = (short*)alloc((hoist ? (size_t)NLAY * WFF : WFF) * 2);
  short* w2T = (short*)alloc((hoist ? (size_t)NLAY * WFF : WFF) * 2);

  dim3 blk(256);
  k_nodefeat<<<dim3(NB * SQ), blk, 0, stream>>>(x, ind, outd, atom, ide, ode, gtok, h);
  k_gab_border<<<dim3(NB), blk, 0, stream>>>(ab, virt, gab);
  k_gab_edge<<<dim3(NB * ND * 2), blk, 0, stream>>>(spos, eidx, eemb, edemb, semb, ab, gab);

  if (hoist) {
    Ptrs4 pq; pq.p[0] = wq; pq.p[1] = wk; pq.p[2] = wv; pq.p[3] = wo;
    k_transpose<4><<<dim3(12, 12, 48), blk, 0, stream>>>(pq, wT, DM, DM, WQKVO);
    Ptrs4 pa; pa.p[0] = w1; pa.p[1] = pa.p[2] = pa.p[3] = w1;
    k_transpose<1><<<dim3(12, 48, 12), blk, 0, stream>>>(pa, w1T, DM, DF, WFF);
    Ptrs4 pb; pb.p[0] = w2; pb.p[1] = pb.p[2] = pb.p[3] = w2;
    k_transpose<1><<<dim3(48, 12, 12), blk, 0, stream>>>(pb, w2T, DF, DM, WFF);
  }

  for (int l = 0; l < NLAY; l++) {
    if (!hoist) {
      Ptrs4 pq;
      pq.p[0] = wq + (size_t)l * DD2; pq.p[1] = wk + (size_t)l * DD2;
      pq.p[2] = wv + (size_t)l * DD2; pq.p[3] = wo + (size_t)l * DD2;
      k_transpose<4><<<dim3(12, 12, 4), blk, 0, stream>>>(pq, wT, DM, DM, 0);
      Ptrs4 pa; pa.p[0] = w1 + (size_t)l * WFF; pa.p[1] = pa.p[2] = pa.p[3] = pa.p[0];
      k_transpose<1><<<dim3(12, 48, 1), blk, 0, stream>>>(pa, w1T, DM, DF, 0);
      Ptrs4 pb; pb.p[0] = w2 + (size_t)l * WFF; pb.p[1] = pb.p[2] = pb.p[3] = pb.p[0];
      k_transpose<1><<<dim3(48, 12, 1), blk, 0, stream>>>(pb, w2T, DF, DM, 0);
    }
    const short* wTl  = wT  + (hoist ? (size_t)l * 4 * WQKVO : 0);
    const short* w1Tl = w1T + (hoist ? (size_t)l * WFF : 0);
    const short* w2Tl = w2T + (hoist ? (size_t)l * WFF : 0);

    if (l == 0)
      k_ln<<<dim3(MROWS), blk, 0, stream>>>(h, ln1g, ln1b, y);

    GemmPtrs gq;
    gq.bt[0] = wTl; gq.bt[1] = wTl + DD2; gq.bt[2] = wTl + 2 * DD2;
    gq.bias[0] = bq + l * DM; gq.bias[1] = bk + l * DM; gq.bias[2] = bv + l * DM;
    gq.out[0] = qb; gq.out[1] = kb2; gq.out[2] = vb2;
    gq.aoff[0] = gq.aoff[1] = gq.aoff[2] = 0;
    k_gemm128<4><<<dim3(17, 6, 3), blk, 0, stream>>>((const short*)y, gq, MROWS, DM, DM, DM, DM);

    k_attn<<<dim3(NB * NH), blk, 0, stream>>>(qb, kb2, vb2, gab, ctx);

    GemmPtrs go;  // Wo split-K: K=768 -> 2 x 384
    go.bt[0] = wTl + 3 * DD2; go.bt[1] = wTl + 3 * DD2 + 384;
    go.bias[0] = go.bias[1] = nullptr;
    go.out[0] = p0; go.out[1] = p1;
    go.aoff[0] = 0; go.aoff[1] = 384;
    go.bt[2] = go.bt[0]; go.out[2] = p0; go.aoff[2] = 0; go.bias[2] = nullptr;
    k_gemm64<3><<<dim3(33, 6, 2), blk, 0, stream>>>((const short*)ctx, go, MROWS, DM, 384, DM, DM);

    k_ln_add2<<<dim3(MROWS), blk, 0, stream>>>(h, p0, p1, bo + l * DM,
                                               ln2g + l * DM, ln2b + l * DM, y);

    GemmPtrs g1;
    g1.bt[0] = g1.bt[1] = g1.bt[2] = w1Tl;
    g1.bias[0] = g1.bias[1] = g1.bias[2] = b1 + l * DF;
    g1.out[0] = g1.out[1] = g1.out[2] = t1;
    g1.aoff[0] = g1.aoff[1] = g1.aoff[2] = 0;
    k_gemm128<2><<<dim3(17, 24, 1), blk, 0, stream>>>((const short*)y, g1, MROWS, DF, DM, DM, DM);

    GemmPtrs g2;  // FFN2 split-K: K=3072 -> 2 x 1536
    g2.bt[0] = w2Tl; g2.bt[1] = w2Tl + 1536;
    g2.bias[0] = g2.bias[1] = nullptr;
    g2.out[0] = p0; g2.out[1] = p1;
    g2.aoff[0] = 0; g2.aoff[1] = 1536;
    g2.bt[2] = g2.bt[0]; g2.out[2] = p0; g2.aoff[2] = 0; g2.bias[2] = nullptr;
    k_gemm64<3><<<dim3(33, 6, 2), blk, 0, stream>>>((const short*)t1, g2, MROWS, DM, 1536, DF, DF);

    if (l < NLAY - 1) {
      k_ln_add2<<<dim3(MROWS), blk, 0, stream>>>(h, p0, p1, b2 + l * DM,
                                                 ln1g + (l + 1) * DM, ln1b + (l + 1) * DM, y);
    } else {
      k_final_add2<<<dim3(NB), blk, 0, stream>>>(h, p0, p1, b2 + l * DM, fg, fb, ow, ob, out);
    }
  }
}